// Round 2
// baseline (7909.656 us; speedup 1.0000x reference)
//
#include <hip/hip_runtime.h>
#include <hip/hip_bf16.h>

typedef __hip_bfloat16 bf16;

static __device__ __forceinline__ float b2f(bf16 x){ return __bfloat162float(x); }

// dtype-flexible input load: isbf ? bf16[i] : f32[i]
static __device__ __forceinline__ float ldin(const void* p, size_t i, bool isbf) {
  return isbf ? b2f(((const bf16*)p)[i]) : ((const float*)p)[i];
}

#define CDIV(a,b) (((a)+(b)-1)/(b))

// Model constants
#define NB   4
#define NSL  50
#define HWT  256
#define NT   306     // NSL + HWT
#define DIM  512
#define NH   8
#define FF   2048

// ---------------------------------------------------------------------------
// dtype detector: if any of the first 256 u16 words of `images` has bf16
// exponent >= 0x88 (|v|>=512 or NaN/Inf) the data cannot be bf16 N(0,1)
// image data -> it is f32 (junk mantissa halves). flag=1 means bf16.
// ---------------------------------------------------------------------------
__global__ void detect_k(const void* p, int* flag) {
  const unsigned short* u = (const unsigned short*)p;
  int t = threadIdx.x;
  int e = (u[t] >> 7) & 0xFF;
  __shared__ int anybad;
  if (t == 0) anybad = 0;
  __syncthreads();
  if (e >= 0x88) atomicOr(&anybad, 1);
  __syncthreads();
  if (t == 0) *flag = anybad ? 0 : 1;
}

// ---------------------------------------------------------------------------
// Offset-aware GEMM: C[M,N] = act(A[M,K] @ W[woff..][K,N] + bias[boff..]),
// optional accumulate. A: f32 ws, W/bias: model inputs (bf16 or f32), C: f32.
// 64x64 tile, 16x16 threads, 4x4 microtile, K-step 16.
// ---------------------------------------------------------------------------
__global__ __launch_bounds__(256) void gemm_k(
    const float* __restrict__ A, const void* __restrict__ W, size_t woff,
    const void* __restrict__ bias, size_t boff, float* __restrict__ C,
    int M, int N, int K, int act, int accum, const int* __restrict__ flagp)
{
  const bool isbf = *flagp != 0;
  __shared__ float As[16][68];
  __shared__ float Ws[16][68];
  const int bm = blockIdx.y * 64, bn = blockIdx.x * 64;
  const int tx = threadIdx.x, ty = threadIdx.y;
  const int tid = ty * 16 + tx;
  float acc[4][4] = {};
  for (int k0 = 0; k0 < K; k0 += 16) {
#pragma unroll
    for (int i = 0; i < 4; ++i) {
      int idx = tid + i * 256;
      int m  = idx >> 4, k = idx & 15;
      int gm = bm + m;
      As[k][m] = (gm < M) ? A[(size_t)gm * K + k0 + k] : 0.f;
      int kk = idx >> 6, n = idx & 63;
      int gn = bn + n;
      Ws[kk][n] = (gn < N) ? ldin(W, woff + (size_t)(k0 + kk) * N + gn, isbf) : 0.f;
    }
    __syncthreads();
#pragma unroll
    for (int k = 0; k < 16; ++k) {
      float4 a4 = *reinterpret_cast<const float4*>(&As[k][ty * 4]);
      float4 w4 = *reinterpret_cast<const float4*>(&Ws[k][tx * 4]);
      float a[4] = {a4.x, a4.y, a4.z, a4.w};
      float w[4] = {w4.x, w4.y, w4.z, w4.w};
#pragma unroll
      for (int i = 0; i < 4; ++i)
#pragma unroll
        for (int j = 0; j < 4; ++j)
          acc[i][j] = fmaf(a[i], w[j], acc[i][j]);
    }
    __syncthreads();
  }
#pragma unroll
  for (int i = 0; i < 4; ++i) {
    int gm = bm + ty * 4 + i;
    if (gm >= M) continue;
#pragma unroll
    for (int j = 0; j < 4; ++j) {
      int gn = bn + tx * 4 + j;
      if (gn >= N) continue;
      float v = acc[i][j];
      if (bias) v += ldin(bias, boff + gn, isbf);
      if (act == 1) v = fmaxf(v, 0.f);
      else if (act == 2) {  // gelu (tanh approx, JAX default)
        float u = 0.7978845608028654f * (v + 0.044715f * v * v * v);
        v = 0.5f * v * (1.f + tanhf(u));
      }
      size_t idx = (size_t)gm * N + gn;
      if (accum) C[idx] += v; else C[idx] = v;
    }
  }
}

// ---------------------------------------------------------------------------
// Patch extraction (im2col): images [B,3,256,256] -> XP [B*256, 768]
// col = (p1*16+p2)*3+c  maps to images[b, c, h*16+p1, w*16+p2]
// ---------------------------------------------------------------------------
__global__ void patchify_k(const void* __restrict__ img, float* __restrict__ xp,
                           const int* __restrict__ flagp) {
  const bool isbf = *flagp != 0;
  int i = blockIdx.x * 256 + threadIdx.x;
  if (i >= NB * HWT * 768) return;
  int col = i % 768, row = i / 768;
  int c = col % 3, p2 = (col / 3) & 15, p1 = col / 48;
  int w = row & 15, h = (row >> 4) & 15, b = row >> 8;
  xp[i] = ldin(img, (((size_t)(b * 3 + c) * 256 + h * 16 + p1) * 256) + w * 16 + p2, isbf);
}

__global__ void addpos_k(float* __restrict__ tok, const void* __restrict__ hp,
                         const void* __restrict__ wp, const int* __restrict__ flagp) {
  const bool isbf = *flagp != 0;
  int i = blockIdx.x * 256 + threadIdx.x;
  if (i >= NB * HWT * DIM) return;
  int d = i & 511;
  int row = i >> 9;
  int w = row & 15, h = (row >> 4) & 15;
  tok[i] += ldin(hp, h * DIM + d, isbf) + ldin(wp, w * DIM + d, isbf);
}

// ---------------------------------------------------------------------------
// LayerNorm / RMSNorm over 512-dim rows, 256 threads/block, 1 block/row
// ---------------------------------------------------------------------------
__global__ void ln512_k(const float* __restrict__ X, const void* __restrict__ g,
                        const void* __restrict__ b, float* __restrict__ Y,
                        const int* __restrict__ flagp) {
  const bool isbf = *flagp != 0;
  int row = blockIdx.x, t = threadIdx.x;
  const float* x = X + (size_t)row * DIM;
  float v0 = x[t], v1 = x[t + 256];
  __shared__ float rs[256], rq[256];
  rs[t] = v0 + v1; rq[t] = v0 * v0 + v1 * v1;
  __syncthreads();
  for (int o = 128; o > 0; o >>= 1) {
    if (t < o) { rs[t] += rs[t + o]; rq[t] += rq[t + o]; }
    __syncthreads();
  }
  float mean = rs[0] * (1.f / 512.f);
  float var  = rq[0] * (1.f / 512.f) - mean * mean;
  float inv  = rsqrtf(var + 1e-5f);
  float* y = Y + (size_t)row * DIM;
  y[t]       = (v0 - mean) * inv * ldin(g, t, isbf)       + ldin(b, t, isbf);
  y[t + 256] = (v1 - mean) * inv * ldin(g, t + 256, isbf) + ldin(b, t + 256, isbf);
}

__global__ void rms512_k(const float* __restrict__ X, const void* __restrict__ g,
                         int goff, float* __restrict__ Y, const int* __restrict__ flagp) {
  const bool isbf = *flagp != 0;
  int row = blockIdx.x, t = threadIdx.x;
  const float* x = X + (size_t)row * DIM;
  float v0 = x[t], v1 = x[t + 256];
  __shared__ float rq[256];
  rq[t] = v0 * v0 + v1 * v1;
  __syncthreads();
  for (int o = 128; o > 0; o >>= 1) {
    if (t < o) rq[t] += rq[t + o];
    __syncthreads();
  }
  float nrm = sqrtf(rq[0]);
  float sc = 22.62741699796952f / fmaxf(nrm, 1e-12f);  // sqrt(512)/max(n,1e-12)
  float* y = Y + (size_t)row * DIM;
  y[t]       = v0 * sc * ldin(g, goff + t, isbf);
  y[t + 256] = v1 * sc * ldin(g, goff + t + 256, isbf);
}

// ---------------------------------------------------------------------------
// Slot attention pieces
// ---------------------------------------------------------------------------
__global__ void slots_init_k(const void* __restrict__ mu, const void* __restrict__ ls,
                             const void* __restrict__ noise, float* __restrict__ slots,
                             const int* __restrict__ flagp) {
  const bool isbf = *flagp != 0;
  int i = blockIdx.x * 256 + threadIdx.x;
  if (i >= NB * NSL * DIM) return;
  int d = i & 511;
  slots[i] = ldin(mu, d, isbf) + expf(ldin(ls, d, isbf)) * ldin(noise, i, isbf);
}

// dots[b,h,i,j] = 0.125 * sum_d q[b,i,h*64+d] * k[b,j,h*64+d]
__global__ void slot_dots_k(const float* __restrict__ q, const float* __restrict__ k,
                            float* __restrict__ dots) {
  int blk = blockIdx.x;                 // b*200 + h*50 + i
  int i = blk % 50, h = (blk / 50) & 3, b = blk / 200;
  int j = threadIdx.x;
  __shared__ float qs[64];
  if (threadIdx.x < 64) qs[threadIdx.x] = q[((size_t)(b * 50 + i)) * 256 + h * 64 + threadIdx.x];
  __syncthreads();
  const float* kr = k + ((size_t)(b * 256 + j)) * 256 + h * 64;
  float s = 0.f;
#pragma unroll 8
  for (int d = 0; d < 64; ++d) s = fmaf(qs[d], kr[d], s);
  dots[(((size_t)(b * 4 + h) * 50) + i) * 256 + j] = s * 0.125f;
}

// softmax over slots (i) for each (b,h,j); 4096 threads total
__global__ void softmax_slots_k(float* __restrict__ dots) {
  int idx = blockIdx.x * 256 + threadIdx.x;
  if (idx >= 4096) return;
  int j = idx & 255, h = (idx >> 8) & 3, b = idx >> 10;
  float* base = dots + ((size_t)(b * 4 + h) * 50) * 256 + j;
  float m = -1e30f;
  for (int i = 0; i < 50; ++i) m = fmaxf(m, base[i * 256]);
  float s = 0.f;
  for (int i = 0; i < 50; ++i) { float e = expf(base[i * 256] - m); base[i * 256] = e; s += e; }
  float inv = 1.f / s;
  for (int i = 0; i < 50; ++i) base[i * 256] *= inv;
}

// attn = (attn + 1e-8) / sum_j(attn + 1e-8); one block per (b,h,i)
__global__ void renorm_attn_k(float* __restrict__ attn) {
  int t = threadIdx.x;
  float* row = attn + (size_t)blockIdx.x * 256;
  float v = row[t] + 1e-8f;
  __shared__ float rs[256];
  rs[t] = v;
  __syncthreads();
  for (int o = 128; o > 0; o >>= 1) {
    if (t < o) rs[t] += rs[t + o];
    __syncthreads();
  }
  row[t] = v / rs[0];
}

// upd[b,i,h*64+d] = sum_j attn[b,h,i,j] * v[b,j,h*64+d]; block per (b,i), 256 thr
__global__ void slot_upd_k(const float* __restrict__ attn, const float* __restrict__ v,
                           float* __restrict__ upd) {
  int bi = blockIdx.x;        // b*50+i
  int b = bi / 50, i = bi % 50;
  int t = threadIdx.x, h = t >> 6;
  const float* arow = attn + ((size_t)((b * 4 + h) * 50) + i) * 256;
  float s = 0.f;
  for (int j = 0; j < 256; ++j) s = fmaf(arow[j], v[((size_t)(b * 256 + j)) * 256 + t], s);
  upd[(size_t)bi * 256 + t] = s;
}

__global__ void gru_k(const float* __restrict__ gx, const float* __restrict__ gh,
                      const float* __restrict__ prev, float* __restrict__ slots) {
  int i = blockIdx.x * 256 + threadIdx.x;
  if (i >= NB * NSL * DIM) return;
  int row = i >> 9, d = i & 511;
  size_t b3 = (size_t)row * 1536;
  float xr = gx[b3 + d], xz = gx[b3 + 512 + d], xn = gx[b3 + 1024 + d];
  float hr = gh[b3 + d], hz = gh[b3 + 512 + d], hn = gh[b3 + 1024 + d];
  float r = 1.f / (1.f + expf(-(xr + hr)));
  float z = 1.f / (1.f + expf(-(xz + hz)));
  float n = tanhf(xn + r * hn);
  slots[i] = (1.f - z) * n + z * prev[i];
}

// ---------------------------------------------------------------------------
// Rel-pos bias MLP: 2 -> 128 (silu) -> 128 (silu) -> 8
// ---------------------------------------------------------------------------
__device__ __forceinline__ void rp_mlp(
    float r0, float r1, int t, bool isbf,
    const void* __restrict__ w1, const void* __restrict__ b1,
    const void* __restrict__ w2, const void* __restrict__ b2,
    const void* __restrict__ w3, const void* __restrict__ b3,
    float* h1, float* h2, float* out, int ostride)
{
  float a = fmaf(r0, ldin(w1, t, isbf), fmaf(r1, ldin(w1, 128 + t, isbf), ldin(b1, t, isbf)));
  h1[t] = a / (1.f + expf(-a));
  __syncthreads();
  float s = ldin(b2, t, isbf);
#pragma unroll 4
  for (int k = 0; k < 128; ++k) s = fmaf(h1[k], ldin(w2, k * 128 + t, isbf), s);
  h2[t] = s / (1.f + expf(-s));
  __syncthreads();
  if (t < 8) {
    float o = ldin(b3, t, isbf);
#pragma unroll 4
    for (int k = 0; k < 128; ++k) o = fmaf(h2[k], ldin(w3, k * 8 + t, isbf), o);
    out[t * ostride] = o;
  }
}

__global__ void build_coords_k(const float* __restrict__ sc, float* __restrict__ coords) {
  int i = blockIdx.x * 256 + threadIdx.x;
  if (i >= NB * NT) return;
  int b = i / NT, n = i % NT;
  float cx, cy;
  if (n < NSL) { cx = sc[(b * NSL + n) * 2]; cy = sc[(b * NSL + n) * 2 + 1]; }
  else { int t = n - NSL; cx = (float)(t >> 4); cy = (float)(t & 15); }
  coords[i * 2] = cx; coords[i * 2 + 1] = cy;
}

// grid-grid pairs depend only on (di,dj) in [-15,15]^2 -> 961-entry table
__global__ void relpos_table_k(const void* w1, const void* b1, const void* w2,
                               const void* b2, const void* w3, const void* b3,
                               float* __restrict__ tab, const int* __restrict__ flagp) {
  const bool isbf = *flagp != 0;
  int blk = blockIdx.x;  // 961
  float r0 = (float)(blk / 31 - 15), r1 = (float)(blk % 31 - 15);
  __shared__ float h1[128], h2[128];
  rp_mlp(r0, r1, threadIdx.x, isbf, w1, b1, w2, b2, w3, b3, h1, h2, tab + blk * 8, 1);
}

__global__ void bias_fill_k(const float* __restrict__ tab, float* __restrict__ bias) {
  int i = blockIdx.x * 256 + threadIdx.x;
  if (i >= NB * NH * HWT * HWT) return;
  int jj = i & 255, ii = (i >> 8) & 255, h = (i >> 16) & 7, b = i >> 19;
  int di = (ii >> 4) - (jj >> 4) + 15;
  int dj = (ii & 15) - (jj & 15) + 15;
  bias[(((size_t)(b * NH + h) * NT) + NSL + ii) * NT + NSL + jj] = tab[(di * 31 + dj) * 8 + h];
}

// brute-force MLP for pairs with i<NSL or j<NSL (28100 per batch)
__global__ void relpos_mixed_k(const float* __restrict__ coords,
                               const void* w1, const void* b1, const void* w2,
                               const void* b2, const void* w3, const void* b3,
                               float* __restrict__ bias, const int* __restrict__ flagp) {
  const bool isbf = *flagp != 0;
  int q = blockIdx.x % 28100, b = blockIdx.x / 28100;
  int i, j;
  if (q < 15300) { i = q / NT; j = q % NT; }
  else { int r = q - 15300; i = NSL + r / NSL; j = r % NSL; }
  float r0 = coords[(b * NT + i) * 2]     - coords[(b * NT + j) * 2];
  float r1 = coords[(b * NT + i) * 2 + 1] - coords[(b * NT + j) * 2 + 1];
  __shared__ float h1[128], h2[128];
  rp_mlp(r0, r1, threadIdx.x, isbf, w1, b1, w2, b2, w3, b3,
         h1, h2, bias + ((size_t)(b * NH) * NT + i) * NT + j, NT * NT);
}

// ---------------------------------------------------------------------------
// Transformer pieces
// ---------------------------------------------------------------------------
__global__ void build_x_k(const float* __restrict__ slots, const float* __restrict__ tok,
                          float* __restrict__ x) {
  int i = blockIdx.x * 256 + threadIdx.x;
  if (i >= NB * NT * DIM) return;
  int d = i & 511, n = (i >> 9) % NT, b = i / (NT * DIM);
  x[i] = (n < NSL) ? slots[((size_t)(b * NSL + n)) * DIM + d]
                   : tok[((size_t)(b * HWT + (n - NSL))) * DIM + d];
}

// sim[b,h,i,j] = 0.125*q·k + bias; block per (b,h,i)
__global__ void trans_sim_k(const float* __restrict__ qh, const float* __restrict__ kh,
                            const float* __restrict__ bias, float* __restrict__ sim) {
  int blk = blockIdx.x;
  int i = blk % NT, h = (blk / NT) & 7, b = blk / (NT * NH);
  __shared__ float qs[64];
  if (threadIdx.x < 64) qs[threadIdx.x] = qh[((size_t)(b * NT + i)) * DIM + h * 64 + threadIdx.x];
  __syncthreads();
  for (int j = threadIdx.x; j < NT; j += 256) {
    const float* kr = kh + ((size_t)(b * NT + j)) * DIM + h * 64;
    float s = 0.f;
#pragma unroll 8
    for (int d = 0; d < 64; ++d) s = fmaf(qs[d], kr[d], s);
    size_t idx = (((size_t)(b * NH + h) * NT) + i) * NT + j;
    sim[idx] = s * 0.125f + bias[idx];
  }
}

// row softmax over length L<=512, 256 threads, 1 block/row
__global__ void softmax_rows_k(float* __restrict__ X, int L) {
  float* row = X + (size_t)blockIdx.x * L;
  int t = threadIdx.x;
  float v0 = (t < L) ? row[t] : -1e30f;
  float v1 = (t + 256 < L) ? row[t + 256] : -1e30f;
  __shared__ float rb[256];
  rb[t] = fmaxf(v0, v1);
  __syncthreads();
  for (int o = 128; o > 0; o >>= 1) {
    if (t < o) rb[t] = fmaxf(rb[t], rb[t + o]);
    __syncthreads();
  }
  float m = rb[0];
  __syncthreads();
  float e0 = (t < L) ? expf(v0 - m) : 0.f;
  float e1 = (t + 256 < L) ? expf(v1 - m) : 0.f;
  rb[t] = e0 + e1;
  __syncthreads();
  for (int o = 128; o > 0; o >>= 1) {
    if (t < o) rb[t] += rb[t + o];
    __syncthreads();
  }
  float inv = 1.f / rb[0];
  if (t < L) row[t] = e0 * inv;
  if (t + 256 < L) row[t + 256] = e1 * inv;
}

// o[b,i,h*64+d] = sum_j a[b,h,i,j] * vh[b,j,h*64+d]; block per (b,i), 512 thr
__global__ __launch_bounds__(512) void trans_av_k(const float* __restrict__ a,
                                                  const float* __restrict__ vh,
                                                  float* __restrict__ o) {
  int bi = blockIdx.x;
  int b = bi / NT, i = bi % NT;
  int t = threadIdx.x, h = t >> 6;
  const float* arow = a + (((size_t)(b * NH + h) * NT) + i) * NT;
  float s = 0.f;
  for (int j = 0; j < NT; ++j) s = fmaf(arow[j], vh[((size_t)(b * NT + j)) * DIM + t], s);
  o[(size_t)bi * DIM + t] = s;
}

__global__ void write_out_k(const float* __restrict__ tmp, void* __restrict__ out,
                            const int* __restrict__ flagp) {
  const bool isbf = *flagp != 0;
  int i = blockIdx.x * 256 + threadIdx.x;
  if (i >= NB * HWT * DIM) return;
  int d = i & 511, tt = (i >> 9) & 255, b = i / (HWT * DIM);
  float v = tmp[((size_t)(b * NT + NSL + tt)) * DIM + d];
  if (isbf) ((bf16*)out)[i] = __float2bfloat16(v);
  else      ((float*)out)[i] = v;
}

// ---------------------------------------------------------------------------
extern "C" void kernel_launch(void* const* d_in, const int* in_sizes, int n_in,
                              void* d_out, int out_size, void* d_ws, size_t ws_size,
                              hipStream_t stream) {
  const void* images        = d_in[0];
  const void* slot_noise    = d_in[1];
  const void* patch_w       = d_in[2];
  const void* patch_b       = d_in[3];
  const void* hpos          = d_in[4];
  const void* wpos          = d_in[5];
  const void* rp_w1         = d_in[6];
  const void* rp_b1         = d_in[7];
  const void* rp_w2         = d_in[8];
  const void* rp_b2         = d_in[9];
  const void* rp_w3         = d_in[10];
  const void* rp_b3         = d_in[11];
  const void* slots_mu      = d_in[12];
  const void* slots_logsig  = d_in[13];
  const void* sa_ln_in_g    = d_in[14];
  const void* sa_ln_in_b    = d_in[15];
  const void* sa_ln_sl_g    = d_in[16];
  const void* sa_ln_sl_b    = d_in[17];
  const void* sa_wq         = d_in[18];
  const void* sa_bq         = d_in[19];
  const void* sa_wk         = d_in[20];
  const void* sa_bk         = d_in[21];
  const void* sa_wv         = d_in[22];
  const void* sa_bv         = d_in[23];
  const void* sa_wo         = d_in[24];
  const void* sa_bo         = d_in[25];
  const void* gru_wih       = d_in[26];
  const void* gru_whh       = d_in[27];
  const void* gru_bih       = d_in[28];
  const void* gru_bhh       = d_in[29];
  const void* sa_ln_ff_g    = d_in[30];
  const void* sa_ln_ff_b    = d_in[31];
  const void* sa_mlp_w1     = d_in[32];
  const void* sa_mlp_b1     = d_in[33];
  const void* sa_mlp_w2     = d_in[34];
  const void* sa_mlp_b2     = d_in[35];
  const void* s2c_w         = d_in[36];
  const void* s2c_b         = d_in[37];
  const void* attn_g        = d_in[38];
  const void* wq            = d_in[39];
  const void* wk            = d_in[40];
  const void* wv            = d_in[41];
  const void* wo            = d_in[42];
  const void* ff_g          = d_in[43];
  const void* ff_w1         = d_in[44];
  const void* ff_b1         = d_in[45];
  const void* ff_w2         = d_in[46];
  const void* ff_b2         = d_in[47];
  const void* final_g       = d_in[48];
  const void* pred_w        = d_in[49];
  const void* pred_b        = d_in[50];

  float* ws = (float*)d_ws;
  int* FLAG = (int*)ws;
  size_t off = 16;
  auto alloc = [&](size_t n) { float* p = ws + off; off += n; return p; };
  float* XP    = alloc((size_t)NB * HWT * 768);
  float* TOK   = alloc((size_t)NB * HWT * DIM);
  float* INP   = alloc((size_t)NB * HWT * DIM);
  float* KB    = alloc((size_t)NB * HWT * 256);
  float* VB    = alloc((size_t)NB * HWT * 256);
  float* SLOTS = alloc((size_t)NB * NSL * DIM);
  float* PREV  = alloc((size_t)NB * NSL * DIM);
  float* SLN   = alloc((size_t)NB * NSL * DIM);
  float* QB    = alloc((size_t)NB * NSL * 256);
  float* ATT   = alloc((size_t)NB * 4 * NSL * HWT);
  float* UPD   = alloc((size_t)NB * NSL * 256);
  float* UPDP  = alloc((size_t)NB * NSL * DIM);
  float* GX    = alloc((size_t)NB * NSL * 1536);
  float* GH    = alloc((size_t)NB * NSL * 1536);
  float* HIDS  = alloc((size_t)NB * NSL * DIM);
  float* SC    = alloc((size_t)NB * NSL * 2);
  float* CRD   = alloc((size_t)NB * NT * 2);
  float* TAB   = alloc((size_t)961 * 8);
  float* BIAS  = alloc((size_t)NB * NH * NT * NT);
  float* X     = alloc((size_t)NB * NT * DIM);
  float* HB    = alloc((size_t)NB * NT * DIM);
  float* QH    = alloc((size_t)NB * NT * DIM);
  float* KH    = alloc((size_t)NB * NT * DIM);
  float* VH    = alloc((size_t)NB * NT * DIM);
  float* SIM   = alloc((size_t)NB * NH * NT * NT);
  float* OB    = alloc((size_t)NB * NT * DIM);
  float* FFH   = alloc((size_t)NB * NT * FF);
  float* OUTT  = alloc((size_t)NB * NT * DIM);
  (void)ws_size; (void)in_sizes; (void)n_in; (void)out_size;

#define GEMM(A_, W_, WOFF_, BIAS_, BOFF_, C_, M_, N_, K_, ACT_, ACC_) \
  gemm_k<<<dim3(CDIV((N_),64), CDIV((M_),64)), dim3(16,16), 0, stream>>>( \
      A_, W_, (size_t)(WOFF_), BIAS_, (size_t)(BOFF_), C_, M_, N_, K_, ACT_, ACC_, FLAG)

  const int MROW = NB * NT;   // 1224

  // ---- dtype detection ----
  detect_k<<<1, 256, 0, stream>>>(images, FLAG);

  // ---- patch embed ----
  patchify_k<<<CDIV(NB*HWT*768, 256), 256, 0, stream>>>(images, XP, FLAG);
  GEMM(XP, patch_w, 0, patch_b, 0, TOK, NB*HWT, DIM, 768, 0, 0);
  addpos_k<<<CDIV(NB*HWT*DIM, 256), 256, 0, stream>>>(TOK, hpos, wpos, FLAG);

  // ---- slot attention: k, v ----
  ln512_k<<<NB*HWT, 256, 0, stream>>>(TOK, sa_ln_in_g, sa_ln_in_b, INP, FLAG);
  GEMM(INP, sa_wk, 0, sa_bk, 0, KB, NB*HWT, 256, DIM, 0, 0);
  GEMM(INP, sa_wv, 0, sa_bv, 0, VB, NB*HWT, 256, DIM, 0, 0);
  slots_init_k<<<CDIV(NB*NSL*DIM, 256), 256, 0, stream>>>(slots_mu, slots_logsig, slot_noise, SLOTS, FLAG);

  for (int it = 0; it < 3; ++it) {
    hipMemcpyAsync(PREV, SLOTS, (size_t)NB*NSL*DIM*sizeof(float),
                   hipMemcpyDeviceToDevice, stream);
    ln512_k<<<NB*NSL, 256, 0, stream>>>(SLOTS, sa_ln_sl_g, sa_ln_sl_b, SLN, FLAG);
    GEMM(SLN, sa_wq, 0, sa_bq, 0, QB, NB*NSL, 256, DIM, 0, 0);
    slot_dots_k<<<NB*4*NSL, 256, 0, stream>>>(QB, KB, ATT);
    softmax_slots_k<<<16, 256, 0, stream>>>(ATT);
    renorm_attn_k<<<NB*4*NSL, 256, 0, stream>>>(ATT);
    slot_upd_k<<<NB*NSL, 256, 0, stream>>>(ATT, VB, UPD);
    GEMM(UPD, sa_wo, 0, sa_bo, 0, UPDP, NB*NSL, DIM, 256, 0, 0);
    GEMM(UPDP, gru_wih, 0, gru_bih, 0, GX, NB*NSL, 1536, DIM, 0, 0);
    GEMM(PREV, gru_whh, 0, gru_bhh, 0, GH, NB*NSL, 1536, DIM, 0, 0);
    gru_k<<<CDIV(NB*NSL*DIM, 256), 256, 0, stream>>>(GX, GH, PREV, SLOTS);
    ln512_k<<<NB*NSL, 256, 0, stream>>>(SLOTS, sa_ln_ff_g, sa_ln_ff_b, SLN, FLAG);
    GEMM(SLN, sa_mlp_w1, 0, sa_mlp_b1, 0, HIDS, NB*NSL, DIM, DIM, 1, 0);
    GEMM(HIDS, sa_mlp_w2, 0, sa_mlp_b2, 0, SLOTS, NB*NSL, DIM, DIM, 0, 1);
  }

  // ---- rel-pos bias ----
  GEMM(SLOTS, s2c_w, 0, s2c_b, 0, SC, NB*NSL, 2, DIM, 0, 0);
  build_coords_k<<<CDIV(NB*NT, 256), 256, 0, stream>>>(SC, CRD);
  relpos_table_k<<<961, 128, 0, stream>>>(rp_w1, rp_b1, rp_w2, rp_b2, rp_w3, rp_b3, TAB, FLAG);
  bias_fill_k<<<CDIV(NB*NH*HWT*HWT, 256), 256, 0, stream>>>(TAB, BIAS);
  relpos_mixed_k<<<NB*28100, 128, 0, stream>>>(CRD, rp_w1, rp_b1, rp_w2, rp_b2, rp_w3, rp_b3, BIAS, FLAG);

  // ---- transformer ----
  build_x_k<<<CDIV(NB*NT*DIM, 256), 256, 0, stream>>>(SLOTS, TOK, X);
  for (int l = 0; l < 6; ++l) {
    size_t woff = (size_t)l * DIM * DIM;
    rms512_k<<<MROW, 256, 0, stream>>>(X, attn_g, l * DIM, HB, FLAG);
    GEMM(HB, wq, woff, (const void*)nullptr, 0, QH, MROW, DIM, DIM, 0, 0);
    GEMM(HB, wk, woff, (const void*)nullptr, 0, KH, MROW, DIM, DIM, 0, 0);
    GEMM(HB, wv, woff, (const void*)nullptr, 0, VH, MROW, DIM, DIM, 0, 0);
    trans_sim_k<<<NB*NH*NT, 256, 0, stream>>>(QH, KH, BIAS, SIM);
    softmax_rows_k<<<NB*NH*NT, 256, 0, stream>>>(SIM, NT);
    trans_av_k<<<NB*NT, 512, 0, stream>>>(SIM, VH, OB);
    GEMM(OB, wo, woff, (const void*)nullptr, 0, X, MROW, DIM, DIM, 0, 1);
    rms512_k<<<MROW, 256, 0, stream>>>(X, ff_g, l * DIM, HB, FLAG);
    GEMM(HB, ff_w1, (size_t)l * DIM * FF, ff_b1, (size_t)l * FF, FFH, MROW, FF, DIM, 2, 0);
    GEMM(FFH, ff_w2, (size_t)l * FF * DIM, ff_b2, (size_t)l * DIM, X, MROW, DIM, FF, 0, 1);
  }

  // ---- head ----
  rms512_k<<<MROW, 256, 0, stream>>>(X, final_g, 0, HB, FLAG);
  GEMM(HB, pred_w, 0, pred_b, 0, OUTT, MROW, DIM, DIM, 0, 0);
  write_out_k<<<CDIV(NB*HWT*DIM, 256), 256, 0, stream>>>(OUTT, d_out, FLAG);

#undef GEMM
}

// Round 3
// 4293.443 us; speedup vs baseline: 1.8423x; 1.8423x over previous
//
#include <hip/hip_runtime.h>
#include <hip/hip_bf16.h>

typedef __hip_bfloat16 bf16;
typedef short short8v __attribute__((ext_vector_type(8)));
typedef float float4v __attribute__((ext_vector_type(4)));

static __device__ __forceinline__ float b2f(bf16 x){ return __bfloat162float(x); }

// dtype-flexible input load: isbf ? bf16[i] : f32[i]
static __device__ __forceinline__ float ldin(const void* p, size_t i, bool isbf) {
  return isbf ? b2f(((const bf16*)p)[i]) : ((const float*)p)[i];
}

static __device__ __forceinline__ unsigned short f2bu(float f) {
  bf16 h = __float2bfloat16(f);
  return *reinterpret_cast<unsigned short*>(&h);
}

#define CDIV(a,b) (((a)+(b)-1)/(b))

// Model constants
#define NB   4
#define NSL  50
#define HWT  256
#define NT   306     // NSL + HWT
#define DIM  512
#define NH   8
#define FF   2048
#define RPP  28100   // mixed rel-pos pairs per batch

// ---------------------------------------------------------------------------
// dtype detector: if any of the first 256 u16 words of `images` has bf16
// exponent >= 0x88 (|v|>=512 or NaN/Inf) the data cannot be bf16 N(0,1)
// image data -> it is f32 (junk mantissa halves). flag=1 means bf16.
// ---------------------------------------------------------------------------
__global__ void detect_k(const void* p, int* flag) {
  const unsigned short* u = (const unsigned short*)p;
  int t = threadIdx.x;
  int e = (u[t] >> 7) & 0xFF;
  __shared__ int anybad;
  if (t == 0) anybad = 0;
  __syncthreads();
  if (e >= 0x88) atomicOr(&anybad, 1);
  __syncthreads();
  if (t == 0) *flag = anybad ? 0 : 1;
}

// ---------------------------------------------------------------------------
// MFMA bf16 GEMM: C[M,N] = act(A[M,K] @ W[woff..][K,N] + bias[boff..])
// A: f32 workspace (converted to bf16 in staging); W: bf16 or f32 (flag).
// Requires N % 64 == 0, K % 32 == 0. 64x64 macro-tile, BK=32, 256 thr = 4 waves,
// each wave one 32x32 quadrant via 2x2 of mfma_f32_16x16x32_bf16.
// LDS: As[m][k] (k contig), Bs[n][k] (k contig), rows padded to 40 shorts.
// act: 0 none, 1 relu, 2 gelu(tanh). accum: C += result.
// ---------------------------------------------------------------------------
#define LDT 40
__global__ __launch_bounds__(256) void gemm_mfma(
    const float* __restrict__ A, const void* __restrict__ W, size_t woff,
    const void* __restrict__ bias, size_t boff, float* __restrict__ C,
    int M, int N, int K, int act, int accum, const int* __restrict__ flagp)
{
  const bool isbf = *flagp != 0;
  __shared__ unsigned short As[64 * LDT];
  __shared__ unsigned short Bs[64 * LDT];
  const int tid  = threadIdx.x;
  const int lane = tid & 63, wave = tid >> 6;
  const int quad = lane >> 4, ti = lane & 15;
  const int wm = (wave & 1) * 32, wn = (wave >> 1) * 32;
  const int bm = blockIdx.y * 64, bn = blockIdx.x * 64;
  // staging roles
  const int arow = tid >> 2, ach = (tid & 3) * 8;     // A: row 0..63, k-chunk
  const int bk = tid & 31, bch = (tid >> 5) * 8;      // B: k 0..31, n-chunk

  float4v acc00 = {0,0,0,0}, acc01 = {0,0,0,0}, acc10 = {0,0,0,0}, acc11 = {0,0,0,0};

  for (int k0 = 0; k0 < K; k0 += 32) {
    // ---- stage A tile (64 x 32), f32 -> bf16 ----
    {
      int gm = bm + arow;
      float v[8];
      if (gm < M) {
        const float* ap = A + (size_t)gm * K + k0 + ach;
        float4 x = *reinterpret_cast<const float4*>(ap);
        float4 y = *reinterpret_cast<const float4*>(ap + 4);
        v[0]=x.x; v[1]=x.y; v[2]=x.z; v[3]=x.w; v[4]=y.x; v[5]=y.y; v[6]=y.z; v[7]=y.w;
      } else {
#pragma unroll
        for (int i = 0; i < 8; ++i) v[i] = 0.f;
      }
      unsigned short h[8];
#pragma unroll
      for (int i = 0; i < 8; ++i) h[i] = f2bu(v[i]);
      *reinterpret_cast<short8v*>(&As[arow * LDT + ach]) = *reinterpret_cast<short8v*>(h);
    }
    // ---- stage B tile (32 x 64) transposed -> Bs[n][k] ----
    {
      size_t base = woff + (size_t)(k0 + bk) * N + bn + bch;
      unsigned short h[8];
      if (isbf) {
        const ushort4* wp = reinterpret_cast<const ushort4*>((const unsigned short*)W + base);
        ushort4 u0 = wp[0], u1 = wp[1];
        h[0]=u0.x; h[1]=u0.y; h[2]=u0.z; h[3]=u0.w; h[4]=u1.x; h[5]=u1.y; h[6]=u1.z; h[7]=u1.w;
      } else {
        const float4* wp = reinterpret_cast<const float4*>((const float*)W + base);
        float4 f0 = wp[0], f1 = wp[1];
        h[0]=f2bu(f0.x); h[1]=f2bu(f0.y); h[2]=f2bu(f0.z); h[3]=f2bu(f0.w);
        h[4]=f2bu(f1.x); h[5]=f2bu(f1.y); h[6]=f2bu(f1.z); h[7]=f2bu(f1.w);
      }
#pragma unroll
      for (int i = 0; i < 8; ++i) Bs[(bch + i) * LDT + bk] = h[i];
    }
    __syncthreads();
    // ---- fragments + mfma ----
    short8v a0 = *reinterpret_cast<const short8v*>(&As[(wm + ti)      * LDT + quad * 8]);
    short8v a1 = *reinterpret_cast<const short8v*>(&As[(wm + 16 + ti) * LDT + quad * 8]);
    short8v b0 = *reinterpret_cast<const short8v*>(&Bs[(wn + ti)      * LDT + quad * 8]);
    short8v b1 = *reinterpret_cast<const short8v*>(&Bs[(wn + 16 + ti) * LDT + quad * 8]);
    acc00 = __builtin_amdgcn_mfma_f32_16x16x32_bf16(a0, b0, acc00, 0, 0, 0);
    acc01 = __builtin_amdgcn_mfma_f32_16x16x32_bf16(a0, b1, acc01, 0, 0, 0);
    acc10 = __builtin_amdgcn_mfma_f32_16x16x32_bf16(a1, b0, acc10, 0, 0, 0);
    acc11 = __builtin_amdgcn_mfma_f32_16x16x32_bf16(a1, b1, acc11, 0, 0, 0);
    __syncthreads();
  }

  // ---- epilogue: C layout col=lane&15, row=quad*4+r ----
  float4v accs[2][2] = {{acc00, acc01}, {acc10, acc11}};
#pragma unroll
  for (int mi = 0; mi < 2; ++mi) {
#pragma unroll
    for (int ni = 0; ni < 2; ++ni) {
      int row0 = bm + wm + mi * 16 + quad * 4;
      int col  = bn + wn + ni * 16 + ti;
      float bv = bias ? ldin(bias, boff + col, isbf) : 0.f;
#pragma unroll
      for (int r = 0; r < 4; ++r) {
        int row = row0 + r;
        if (row >= M) continue;
        float v = accs[mi][ni][r] + bv;
        if (act == 1) v = fmaxf(v, 0.f);
        else if (act == 2) {
          float u = 0.7978845608028654f * (v + 0.044715f * v * v * v);
          v = 0.5f * v * (1.f + tanhf(u));
        }
        size_t idx = (size_t)row * N + col;
        if (accum) C[idx] += v; else C[idx] = v;
      }
    }
  }
}

// ---------------------------------------------------------------------------
// f32 fallback GEMM (small M, slot attention path). K % 16 == 0.
// ---------------------------------------------------------------------------
__global__ __launch_bounds__(256) void gemm_k(
    const float* __restrict__ A, const void* __restrict__ W, size_t woff,
    const void* __restrict__ bias, size_t boff, float* __restrict__ C,
    int M, int N, int K, int act, int accum, const int* __restrict__ flagp)
{
  const bool isbf = *flagp != 0;
  __shared__ float As[16][68];
  __shared__ float Ws[16][68];
  const int bm = blockIdx.y * 64, bn = blockIdx.x * 64;
  const int tx = threadIdx.x, ty = threadIdx.y;
  const int tid = ty * 16 + tx;
  float acc[4][4] = {};
  for (int k0 = 0; k0 < K; k0 += 16) {
#pragma unroll
    for (int i = 0; i < 4; ++i) {
      int idx = tid + i * 256;
      int m  = idx >> 4, k = idx & 15;
      int gm = bm + m;
      As[k][m] = (gm < M) ? A[(size_t)gm * K + k0 + k] : 0.f;
      int kk = idx >> 6, n = idx & 63;
      int gn = bn + n;
      Ws[kk][n] = (gn < N) ? ldin(W, woff + (size_t)(k0 + kk) * N + gn, isbf) : 0.f;
    }
    __syncthreads();
#pragma unroll
    for (int k = 0; k < 16; ++k) {
      float4 a4 = *reinterpret_cast<const float4*>(&As[k][ty * 4]);
      float4 w4 = *reinterpret_cast<const float4*>(&Ws[k][tx * 4]);
      float a[4] = {a4.x, a4.y, a4.z, a4.w};
      float w[4] = {w4.x, w4.y, w4.z, w4.w};
#pragma unroll
      for (int i = 0; i < 4; ++i)
#pragma unroll
        for (int j = 0; j < 4; ++j)
          acc[i][j] = fmaf(a[i], w[j], acc[i][j]);
    }
    __syncthreads();
  }
#pragma unroll
  for (int i = 0; i < 4; ++i) {
    int gm = bm + ty * 4 + i;
    if (gm >= M) continue;
#pragma unroll
    for (int j = 0; j < 4; ++j) {
      int gn = bn + tx * 4 + j;
      if (gn >= N) continue;
      float v = acc[i][j];
      if (bias) v += ldin(bias, boff + gn, isbf);
      if (act == 1) v = fmaxf(v, 0.f);
      else if (act == 2) {
        float u = 0.7978845608028654f * (v + 0.044715f * v * v * v);
        v = 0.5f * v * (1.f + tanhf(u));
      }
      size_t idx = (size_t)gm * N + gn;
      if (accum) C[idx] += v; else C[idx] = v;
    }
  }
}

// ---------------------------------------------------------------------------
// Patch extraction (im2col): images [B,3,256,256] -> XP [B*256, 768]
// ---------------------------------------------------------------------------
__global__ void patchify_k(const void* __restrict__ img, float* __restrict__ xp,
                           const int* __restrict__ flagp) {
  const bool isbf = *flagp != 0;
  int i = blockIdx.x * 256 + threadIdx.x;
  if (i >= NB * HWT * 768) return;
  int col = i % 768, row = i / 768;
  int c = col % 3, p2 = (col / 3) & 15, p1 = col / 48;
  int w = row & 15, h = (row >> 4) & 15, b = row >> 8;
  xp[i] = ldin(img, (((size_t)(b * 3 + c) * 256 + h * 16 + p1) * 256) + w * 16 + p2, isbf);
}

__global__ void addpos_k(float* __restrict__ tok, const void* __restrict__ hp,
                         const void* __restrict__ wp, const int* __restrict__ flagp) {
  const bool isbf = *flagp != 0;
  int i = blockIdx.x * 256 + threadIdx.x;
  if (i >= NB * HWT * DIM) return;
  int d = i & 511;
  int row = i >> 9;
  int w = row & 15, h = (row >> 4) & 15;
  tok[i] += ldin(hp, h * DIM + d, isbf) + ldin(wp, w * DIM + d, isbf);
}

// ---------------------------------------------------------------------------
// LayerNorm / RMSNorm over 512-dim rows
// ---------------------------------------------------------------------------
__global__ void ln512_k(const float* __restrict__ X, const void* __restrict__ g,
                        const void* __restrict__ b, float* __restrict__ Y,
                        const int* __restrict__ flagp) {
  const bool isbf = *flagp != 0;
  int row = blockIdx.x, t = threadIdx.x;
  const float* x = X + (size_t)row * DIM;
  float v0 = x[t], v1 = x[t + 256];
  __shared__ float rs[256], rq[256];
  rs[t] = v0 + v1; rq[t] = v0 * v0 + v1 * v1;
  __syncthreads();
  for (int o = 128; o > 0; o >>= 1) {
    if (t < o) { rs[t] += rs[t + o]; rq[t] += rq[t + o]; }
    __syncthreads();
  }
  float mean = rs[0] * (1.f / 512.f);
  float var  = rq[0] * (1.f / 512.f) - mean * mean;
  float inv  = rsqrtf(var + 1e-5f);
  float* y = Y + (size_t)row * DIM;
  y[t]       = (v0 - mean) * inv * ldin(g, t, isbf)       + ldin(b, t, isbf);
  y[t + 256] = (v1 - mean) * inv * ldin(g, t + 256, isbf) + ldin(b, t + 256, isbf);
}

__global__ void rms512_k(const float* __restrict__ X, const void* __restrict__ g,
                         int goff, float* __restrict__ Y, const int* __restrict__ flagp) {
  const bool isbf = *flagp != 0;
  int row = blockIdx.x, t = threadIdx.x;
  const float* x = X + (size_t)row * DIM;
  float v0 = x[t], v1 = x[t + 256];
  __shared__ float rq[256];
  rq[t] = v0 * v0 + v1 * v1;
  __syncthreads();
  for (int o = 128; o > 0; o >>= 1) {
    if (t < o) rq[t] += rq[t + o];
    __syncthreads();
  }
  float nrm = sqrtf(rq[0]);
  float sc = 22.62741699796952f / fmaxf(nrm, 1e-12f);
  float* y = Y + (size_t)row * DIM;
  y[t]       = v0 * sc * ldin(g, goff + t, isbf);
  y[t + 256] = v1 * sc * ldin(g, goff + t + 256, isbf);
}

// ---------------------------------------------------------------------------
// Slot attention pieces (unchanged, f32)
// ---------------------------------------------------------------------------
__global__ void slots_init_k(const void* __restrict__ mu, const void* __restrict__ ls,
                             const void* __restrict__ noise, float* __restrict__ slots,
                             const int* __restrict__ flagp) {
  const bool isbf = *flagp != 0;
  int i = blockIdx.x * 256 + threadIdx.x;
  if (i >= NB * NSL * DIM) return;
  int d = i & 511;
  slots[i] = ldin(mu, d, isbf) + expf(ldin(ls, d, isbf)) * ldin(noise, i, isbf);
}

__global__ void slot_dots_k(const float* __restrict__ q, const float* __restrict__ k,
                            float* __restrict__ dots) {
  int blk = blockIdx.x;                 // b*200 + h*50 + i
  int i = blk % 50, h = (blk / 50) & 3, b = blk / 200;
  int j = threadIdx.x;
  __shared__ float qs[64];
  if (threadIdx.x < 64) qs[threadIdx.x] = q[((size_t)(b * 50 + i)) * 256 + h * 64 + threadIdx.x];
  __syncthreads();
  const float* kr = k + ((size_t)(b * 256 + j)) * 256 + h * 64;
  float s = 0.f;
#pragma unroll 8
  for (int d = 0; d < 64; ++d) s = fmaf(qs[d], kr[d], s);
  dots[(((size_t)(b * 4 + h) * 50) + i) * 256 + j] = s * 0.125f;
}

__global__ void softmax_slots_k(float* __restrict__ dots) {
  int idx = blockIdx.x * 256 + threadIdx.x;
  if (idx >= 4096) return;
  int j = idx & 255, h = (idx >> 8) & 3, b = idx >> 10;
  float* base = dots + ((size_t)(b * 4 + h) * 50) * 256 + j;
  float m = -1e30f;
  for (int i = 0; i < 50; ++i) m = fmaxf(m, base[i * 256]);
  float s = 0.f;
  for (int i = 0; i < 50; ++i) { float e = expf(base[i * 256] - m); base[i * 256] = e; s += e; }
  float inv = 1.f / s;
  for (int i = 0; i < 50; ++i) base[i * 256] *= inv;
}

__global__ void renorm_attn_k(float* __restrict__ attn) {
  int t = threadIdx.x;
  float* row = attn + (size_t)blockIdx.x * 256;
  float v = row[t] + 1e-8f;
  __shared__ float rs[256];
  rs[t] = v;
  __syncthreads();
  for (int o = 128; o > 0; o >>= 1) {
    if (t < o) rs[t] += rs[t + o];
    __syncthreads();
  }
  row[t] = v / rs[0];
}

__global__ void slot_upd_k(const float* __restrict__ attn, const float* __restrict__ v,
                           float* __restrict__ upd) {
  int bi = blockIdx.x;        // b*50+i
  int b = bi / 50, i = bi % 50;
  int t = threadIdx.x, h = t >> 6;
  const float* arow = attn + ((size_t)((b * 4 + h) * 50) + i) * 256;
  float s = 0.f;
  for (int j = 0; j < 256; ++j) s = fmaf(arow[j], v[((size_t)(b * 256 + j)) * 256 + t], s);
  upd[(size_t)bi * 256 + t] = s;
}

__global__ void gru_k(const float* __restrict__ gx, const float* __restrict__ gh,
                      const float* __restrict__ prev, float* __restrict__ slots) {
  int i = blockIdx.x * 256 + threadIdx.x;
  if (i >= NB * NSL * DIM) return;
  int row = i >> 9, d = i & 511;
  size_t b3 = (size_t)row * 1536;
  float xr = gx[b3 + d], xz = gx[b3 + 512 + d], xn = gx[b3 + 1024 + d];
  float hr = gh[b3 + d], hz = gh[b3 + 512 + d], hn = gh[b3 + 1024 + d];
  float r = 1.f / (1.f + expf(-(xr + hr)));
  float z = 1.f / (1.f + expf(-(xz + hz)));
  float n = tanhf(xn + r * hn);
  slots[i] = (1.f - z) * n + z * prev[i];
}

// ---------------------------------------------------------------------------
// Rel-pos bias
// ---------------------------------------------------------------------------
__global__ void build_coords_k(const float* __restrict__ sc, float* __restrict__ coords) {
  int i = blockIdx.x * 256 + threadIdx.x;
  if (i >= NB * NT) return;
  int b = i / NT, n = i % NT;
  float cx, cy;
  if (n < NSL) { cx = sc[(b * NSL + n) * 2]; cy = sc[(b * NSL + n) * 2 + 1]; }
  else { int t = n - NSL; cx = (float)(t >> 4); cy = (float)(t & 15); }
  coords[i * 2] = cx; coords[i * 2 + 1] = cy;
}

// table kernel for grid-grid deltas (961 entries), 128 threads
__global__ void relpos_table_k(const void* w1, const void* b1, const void* w2,
                               const void* b2, const void* w3, const void* b3,
                               float* __restrict__ tab, const int* __restrict__ flagp) {
  const bool isbf = *flagp != 0;
  int blk = blockIdx.x;  // 961
  float r0 = (float)(blk / 31 - 15), r1 = (float)(blk % 31 - 15);
  int t = threadIdx.x;
  __shared__ float h1[128], h2[128];
  float a = fmaf(r0, ldin(w1, t, isbf), fmaf(r1, ldin(w1, 128 + t, isbf), ldin(b1, t, isbf)));
  h1[t] = a / (1.f + expf(-a));
  __syncthreads();
  float s = ldin(b2, t, isbf);
#pragma unroll 4
  for (int k = 0; k < 128; ++k) s = fmaf(h1[k], ldin(w2, k * 128 + t, isbf), s);
  h2[t] = s / (1.f + expf(-s));
  __syncthreads();
  if (t < 8) {
    float o = ldin(b3, t, isbf);
#pragma unroll 4
    for (int k = 0; k < 128; ++k) o = fmaf(h2[k], ldin(w3, k * 8 + t, isbf), o);
    tab[blk * 8 + t] = o;
  }
}

__global__ void bias_fill_k(const float* __restrict__ tab, float* __restrict__ bias) {
  int i = blockIdx.x * 256 + threadIdx.x;
  if (i >= NB * NH * HWT * HWT) return;
  int jj = i & 255, ii = (i >> 8) & 255, h = (i >> 16) & 7, b = i >> 19;
  int di = (ii >> 4) - (jj >> 4) + 15;
  int dj = (ii & 15) - (jj & 15) + 15;
  bias[(((size_t)(b * NH + h) * NT) + NSL + ii) * NT + NSL + jj] = tab[(di * 31 + dj) * 8 + h];
}

// mixed pairs: persistent blocks, w2/w3 staged in LDS, 2 pairs per iteration
__global__ __launch_bounds__(256) void relpos_mixed2_k(
    const float* __restrict__ coords,
    const void* w1, const void* b1, const void* w2,
    const void* b2, const void* w3, const void* b3,
    float* __restrict__ bias, const int* __restrict__ flagp)
{
  const bool isbf = *flagp != 0;
  __shared__ float W2s[128 * 128];
  __shared__ float W3s[128 * 8];
  __shared__ float H1[2][128], H2[2][128];
  int t = threadIdx.x;
  for (int i = t; i < 128 * 128; i += 256) W2s[i] = ldin(w2, i, isbf);
  for (int i = t; i < 128 * 8; i += 256) W3s[i] = ldin(w3, i, isbf);
  __syncthreads();
  const int sub = t >> 7, u = t & 127;
  const float w1a = ldin(w1, u, isbf), w1b = ldin(w1, 128 + u, isbf);
  const float b1v = ldin(b1, u, isbf), b2v = ldin(b2, u, isbf);
  const float b3v = (u < 8) ? ldin(b3, u, isbf) : 0.f;
  const int total = NB * RPP;
  for (int base = blockIdx.x * 2; base < total; base += gridDim.x * 2) {
    int p = base + sub;
    bool valid = p < total;
    float r0 = 0.f, r1 = 0.f; int i = 0, j = 0, b = 0;
    if (valid) {
      int q = p % RPP; b = p / RPP;
      if (q < 15300) { i = q / NT; j = q % NT; }
      else { int r = q - 15300; i = NSL + r / NSL; j = r % NSL; }
      r0 = coords[(b * NT + i) * 2]     - coords[(b * NT + j) * 2];
      r1 = coords[(b * NT + i) * 2 + 1] - coords[(b * NT + j) * 2 + 1];
    }
    float a = fmaf(r0, w1a, fmaf(r1, w1b, b1v));
    H1[sub][u] = a / (1.f + expf(-a));
    __syncthreads();
    float s = b2v;
    const float* h1 = H1[sub];
#pragma unroll 8
    for (int k = 0; k < 128; ++k) s = fmaf(h1[k], W2s[k * 128 + u], s);
    H2[sub][u] = s / (1.f + expf(-s));
    __syncthreads();
    if (u < 8 && valid) {
      float o = b3v;
      const float* h2 = H2[sub];
#pragma unroll 8
      for (int k = 0; k < 128; ++k) o = fmaf(h2[k], W3s[k * 8 + u], o);
      bias[((size_t)(b * NH + u) * NT + i) * NT + j] = o;
    }
    __syncthreads();
  }
}

// ---------------------------------------------------------------------------
// Transformer pieces
// ---------------------------------------------------------------------------
__global__ void build_x_k(const float* __restrict__ slots, const float* __restrict__ tok,
                          float* __restrict__ x) {
  int i = blockIdx.x * 256 + threadIdx.x;
  if (i >= NB * NT * DIM) return;
  int d = i & 511, n = (i >> 9) % NT, b = i / (NT * DIM);
  x[i] = (n < NSL) ? slots[((size_t)(b * NSL + n)) * DIM + d]
                   : tok[((size_t)(b * HWT + (n - NSL))) * DIM + d];
}

__global__ void trans_sim_k(const float* __restrict__ qh, const float* __restrict__ kh,
                            const float* __restrict__ bias, float* __restrict__ sim) {
  int blk = blockIdx.x;
  int i = blk % NT, h = (blk / NT) & 7, b = blk / (NT * NH);
  __shared__ float qs[64];
  if (threadIdx.x < 64) qs[threadIdx.x] = qh[((size_t)(b * NT + i)) * DIM + h * 64 + threadIdx.x];
  __syncthreads();
  for (int j = threadIdx.x; j < NT; j += 256) {
    const float* kr = kh + ((size_t)(b * NT + j)) * DIM + h * 64;
    float s = 0.f;
#pragma unroll 8
    for (int d = 0; d < 64; ++d) s = fmaf(qs[d], kr[d], s);
    size_t idx = (((size_t)(b * NH + h) * NT) + i) * NT + j;
    sim[idx] = s * 0.125f + bias[idx];
  }
}

__global__ void softmax_rows_k(float* __restrict__ X, int L) {
  float* row = X + (size_t)blockIdx.x * L;
  int t = threadIdx.x;
  float v0 = (t < L) ? row[t] : -1e30f;
  float v1 = (t + 256 < L) ? row[t + 256] : -1e30f;
  __shared__ float rb[256];
  rb[t] = fmaxf(v0, v1);
  __syncthreads();
  for (int o = 128; o > 0; o >>= 1) {
    if (t < o) rb[t] = fmaxf(rb[t], rb[t + o]);
    __syncthreads();
  }
  float m = rb[0];
  __syncthreads();
  float e0 = (t < L) ? expf(v0 - m) : 0.f;
  float e1 = (t + 256 < L) ? expf(v1 - m) : 0.f;
  rb[t] = e0 + e1;
  __syncthreads();
  for (int o = 128; o > 0; o >>= 1) {
    if (t < o) rb[t] += rb[t + o];
    __syncthreads();
  }
  float inv = 1.f / rb[0];
  if (t < L) row[t] = e0 * inv;
  if (t + 256 < L) row[t + 256] = e1 * inv;
}

__global__ __launch_bounds__(512) void trans_av_k(const float* __restrict__ a,
                                                  const float* __restrict__ vh,
                                                  float* __restrict__ o) {
  int bi = blockIdx.x;
  int b = bi / NT, i = bi % NT;
  int t = threadIdx.x, h = t >> 6;
  const float* arow = a + (((size_t)(b * NH + h) * NT) + i) * NT;
  float s = 0.f;
  for (int j = 0; j < NT; ++j) s = fmaf(arow[j], vh[((size_t)(b * NT + j)) * DIM + t], s);
  o[(size_t)bi * DIM + t] = s;
}

__global__ void write_out_k(const float* __restrict__ tmp, void* __restrict__ out,
                            const int* __restrict__ flagp) {
  const bool isbf = *flagp != 0;
  int i = blockIdx.x * 256 + threadIdx.x;
  if (i >= NB * HWT * DIM) return;
  int d = i & 511, tt = (i >> 9) & 255, b = i / (HWT * DIM);
  float v = tmp[((size_t)(b * NT + NSL + tt)) * DIM + d];
  if (isbf) ((bf16*)out)[i] = __float2bfloat16(v);
  else      ((float*)out)[i] = v;
}

// ---------------------------------------------------------------------------
extern "C" void kernel_launch(void* const* d_in, const int* in_sizes, int n_in,
                              void* d_out, int out_size, void* d_ws, size_t ws_size,
                              hipStream_t stream) {
  const void* images        = d_in[0];
  const void* slot_noise    = d_in[1];
  const void* patch_w       = d_in[2];
  const void* patch_b       = d_in[3];
  const void* hpos          = d_in[4];
  const void* wpos          = d_in[5];
  const void* rp_w1         = d_in[6];
  const void* rp_b1         = d_in[7];
  const void* rp_w2         = d_in[8];
  const void* rp_b2         = d_in[9];
  const void* rp_w3         = d_in[10];
  const void* rp_b3         = d_in[11];
  const void* slots_mu      = d_in[12];
  const void* slots_logsig  = d_in[13];
  const void* sa_ln_in_g    = d_in[14];
  const void* sa_ln_in_b    = d_in[15];
  const void* sa_ln_sl_g    = d_in[16];
  const void* sa_ln_sl_b    = d_in[17];
  const void* sa_wq         = d_in[18];
  const void* sa_bq         = d_in[19];
  const void* sa_wk         = d_in[20];
  const void* sa_bk         = d_in[21];
  const void* sa_wv         = d_in[22];
  const void* sa_bv         = d_in[23];
  const void* sa_wo         = d_in[24];
  const void* sa_bo         = d_in[25];
  const void* gru_wih       = d_in[26];
  const void* gru_whh       = d_in[27];
  const void* gru_bih       = d_in[28];
  const void* gru_bhh       = d_in[29];
  const void* sa_ln_ff_g    = d_in[30];
  const void* sa_ln_ff_b    = d_in[31];
  const void* sa_mlp_w1     = d_in[32];
  const void* sa_mlp_b1     = d_in[33];
  const void* sa_mlp_w2     = d_in[34];
  const void* sa_mlp_b2     = d_in[35];
  const void* s2c_w         = d_in[36];
  const void* s2c_b         = d_in[37];
  const void* attn_g        = d_in[38];
  const void* wq            = d_in[39];
  const void* wk            = d_in[40];
  const void* wv            = d_in[41];
  const void* wo            = d_in[42];
  const void* ff_g          = d_in[43];
  const void* ff_w1         = d_in[44];
  const void* ff_b1         = d_in[45];
  const void* ff_w2         = d_in[46];
  const void* ff_b2         = d_in[47];
  const void* final_g       = d_in[48];
  const void* pred_w        = d_in[49];
  const void* pred_b        = d_in[50];

  float* ws = (float*)d_ws;
  int* FLAG = (int*)ws;
  size_t off = 16;
  auto alloc = [&](size_t n) { float* p = ws + off; off += n; return p; };
  float* XP    = alloc((size_t)NB * HWT * 768);
  float* TOK   = alloc((size_t)NB * HWT * DIM);
  float* INP   = alloc((size_t)NB * HWT * DIM);
  float* KB    = alloc((size_t)NB * HWT * 256);
  float* VB    = alloc((size_t)NB * HWT * 256);
  float* SLOTS = alloc((size_t)NB * NSL * DIM);
  float* PREV  = alloc((size_t)NB * NSL * DIM);
  float* SLN   = alloc((size_t)NB * NSL * DIM);
  float* QB    = alloc((size_t)NB * NSL * 256);
  float* ATT   = alloc((size_t)NB * 4 * NSL * HWT);
  float* UPD   = alloc((size_t)NB * NSL * 256);
  float* UPDP  = alloc((size_t)NB * NSL * DIM);
  float* GX    = alloc((size_t)NB * NSL * 1536);
  float* GH    = alloc((size_t)NB * NSL * 1536);
  float* HIDS  = alloc((size_t)NB * NSL * DIM);
  float* SC    = alloc((size_t)NB * NSL * 2);
  float* CRD   = alloc((size_t)NB * NT * 2);
  float* TAB   = alloc((size_t)961 * 8);
  float* BIAS  = alloc((size_t)NB * NH * NT * NT);
  float* X     = alloc((size_t)NB * NT * DIM);
  float* HB    = alloc((size_t)NB * NT * DIM);
  float* QH    = alloc((size_t)NB * NT * DIM);
  float* KH    = alloc((size_t)NB * NT * DIM);
  float* VH    = alloc((size_t)NB * NT * DIM);
  float* SIM   = alloc((size_t)NB * NH * NT * NT);
  float* OB    = alloc((size_t)NB * NT * DIM);
  float* FFH   = alloc((size_t)NB * NT * FF);
  float* OUTT  = alloc((size_t)NB * NT * DIM);
  (void)ws_size; (void)in_sizes; (void)n_in; (void)out_size;

// f32 vector-ALU GEMM (small/slot path)
#define GEMM(A_, W_, WOFF_, BIAS_, BOFF_, C_, M_, N_, K_, ACT_, ACC_) \
  gemm_k<<<dim3(CDIV((N_),64), CDIV((M_),64)), dim3(16,16), 0, stream>>>( \
      A_, W_, (size_t)(WOFF_), BIAS_, (size_t)(BOFF_), C_, M_, N_, K_, ACT_, ACC_, FLAG)
// bf16 MFMA GEMM (requires N%64==0, K%32==0)
#define GEMMM(A_, W_, WOFF_, BIAS_, BOFF_, C_, M_, N_, K_, ACT_, ACC_) \
  gemm_mfma<<<dim3((N_)/64, CDIV((M_),64)), 256, 0, stream>>>( \
      A_, W_, (size_t)(WOFF_), BIAS_, (size_t)(BOFF_), C_, M_, N_, K_, ACT_, ACC_, FLAG)

  const int MROW = NB * NT;   // 1224

  // ---- dtype detection ----
  detect_k<<<1, 256, 0, stream>>>(images, FLAG);

  // ---- patch embed ----
  patchify_k<<<CDIV(NB*HWT*768, 256), 256, 0, stream>>>(images, XP, FLAG);
  GEMMM(XP, patch_w, 0, patch_b, 0, TOK, NB*HWT, DIM, 768, 0, 0);
  addpos_k<<<CDIV(NB*HWT*DIM, 256), 256, 0, stream>>>(TOK, hpos, wpos, FLAG);

  // ---- slot attention: k, v ----
  ln512_k<<<NB*HWT, 256, 0, stream>>>(TOK, sa_ln_in_g, sa_ln_in_b, INP, FLAG);
  GEMMM(INP, sa_wk, 0, sa_bk, 0, KB, NB*HWT, 256, DIM, 0, 0);
  GEMMM(INP, sa_wv, 0, sa_bv, 0, VB, NB*HWT, 256, DIM, 0, 0);
  slots_init_k<<<CDIV(NB*NSL*DIM, 256), 256, 0, stream>>>(slots_mu, slots_logsig, slot_noise, SLOTS, FLAG);

  for (int it = 0; it < 3; ++it) {
    hipMemcpyAsync(PREV, SLOTS, (size_t)NB*NSL*DIM*sizeof(float),
                   hipMemcpyDeviceToDevice, stream);
    ln512_k<<<NB*NSL, 256, 0, stream>>>(SLOTS, sa_ln_sl_g, sa_ln_sl_b, SLN, FLAG);
    GEMM(SLN, sa_wq, 0, sa_bq, 0, QB, NB*NSL, 256, DIM, 0, 0);
    slot_dots_k<<<NB*4*NSL, 256, 0, stream>>>(QB, KB, ATT);
    softmax_slots_k<<<16, 256, 0, stream>>>(ATT);
    renorm_attn_k<<<NB*4*NSL, 256, 0, stream>>>(ATT);
    slot_upd_k<<<NB*NSL, 256, 0, stream>>>(ATT, VB, UPD);
    GEMM(UPD, sa_wo, 0, sa_bo, 0, UPDP, NB*NSL, DIM, 256, 0, 0);
    GEMM(UPDP, gru_wih, 0, gru_bih, 0, GX, NB*NSL, 1536, DIM, 0, 0);
    GEMM(PREV, gru_whh, 0, gru_bhh, 0, GH, NB*NSL, 1536, DIM, 0, 0);
    gru_k<<<CDIV(NB*NSL*DIM, 256), 256, 0, stream>>>(GX, GH, PREV, SLOTS);
    ln512_k<<<NB*NSL, 256, 0, stream>>>(SLOTS, sa_ln_ff_g, sa_ln_ff_b, SLN, FLAG);
    GEMM(SLN, sa_mlp_w1, 0, sa_mlp_b1, 0, HIDS, NB*NSL, DIM, DIM, 1, 0);
    GEMM(HIDS, sa_mlp_w2, 0, sa_mlp_b2, 0, SLOTS, NB*NSL, DIM, DIM, 0, 1);
  }

  // ---- rel-pos bias ----
  GEMM(SLOTS, s2c_w, 0, s2c_b, 0, SC, NB*NSL, 2, DIM, 0, 0);
  build_coords_k<<<CDIV(NB*NT, 256), 256, 0, stream>>>(SC, CRD);
  relpos_table_k<<<961, 128, 0, stream>>>(rp_w1, rp_b1, rp_w2, rp_b2, rp_w3, rp_b3, TAB, FLAG);
  bias_fill_k<<<CDIV(NB*NH*HWT*HWT, 256), 256, 0, stream>>>(TAB, BIAS);
  relpos_mixed2_k<<<512, 256, 0, stream>>>(CRD, rp_w1, rp_b1, rp_w2, rp_b2, rp_w3, rp_b3, BIAS, FLAG);

  // ---- transformer ----
  build_x_k<<<CDIV(NB*NT*DIM, 256), 256, 0, stream>>>(SLOTS, TOK, X);
  for (int l = 0; l < 6; ++l) {
    size_t woff = (size_t)l * DIM * DIM;
    rms512_k<<<MROW, 256, 0, stream>>>(X, attn_g, l * DIM, HB, FLAG);
    GEMMM(HB, wq, woff, (const void*)nullptr, 0, QH, MROW, DIM, DIM, 0, 0);
    GEMMM(HB, wk, woff, (const void*)nullptr, 0, KH, MROW, DIM, DIM, 0, 0);
    GEMMM(HB, wv, woff, (const void*)nullptr, 0, VH, MROW, DIM, DIM, 0, 0);
    trans_sim_k<<<NB*NH*NT, 256, 0, stream>>>(QH, KH, BIAS, SIM);
    softmax_rows_k<<<NB*NH*NT, 256, 0, stream>>>(SIM, NT);
    trans_av_k<<<NB*NT, 512, 0, stream>>>(SIM, VH, OB);
    GEMMM(OB, wo, woff, (const void*)nullptr, 0, X, MROW, DIM, DIM, 0, 1);
    rms512_k<<<MROW, 256, 0, stream>>>(X, ff_g, l * DIM, HB, FLAG);
    GEMMM(HB, ff_w1, (size_t)l * DIM * FF, ff_b1, (size_t)l * FF, FFH, MROW, FF, DIM, 2, 0);
    GEMMM(FFH, ff_w2, (size_t)l * FF * DIM, ff_b2, (size_t)l * DIM, X, MROW, DIM, FF, 0, 1);
  }

  // ---- head ----
  rms512_k<<<MROW, 256, 0, stream>>>(X, final_g, 0, HB, FLAG);
  GEMMM(HB, pred_w, 0, pred_b, 0, OUTT, MROW, DIM, DIM, 0, 0);
  write_out_k<<<CDIV(NB*HWT*DIM, 256), 256, 0, stream>>>(OUTT, d_out, FLAG);

#undef GEMM
#undef GEMMM
}

// Round 4
// 2720.940 us; speedup vs baseline: 2.9070x; 1.5779x over previous
//
#include <hip/hip_runtime.h>
#include <hip/hip_bf16.h>

typedef __hip_bfloat16 bf16;
typedef short short8v __attribute__((ext_vector_type(8)));
typedef float float4v __attribute__((ext_vector_type(4)));

static __device__ __forceinline__ float b2f(bf16 x){ return __bfloat162float(x); }

// dtype-flexible input load: isbf ? bf16[i] : f32[i]
static __device__ __forceinline__ float ldin(const void* p, size_t i, bool isbf) {
  return isbf ? b2f(((const bf16*)p)[i]) : ((const float*)p)[i];
}

static __device__ __forceinline__ unsigned short f2bu(float f) {
  bf16 h = __float2bfloat16(f);
  return *reinterpret_cast<unsigned short*>(&h);
}

#define CDIV(a,b) (((a)+(b)-1)/(b))

// Model constants
#define NB   4
#define NSL  50
#define HWT  256
#define NT   306     // NSL + HWT
#define DIM  512
#define NH   8
#define FF   2048
#define RPP  28100   // mixed rel-pos pairs per batch

// ---------------------------------------------------------------------------
// dtype detector (bf16 vs f32 served data); flag=1 means bf16.
// ---------------------------------------------------------------------------
__global__ void detect_k(const void* p, int* flag) {
  const unsigned short* u = (const unsigned short*)p;
  int t = threadIdx.x;
  int e = (u[t] >> 7) & 0xFF;
  __shared__ int anybad;
  if (t == 0) anybad = 0;
  __syncthreads();
  if (e >= 0x88) atomicOr(&anybad, 1);
  __syncthreads();
  if (t == 0) *flag = anybad ? 0 : 1;
}

// ---------------------------------------------------------------------------
// MFMA bf16 GEMM body: C[M,N] = act(A[M,K] @ W[woff..][K,N] + bias[boff..])
// A: f32 ws (converted to bf16 in staging); W: bf16 or f32 per flag.
// N%64==0, K%32==0. 64x64 tile, BK=32, 256 thr = 4 waves.
// ---------------------------------------------------------------------------
#define LDT 40
static __device__ __forceinline__ void gemm_body(
    const float* __restrict__ A, const void* __restrict__ W, size_t woff,
    const void* __restrict__ bias, size_t boff, float* __restrict__ C,
    int M, int N, int K, int act, int accum, bool isbf)
{
  __shared__ unsigned short As[64 * LDT];
  __shared__ unsigned short Bs[64 * LDT];
  const int tid  = threadIdx.x;
  const int lane = tid & 63, wave = tid >> 6;
  const int quad = lane >> 4, ti = lane & 15;
  const int wm = (wave & 1) * 32, wn = (wave >> 1) * 32;
  const int bm = blockIdx.y * 64, bn = blockIdx.x * 64;
  const int arow = tid >> 2, ach = (tid & 3) * 8;
  const int bk = tid & 31, bch = (tid >> 5) * 8;

  float4v acc00 = {0,0,0,0}, acc01 = {0,0,0,0}, acc10 = {0,0,0,0}, acc11 = {0,0,0,0};

  for (int k0 = 0; k0 < K; k0 += 32) {
    {
      int gm = bm + arow;
      float v[8];
      if (gm < M) {
        const float* ap = A + (size_t)gm * K + k0 + ach;
        float4 x = *reinterpret_cast<const float4*>(ap);
        float4 y = *reinterpret_cast<const float4*>(ap + 4);
        v[0]=x.x; v[1]=x.y; v[2]=x.z; v[3]=x.w; v[4]=y.x; v[5]=y.y; v[6]=y.z; v[7]=y.w;
      } else {
#pragma unroll
        for (int i = 0; i < 8; ++i) v[i] = 0.f;
      }
      unsigned short h[8];
#pragma unroll
      for (int i = 0; i < 8; ++i) h[i] = f2bu(v[i]);
      *reinterpret_cast<short8v*>(&As[arow * LDT + ach]) = *reinterpret_cast<short8v*>(h);
    }
    {
      size_t base = woff + (size_t)(k0 + bk) * N + bn + bch;
      unsigned short h[8];
      if (isbf) {
        const ushort4* wp = reinterpret_cast<const ushort4*>((const unsigned short*)W + base);
        ushort4 u0 = wp[0], u1 = wp[1];
        h[0]=u0.x; h[1]=u0.y; h[2]=u0.z; h[3]=u0.w; h[4]=u1.x; h[5]=u1.y; h[6]=u1.z; h[7]=u1.w;
      } else {
        const float4* wp = reinterpret_cast<const float4*>((const float*)W + base);
        float4 f0 = wp[0], f1 = wp[1];
        h[0]=f2bu(f0.x); h[1]=f2bu(f0.y); h[2]=f2bu(f0.z); h[3]=f2bu(f0.w);
        h[4]=f2bu(f1.x); h[5]=f2bu(f1.y); h[6]=f2bu(f1.z); h[7]=f2bu(f1.w);
      }
#pragma unroll
      for (int i = 0; i < 8; ++i) Bs[(bch + i) * LDT + bk] = h[i];
    }
    __syncthreads();
    short8v a0 = *reinterpret_cast<const short8v*>(&As[(wm + ti)      * LDT + quad * 8]);
    short8v a1 = *reinterpret_cast<const short8v*>(&As[(wm + 16 + ti) * LDT + quad * 8]);
    short8v b0 = *reinterpret_cast<const short8v*>(&Bs[(wn + ti)      * LDT + quad * 8]);
    short8v b1 = *reinterpret_cast<const short8v*>(&Bs[(wn + 16 + ti) * LDT + quad * 8]);
    acc00 = __builtin_amdgcn_mfma_f32_16x16x32_bf16(a0, b0, acc00, 0, 0, 0);
    acc01 = __builtin_amdgcn_mfma_f32_16x16x32_bf16(a0, b1, acc01, 0, 0, 0);
    acc10 = __builtin_amdgcn_mfma_f32_16x16x32_bf16(a1, b0, acc10, 0, 0, 0);
    acc11 = __builtin_amdgcn_mfma_f32_16x16x32_bf16(a1, b1, acc11, 0, 0, 0);
    __syncthreads();
  }

  float4v accs[2][2] = {{acc00, acc01}, {acc10, acc11}};
#pragma unroll
  for (int mi = 0; mi < 2; ++mi) {
#pragma unroll
    for (int ni = 0; ni < 2; ++ni) {
      int row0 = bm + wm + mi * 16 + quad * 4;
      int col  = bn + wn + ni * 16 + ti;
      float bv = bias ? ldin(bias, boff + col, isbf) : 0.f;
#pragma unroll
      for (int r = 0; r < 4; ++r) {
        int row = row0 + r;
        if (row >= M) continue;
        float v = accs[mi][ni][r] + bv;
        if (act == 1) v = fmaxf(v, 0.f);
        else if (act == 2) {
          float u = 0.7978845608028654f * (v + 0.044715f * v * v * v);
          v = 0.5f * v * (1.f + tanhf(u));
        }
        size_t idx = (size_t)row * N + col;
        if (accum) C[idx] += v; else C[idx] = v;
      }
    }
  }
}

__global__ __launch_bounds__(256) void gemm_mfma(
    const float* __restrict__ A, const void* __restrict__ W, size_t woff,
    const void* __restrict__ bias, size_t boff, float* __restrict__ C,
    int M, int N, int K, int act, int accum, const int* __restrict__ flagp)
{
  gemm_body(A, W, woff, bias, boff, C, M, N, K, act, accum, *flagp != 0);
}

// 3 GEMMs sharing A and shapes (QKV); blockIdx.z selects job
__global__ __launch_bounds__(256) void gemm_mfma_tri(
    const float* __restrict__ A, const void* W0, const void* W1, const void* W2p,
    size_t woff, float* C0, float* C1, float* C2,
    int M, int N, int K, const int* __restrict__ flagp)
{
  const void* W = blockIdx.z == 0 ? W0 : (blockIdx.z == 1 ? W1 : W2p);
  float* C = blockIdx.z == 0 ? C0 : (blockIdx.z == 1 ? C1 : C2);
  gemm_body(A, W, woff, nullptr, 0, C, M, N, K, 0, 0, *flagp != 0);
}

// 2 GEMMs with separate A/W/bias/C, shared shapes (GX/GH, K/V)
__global__ __launch_bounds__(256) void gemm_mfma_duo(
    const float* A0, const float* A1, const void* W0, const void* W1,
    const void* bias0, const void* bias1, float* C0, float* C1,
    int M, int N, int K, const int* __restrict__ flagp)
{
  const float* A = blockIdx.z == 0 ? A0 : A1;
  const void* W = blockIdx.z == 0 ? W0 : W1;
  const void* bias = blockIdx.z == 0 ? bias0 : bias1;
  float* C = blockIdx.z == 0 ? C0 : C1;
  gemm_body(A, W, 0, bias, 0, C, M, N, K, 0, 0, *flagp != 0);
}

// ---------------------------------------------------------------------------
// f32 GEMM (only for the N=2 coords projection)
// ---------------------------------------------------------------------------
__global__ __launch_bounds__(256) void gemm_k(
    const float* __restrict__ A, const void* __restrict__ W, size_t woff,
    const void* __restrict__ bias, size_t boff, float* __restrict__ C,
    int M, int N, int K, int act, int accum, const int* __restrict__ flagp)
{
  const bool isbf = *flagp != 0;
  __shared__ float As[16][68];
  __shared__ float Ws[16][68];
  const int bm = blockIdx.y * 64, bn = blockIdx.x * 64;
  const int tx = threadIdx.x, ty = threadIdx.y;
  const int tid = ty * 16 + tx;
  float acc[4][4] = {};
  for (int k0 = 0; k0 < K; k0 += 16) {
#pragma unroll
    for (int i = 0; i < 4; ++i) {
      int idx = tid + i * 256;
      int m  = idx >> 4, k = idx & 15;
      int gm = bm + m;
      As[k][m] = (gm < M) ? A[(size_t)gm * K + k0 + k] : 0.f;
      int kk = idx >> 6, n = idx & 63;
      int gn = bn + n;
      Ws[kk][n] = (gn < N) ? ldin(W, woff + (size_t)(k0 + kk) * N + gn, isbf) : 0.f;
    }
    __syncthreads();
#pragma unroll
    for (int k = 0; k < 16; ++k) {
      float4 a4 = *reinterpret_cast<const float4*>(&As[k][ty * 4]);
      float4 w4 = *reinterpret_cast<const float4*>(&Ws[k][tx * 4]);
      float a[4] = {a4.x, a4.y, a4.z, a4.w};
      float w[4] = {w4.x, w4.y, w4.z, w4.w};
#pragma unroll
      for (int i = 0; i < 4; ++i)
#pragma unroll
        for (int j = 0; j < 4; ++j)
          acc[i][j] = fmaf(a[i], w[j], acc[i][j]);
    }
    __syncthreads();
  }
#pragma unroll
  for (int i = 0; i < 4; ++i) {
    int gm = bm + ty * 4 + i;
    if (gm >= M) continue;
#pragma unroll
    for (int j = 0; j < 4; ++j) {
      int gn = bn + tx * 4 + j;
      if (gn >= N) continue;
      float v = acc[i][j];
      if (bias) v += ldin(bias, boff + gn, isbf);
      size_t idx = (size_t)gm * N + gn;
      if (accum) C[idx] += v; else C[idx] = v;
    }
  }
}

// ---------------------------------------------------------------------------
// Patch extraction (im2col)
// ---------------------------------------------------------------------------
__global__ void patchify_k(const void* __restrict__ img, float* __restrict__ xp,
                           const int* __restrict__ flagp) {
  const bool isbf = *flagp != 0;
  int i = blockIdx.x * 256 + threadIdx.x;
  if (i >= NB * HWT * 768) return;
  int col = i % 768, row = i / 768;
  int c = col % 3, p2 = (col / 3) & 15, p1 = col / 48;
  int w = row & 15, h = (row >> 4) & 15, b = row >> 8;
  xp[i] = ldin(img, (((size_t)(b * 3 + c) * 256 + h * 16 + p1) * 256) + w * 16 + p2, isbf);
}

__global__ void addpos_k(float* __restrict__ tok, const void* __restrict__ hp,
                         const void* __restrict__ wp, const int* __restrict__ flagp) {
  const bool isbf = *flagp != 0;
  int i = blockIdx.x * 256 + threadIdx.x;
  if (i >= NB * HWT * DIM) return;
  int d = i & 511;
  int row = i >> 9;
  int w = row & 15, h = (row >> 4) & 15;
  tok[i] += ldin(hp, h * DIM + d, isbf) + ldin(wp, w * DIM + d, isbf);
}

// ---------------------------------------------------------------------------
// LayerNorm / RMSNorm over 512-dim rows
// ---------------------------------------------------------------------------
__global__ void ln512_k(const float* __restrict__ X, const void* __restrict__ g,
                        const void* __restrict__ b, float* __restrict__ Y,
                        const int* __restrict__ flagp) {
  const bool isbf = *flagp != 0;
  int row = blockIdx.x, t = threadIdx.x;
  const float* x = X + (size_t)row * DIM;
  float v0 = x[t], v1 = x[t + 256];
  __shared__ float rs[256], rq[256];
  rs[t] = v0 + v1; rq[t] = v0 * v0 + v1 * v1;
  __syncthreads();
  for (int o = 128; o > 0; o >>= 1) {
    if (t < o) { rs[t] += rs[t + o]; rq[t] += rq[t + o]; }
    __syncthreads();
  }
  float mean = rs[0] * (1.f / 512.f);
  float var  = rq[0] * (1.f / 512.f) - mean * mean;
  float inv  = rsqrtf(var + 1e-5f);
  float* y = Y + (size_t)row * DIM;
  y[t]       = (v0 - mean) * inv * ldin(g, t, isbf)       + ldin(b, t, isbf);
  y[t + 256] = (v1 - mean) * inv * ldin(g, t + 256, isbf) + ldin(b, t + 256, isbf);
}

__global__ void rms512_k(const float* __restrict__ X, const void* __restrict__ g,
                         int goff, float* __restrict__ Y, const int* __restrict__ flagp) {
  const bool isbf = *flagp != 0;
  int row = blockIdx.x, t = threadIdx.x;
  const float* x = X + (size_t)row * DIM;
  float v0 = x[t], v1 = x[t + 256];
  __shared__ float rq[256];
  rq[t] = v0 * v0 + v1 * v1;
  __syncthreads();
  for (int o = 128; o > 0; o >>= 1) {
    if (t < o) rq[t] += rq[t + o];
    __syncthreads();
  }
  float nrm = sqrtf(rq[0]);
  float sc = 22.62741699796952f / fmaxf(nrm, 1e-12f);
  float* y = Y + (size_t)row * DIM;
  y[t]       = v0 * sc * ldin(g, goff + t, isbf);
  y[t + 256] = v1 * sc * ldin(g, goff + t + 256, isbf);
}

// ---------------------------------------------------------------------------
// Slot attention pieces
// ---------------------------------------------------------------------------
__global__ void slots_init_k(const void* __restrict__ mu, const void* __restrict__ ls,
                             const void* __restrict__ noise, float* __restrict__ slots,
                             const int* __restrict__ flagp) {
  const bool isbf = *flagp != 0;
  int i = blockIdx.x * 256 + threadIdx.x;
  if (i >= NB * NSL * DIM) return;
  int d = i & 511;
  slots[i] = ldin(mu, d, isbf) + expf(ldin(ls, d, isbf)) * ldin(noise, i, isbf);
}

__global__ void slot_dots_k(const float* __restrict__ q, const float* __restrict__ k,
                            float* __restrict__ dots) {
  int blk = blockIdx.x;                 // b*200 + h*50 + i
  int i = blk % 50, h = (blk / 50) & 3, b = blk / 200;
  int j = threadIdx.x;
  __shared__ float qs[64];
  if (threadIdx.x < 64) qs[threadIdx.x] = q[((size_t)(b * 50 + i)) * 256 + h * 64 + threadIdx.x];
  __syncthreads();
  const float* kr = k + ((size_t)(b * 256 + j)) * 256 + h * 64;
  float s = 0.f;
#pragma unroll 8
  for (int d = 0; d < 64; ++d) s = fmaf(qs[d], kr[d], s);
  dots[(((size_t)(b * 4 + h) * 50) + i) * 256 + j] = s * 0.125f;
}

__global__ void softmax_slots_k(float* __restrict__ dots) {
  int idx = blockIdx.x * 256 + threadIdx.x;
  if (idx >= 4096) return;
  int j = idx & 255, h = (idx >> 8) & 3, b = idx >> 10;
  float* base = dots + ((size_t)(b * 4 + h) * 50) * 256 + j;
  float m = -1e30f;
  for (int i = 0; i < 50; ++i) m = fmaxf(m, base[i * 256]);
  float s = 0.f;
  for (int i = 0; i < 50; ++i) { float e = expf(base[i * 256] - m); base[i * 256] = e; s += e; }
  float inv = 1.f / s;
  for (int i = 0; i < 50; ++i) base[i * 256] *= inv;
}

__global__ void renorm_attn_k(float* __restrict__ attn) {
  int t = threadIdx.x;
  float* row = attn + (size_t)blockIdx.x * 256;
  float v = row[t] + 1e-8f;
  __shared__ float rs[256];
  rs[t] = v;
  __syncthreads();
  for (int o = 128; o > 0; o >>= 1) {
    if (t < o) rs[t] += rs[t + o];
    __syncthreads();
  }
  row[t] = v / rs[0];
}

__global__ void slot_upd_k(const float* __restrict__ attn, const float* __restrict__ v,
                           float* __restrict__ upd) {
  int bi = blockIdx.x;        // b*50+i
  int b = bi / 50, i = bi % 50;
  int t = threadIdx.x, h = t >> 6;
  const float* arow = attn + ((size_t)((b * 4 + h) * 50) + i) * 256;
  float s = 0.f;
  for (int j = 0; j < 256; ++j) s = fmaf(arow[j], v[((size_t)(b * 256 + j)) * 256 + t], s);
  upd[(size_t)bi * 256 + t] = s;
}

// in-place safe: prev==slots allowed (elementwise)
__global__ void gru_k(const float* __restrict__ gx, const float* __restrict__ gh,
                      float* __restrict__ slots) {
  int i = blockIdx.x * 256 + threadIdx.x;
  if (i >= NB * NSL * DIM) return;
  int row = i >> 9, d = i & 511;
  size_t b3 = (size_t)row * 1536;
  float xr = gx[b3 + d], xz = gx[b3 + 512 + d], xn = gx[b3 + 1024 + d];
  float hr = gh[b3 + d], hz = gh[b3 + 512 + d], hn = gh[b3 + 1024 + d];
  float r = 1.f / (1.f + expf(-(xr + hr)));
  float z = 1.f / (1.f + expf(-(xz + hz)));
  float n = tanhf(xn + r * hn);
  float prev = slots[i];
  slots[i] = (1.f - z) * n + z * prev;
}

// ---------------------------------------------------------------------------
// Rel-pos bias
// ---------------------------------------------------------------------------
__global__ void build_coords_k(const float* __restrict__ sc, float* __restrict__ coords) {
  int i = blockIdx.x * 256 + threadIdx.x;
  if (i >= NB * NT) return;
  int b = i / NT, n = i % NT;
  float cx, cy;
  if (n < NSL) { cx = sc[(b * NSL + n) * 2]; cy = sc[(b * NSL + n) * 2 + 1]; }
  else { int t = n - NSL; cx = (float)(t >> 4); cy = (float)(t & 15); }
  coords[i * 2] = cx; coords[i * 2 + 1] = cy;
}

__global__ void relpos_table_k(const void* w1, const void* b1, const void* w2,
                               const void* b2, const void* w3, const void* b3,
                               float* __restrict__ tab, const int* __restrict__ flagp) {
  const bool isbf = *flagp != 0;
  int blk = blockIdx.x;  // 961
  float r0 = (float)(blk / 31 - 15), r1 = (float)(blk % 31 - 15);
  int t = threadIdx.x;
  __shared__ float h1[128], h2[128];
  float a = fmaf(r0, ldin(w1, t, isbf), fmaf(r1, ldin(w1, 128 + t, isbf), ldin(b1, t, isbf)));
  h1[t] = a / (1.f + expf(-a));
  __syncthreads();
  float s = ldin(b2, t, isbf);
#pragma unroll 4
  for (int k = 0; k < 128; ++k) s = fmaf(h1[k], ldin(w2, k * 128 + t, isbf), s);
  h2[t] = s / (1.f + expf(-s));
  __syncthreads();
  if (t < 8) {
    float o = ldin(b3, t, isbf);
#pragma unroll 4
    for (int k = 0; k < 128; ++k) o = fmaf(h2[k], ldin(w3, k * 8 + t, isbf), o);
    tab[blk * 8 + t] = o;
  }
}

__global__ void bias_fill_k(const float* __restrict__ tab, float* __restrict__ bias) {
  int i = blockIdx.x * 256 + threadIdx.x;
  if (i >= NB * NH * HWT * HWT) return;
  int jj = i & 255, ii = (i >> 8) & 255, h = (i >> 16) & 7, b = i >> 19;
  int di = (ii >> 4) - (jj >> 4) + 15;
  int dj = (ii & 15) - (jj & 15) + 15;
  bias[(((size_t)(b * NH + h) * NT) + NSL + ii) * NT + NSL + jj] = tab[(di * 31 + dj) * 8 + h];
}

// ---------------------------------------------------------------------------
// Fused mixed-pair rel-pos MLP: layer1 -> LDS(bf16), layer2 via MFMA,
// layer3 + scatter. One block = 64 pairs. LDS ~71 KB.
// ---------------------------------------------------------------------------
union RelUnion { unsigned short h1[64 * 136]; float h2[64 * 132]; };
__global__ __launch_bounds__(256) void relpos_fused_k(
    const float* __restrict__ coords,
    const void* w1, const void* b1, const void* w2,
    const void* b2, const void* w3, const void* b3,
    float* __restrict__ bias, const int* __restrict__ flagp)
{
  const bool isbf = *flagp != 0;
  __shared__ unsigned short W2s[128 * 136];   // [n][k] bf16, k-contig
  __shared__ float W3s[128 * 8];
  __shared__ RelUnion U;
  const int t = threadIdx.x;
  const int lane = t & 63, wave = t >> 6;
  const int quad = lane >> 4, ti = lane & 15;

  // stage W2 transposed + W3
  for (int e = t; e < 128 * 128; e += 256) {
    int k = e >> 7, n = e & 127;
    W2s[n * 136 + k] = isbf ? ((const unsigned short*)w2)[e] : f2bu(((const float*)w2)[e]);
  }
  for (int e = t; e < 128 * 8; e += 256) W3s[e] = ldin(w3, e, isbf);

  // phase A: layer-1 silu -> U.h1 (bf16)
  {
    const int pr = t >> 2, c0 = (t & 3) * 32;
    int p = blockIdx.x * 64 + pr;
    float r0 = 0.f, r1 = 0.f;
    if (p < NB * RPP) {
      int q = p % RPP, bb = p / RPP;
      int ii, jj;
      if (q < 15300) { ii = q / NT; jj = q % NT; }
      else { int r = q - 15300; ii = NSL + r / NSL; jj = r % NSL; }
      r0 = coords[(bb * NT + ii) * 2]     - coords[(bb * NT + jj) * 2];
      r1 = coords[(bb * NT + ii) * 2 + 1] - coords[(bb * NT + jj) * 2 + 1];
    }
    for (int u = c0; u < c0 + 32; ++u) {
      float a = fmaf(r0, ldin(w1, u, isbf), fmaf(r1, ldin(w1, 128 + u, isbf), ldin(b1, u, isbf)));
      a = a / (1.f + expf(-a));
      U.h1[pr * 136 + u] = f2bu(a);
    }
  }
  __syncthreads();

  // phase B: H2 = silu(H1 @ W2 + b2). wave handles 16 rows x 128 cols.
  const int m0 = wave * 16;
  float4v acc[8];
#pragma unroll
  for (int nt = 0; nt < 8; ++nt) acc[nt] = (float4v){0.f, 0.f, 0.f, 0.f};
#pragma unroll
  for (int ks = 0; ks < 4; ++ks) {
    short8v a = *reinterpret_cast<const short8v*>(&U.h1[(m0 + ti) * 136 + ks * 32 + quad * 8]);
#pragma unroll
    for (int nt = 0; nt < 8; ++nt) {
      short8v bfr = *reinterpret_cast<const short8v*>(&W2s[(nt * 16 + ti) * 136 + ks * 32 + quad * 8]);
      acc[nt] = __builtin_amdgcn_mfma_f32_16x16x32_bf16(a, bfr, acc[nt], 0, 0, 0);
    }
  }
  __syncthreads();   // all h1 reads complete before overwriting with h2
#pragma unroll
  for (int nt = 0; nt < 8; ++nt) {
    int col = nt * 16 + ti;
    float b2v = ldin(b2, col, isbf);
#pragma unroll
    for (int r = 0; r < 4; ++r) {
      float v = acc[nt][r] + b2v;
      U.h2[(m0 + quad * 4 + r) * 132 + col] = v / (1.f + expf(-v));
    }
  }
  __syncthreads();

  // phase C: layer 3 (128->8) + scatter. 4 threads/pair, 2 heads each.
  {
    int pr = t >> 2, sub = t & 3;
    int p = blockIdx.x * 64 + pr;
    if (p < NB * RPP) {
      int q = p % RPP, bb = p / RPP;
      int ii, jj;
      if (q < 15300) { ii = q / NT; jj = q % NT; }
      else { int r = q - 15300; ii = NSL + r / NSL; jj = r % NSL; }
      int h0 = sub * 2, h1i = sub * 2 + 1;
      float s0 = ldin(b3, h0, isbf), s1 = ldin(b3, h1i, isbf);
      const float* h2row = &U.h2[pr * 132];
#pragma unroll 8
      for (int k = 0; k < 128; ++k) {
        float v = h2row[k];
        s0 = fmaf(v, W3s[k * 8 + h0], s0);
        s1 = fmaf(v, W3s[k * 8 + h1i], s1);
      }
      bias[((size_t)(bb * NH + h0)  * NT + ii) * NT + jj] = s0;
      bias[((size_t)(bb * NH + h1i) * NT + ii) * NT + jj] = s1;
    }
  }
}

// ---------------------------------------------------------------------------
// Transformer pieces
// ---------------------------------------------------------------------------
__global__ void build_x_k(const float* __restrict__ slots, const float* __restrict__ tok,
                          float* __restrict__ x) {
  int i = blockIdx.x * 256 + threadIdx.x;
  if (i >= NB * NT * DIM) return;
  int d = i & 511, n = (i >> 9) % NT, b = i / (NT * DIM);
  x[i] = (n < NSL) ? slots[((size_t)(b * NSL + n)) * DIM + d]
                   : tok[((size_t)(b * HWT + (n - NSL))) * DIM + d];
}

// fused sim + bias + row-softmax: block per (b,h,i); writes probabilities
__global__ void trans_attn_k(const float* __restrict__ qh, const float* __restrict__ kh,
                             const float* __restrict__ bias, float* __restrict__ prob) {
  int blk = blockIdx.x;
  int i = blk % NT, h = (blk / NT) & 7, b = blk / (NT * NH);
  int t = threadIdx.x;
  __shared__ float qs[64];
  if (t < 64) qs[t] = qh[((size_t)(b * NT + i)) * DIM + h * 64 + t];
  __syncthreads();
  size_t rowbase = (((size_t)(b * NH + h) * NT) + i) * NT;
  float sv[2];
#pragma unroll
  for (int m = 0; m < 2; ++m) {
    int j = t + m * 256;
    if (j < NT) {
      const float* kr = kh + ((size_t)(b * NT + j)) * DIM + h * 64;
      float s = 0.f;
#pragma unroll 8
      for (int d = 0; d < 64; ++d) s = fmaf(qs[d], kr[d], s);
      sv[m] = s * 0.125f + bias[rowbase + j];
    } else sv[m] = -1e30f;
  }
  __shared__ float rb[256];
  rb[t] = fmaxf(sv[0], sv[1]);
  __syncthreads();
  for (int o = 128; o > 0; o >>= 1) {
    if (t < o) rb[t] = fmaxf(rb[t], rb[t + o]);
    __syncthreads();
  }
  float mx = rb[0];
  __syncthreads();
  float e0 = (t < NT) ? expf(sv[0] - mx) : 0.f;
  float e1 = (t + 256 < NT) ? expf(sv[1] - mx) : 0.f;
  rb[t] = e0 + e1;
  __syncthreads();
  for (int o = 128; o > 0; o >>= 1) {
    if (t < o) rb[t] += rb[t + o];
    __syncthreads();
  }
  float inv = 1.f / rb[0];
  if (t < NT) prob[rowbase + t] = e0 * inv;
  if (t + 256 < NT) prob[rowbase + t + 256] = e1 * inv;
}

__global__ __launch_bounds__(512) void trans_av_k(const float* __restrict__ a,
                                                  const float* __restrict__ vh,
                                                  float* __restrict__ o) {
  int bi = blockIdx.x;
  int b = bi / NT, i = bi % NT;
  int t = threadIdx.x, h = t >> 6;
  const float* arow = a + (((size_t)(b * NH + h) * NT) + i) * NT;
  float s = 0.f;
  for (int j = 0; j < NT; ++j) s = fmaf(arow[j], vh[((size_t)(b * NT + j)) * DIM + t], s);
  o[(size_t)bi * DIM + t] = s;
}

__global__ void write_out_k(const float* __restrict__ tmp, void* __restrict__ out,
                            const int* __restrict__ flagp) {
  const bool isbf = *flagp != 0;
  int i = blockIdx.x * 256 + threadIdx.x;
  if (i >= NB * HWT * DIM) return;
  int d = i & 511, tt = (i >> 9) & 255, b = i / (HWT * DIM);
  float v = tmp[((size_t)(b * NT + NSL + tt)) * DIM + d];
  if (isbf) ((bf16*)out)[i] = __float2bfloat16(v);
  else      ((float*)out)[i] = v;
}

// ---------------------------------------------------------------------------
extern "C" void kernel_launch(void* const* d_in, const int* in_sizes, int n_in,
                              void* d_out, int out_size, void* d_ws, size_t ws_size,
                              hipStream_t stream) {
  const void* images        = d_in[0];
  const void* slot_noise    = d_in[1];
  const void* patch_w       = d_in[2];
  const void* patch_b       = d_in[3];
  const void* hpos          = d_in[4];
  const void* wpos          = d_in[5];
  const void* rp_w1         = d_in[6];
  const void* rp_b1         = d_in[7];
  const void* rp_w2         = d_in[8];
  const void* rp_b2         = d_in[9];
  const void* rp_w3         = d_in[10];
  const void* rp_b3         = d_in[11];
  const void* slots_mu      = d_in[12];
  const void* slots_logsig  = d_in[13];
  const void* sa_ln_in_g    = d_in[14];
  const void* sa_ln_in_b    = d_in[15];
  const void* sa_ln_sl_g    = d_in[16];
  const void* sa_ln_sl_b    = d_in[17];
  const void* sa_wq         = d_in[18];
  const void* sa_bq         = d_in[19];
  const void* sa_wk         = d_in[20];
  const void* sa_bk         = d_in[21];
  const void* sa_wv         = d_in[22];
  const void* sa_bv         = d_in[23];
  const void* sa_wo         = d_in[24];
  const void* sa_bo         = d_in[25];
  const void* gru_wih       = d_in[26];
  const void* gru_whh       = d_in[27];
  const void* gru_bih       = d_in[28];
  const void* gru_bhh       = d_in[29];
  const void* sa_ln_ff_g    = d_in[30];
  const void* sa_ln_ff_b    = d_in[31];
  const void* sa_mlp_w1     = d_in[32];
  const void* sa_mlp_b1     = d_in[33];
  const void* sa_mlp_w2     = d_in[34];
  const void* sa_mlp_b2     = d_in[35];
  const void* s2c_w         = d_in[36];
  const void* s2c_b         = d_in[37];
  const void* attn_g        = d_in[38];
  const void* wq            = d_in[39];
  const void* wk            = d_in[40];
  const void* wv            = d_in[41];
  const void* wo            = d_in[42];
  const void* ff_g          = d_in[43];
  const void* ff_w1         = d_in[44];
  const void* ff_b1         = d_in[45];
  const void* ff_w2         = d_in[46];
  const void* ff_b2         = d_in[47];
  const void* final_g       = d_in[48];
  const void* pred_w        = d_in[49];
  const void* pred_b        = d_in[50];

  float* ws = (float*)d_ws;
  int* FLAG = (int*)ws;
  size_t off = 16;
  auto alloc = [&](size_t n) { float* p = ws + off; off += n; return p; };
  float* XP    = alloc((size_t)NB * HWT * 768);
  float* TOK   = alloc((size_t)NB * HWT * DIM);
  float* INP   = alloc((size_t)NB * HWT * DIM);
  float* KB    = alloc((size_t)NB * HWT * 256);
  float* VB    = alloc((size_t)NB * HWT * 256);
  float* SLOTS = alloc((size_t)NB * NSL * DIM);
  float* SLN   = alloc((size_t)NB * NSL * DIM);
  float* QB    = alloc((size_t)NB * NSL * 256);
  float* ATT   = alloc((size_t)NB * 4 * NSL * HWT);
  float* UPD   = alloc((size_t)NB * NSL * 256);
  float* UPDP  = alloc((size_t)NB * NSL * DIM);
  float* GX    = alloc((size_t)NB * NSL * 1536);
  float* GH    = alloc((size_t)NB * NSL * 1536);
  float* HIDS  = alloc((size_t)NB * NSL * DIM);
  float* SC    = alloc((size_t)NB * NSL * 2);
  float* CRD   = alloc((size_t)NB * NT * 2);
  float* TAB   = alloc((size_t)961 * 8);
  float* BIAS  = alloc((size_t)NB * NH * NT * NT);
  float* X     = alloc((size_t)NB * NT * DIM);
  float* HB    = alloc((size_t)NB * NT * DIM);
  float* QH    = alloc((size_t)NB * NT * DIM);
  float* KH    = alloc((size_t)NB * NT * DIM);
  float* VH    = alloc((size_t)NB * NT * DIM);
  float* SIM   = alloc((size_t)NB * NH * NT * NT);
  float* OB    = alloc((size_t)NB * NT * DIM);
  float* FFH   = alloc((size_t)NB * NT * FF);
  float* OUTT  = alloc((size_t)NB * NT * DIM);
  (void)ws_size; (void)in_sizes; (void)n_in; (void)out_size;

#define GEMMF(A_, W_, WOFF_, BIAS_, BOFF_, C_, M_, N_, K_, ACT_, ACC_) \
  gemm_k<<<dim3(CDIV((N_),64), CDIV((M_),64)), dim3(16,16), 0, stream>>>( \
      A_, W_, (size_t)(WOFF_), BIAS_, (size_t)(BOFF_), C_, M_, N_, K_, ACT_, ACC_, FLAG)
#define GEMMM(A_, W_, WOFF_, BIAS_, BOFF_, C_, M_, N_, K_, ACT_, ACC_) \
  gemm_mfma<<<dim3((N_)/64, CDIV((M_),64)), 256, 0, stream>>>( \
      A_, W_, (size_t)(WOFF_), BIAS_, (size_t)(BOFF_), C_, M_, N_, K_, ACT_, ACC_, FLAG)

  const int MROW = NB * NT;   // 1224
  const int MS   = NB * NSL;  // 200

  // ---- dtype detection ----
  detect_k<<<1, 256, 0, stream>>>(images, FLAG);

  // ---- patch embed ----
  patchify_k<<<CDIV(NB*HWT*768, 256), 256, 0, stream>>>(images, XP, FLAG);
  GEMMM(XP, patch_w, 0, patch_b, 0, TOK, NB*HWT, DIM, 768, 0, 0);
  addpos_k<<<CDIV(NB*HWT*DIM, 256), 256, 0, stream>>>(TOK, hpos, wpos, FLAG);

  // ---- slot attention: k, v (batched duo) ----
  ln512_k<<<NB*HWT, 256, 0, stream>>>(TOK, sa_ln_in_g, sa_ln_in_b, INP, FLAG);
  gemm_mfma_duo<<<dim3(256/64, CDIV(NB*HWT,64), 2), 256, 0, stream>>>(
      INP, INP, sa_wk, sa_wv, sa_bk, sa_bv, KB, VB, NB*HWT, 256, DIM, FLAG);
  slots_init_k<<<CDIV(NB*NSL*DIM, 256), 256, 0, stream>>>(slots_mu, slots_logsig, slot_noise, SLOTS, FLAG);

  for (int it = 0; it < 3; ++it) {
    ln512_k<<<MS, 256, 0, stream>>>(SLOTS, sa_ln_sl_g, sa_ln_sl_b, SLN, FLAG);
    GEMMM(SLN, sa_wq, 0, sa_bq, 0, QB, MS, 256, DIM, 0, 0);
    slot_dots_k<<<NB*4*NSL, 256, 0, stream>>>(QB, KB, ATT);
    softmax_slots_k<<<16, 256, 0, stream>>>(ATT);
    renorm_attn_k<<<NB*4*NSL, 256, 0, stream>>>(ATT);
    slot_upd_k<<<MS, 256, 0, stream>>>(ATT, VB, UPD);
    GEMMM(UPD, sa_wo, 0, sa_bo, 0, UPDP, MS, DIM, 256, 0, 0);
    gemm_mfma_duo<<<dim3(1536/64, CDIV(MS,64), 2), 256, 0, stream>>>(
        UPDP, SLOTS, gru_wih, gru_whh, gru_bih, gru_bhh, GX, GH, MS, 1536, DIM, FLAG);
    gru_k<<<CDIV(NB*NSL*DIM, 256), 256, 0, stream>>>(GX, GH, SLOTS);
    ln512_k<<<MS, 256, 0, stream>>>(SLOTS, sa_ln_ff_g, sa_ln_ff_b, SLN, FLAG);
    GEMMM(SLN, sa_mlp_w1, 0, sa_mlp_b1, 0, HIDS, MS, DIM, DIM, 1, 0);
    GEMMM(HIDS, sa_mlp_w2, 0, sa_mlp_b2, 0, SLOTS, MS, DIM, DIM, 0, 1);
  }

  // ---- rel-pos bias ----
  GEMMF(SLOTS, s2c_w, 0, s2c_b, 0, SC, MS, 2, DIM, 0, 0);
  build_coords_k<<<CDIV(NB*NT, 256), 256, 0, stream>>>(SC, CRD);
  relpos_table_k<<<961, 128, 0, stream>>>(rp_w1, rp_b1, rp_w2, rp_b2, rp_w3, rp_b3, TAB, FLAG);
  bias_fill_k<<<CDIV(NB*NH*HWT*HWT, 256), 256, 0, stream>>>(TAB, BIAS);
  relpos_fused_k<<<CDIV(NB*RPP, 64), 256, 0, stream>>>(CRD, rp_w1, rp_b1, rp_w2, rp_b2, rp_w3, rp_b3, BIAS, FLAG);

  // ---- transformer ----
  build_x_k<<<CDIV(NB*NT*DIM, 256), 256, 0, stream>>>(SLOTS, TOK, X);
  for (int l = 0; l < 6; ++l) {
    size_t woff = (size_t)l * DIM * DIM;
    rms512_k<<<MROW, 256, 0, stream>>>(X, attn_g, l * DIM, HB, FLAG);
    gemm_mfma_tri<<<dim3(DIM/64, CDIV(MROW,64), 3), 256, 0, stream>>>(
        HB, wq, wk, wv, woff, QH, KH, VH, MROW, DIM, DIM, FLAG);
    trans_attn_k<<<NB*NH*NT, 256, 0, stream>>>(QH, KH, BIAS, SIM);
    trans_av_k<<<NB*NT, 512, 0, stream>>>(SIM, VH, OB);
    GEMMM(OB, wo, woff, (const void*)nullptr, 0, X, MROW, DIM, DIM, 0, 1);
    rms512_k<<<MROW, 256, 0, stream>>>(X, ff_g, l * DIM, HB, FLAG);
    GEMMM(HB, ff_w1, (size_t)l * DIM * FF, ff_b1, (size_t)l * FF, FFH, MROW, FF, DIM, 2, 0);
    GEMMM(FFH, ff_w2, (size_t)l * FF * DIM, ff_b2, (size_t)l * DIM, X, MROW, DIM, FF, 0, 1);
  }

  // ---- head ----
  rms512_k<<<MROW, 256, 0, stream>>>(X, final_g, 0, HB, FLAG);
  GEMMM(HB, pred_w, 0, pred_b, 0, OUTT, MROW, DIM, DIM, 0, 0);
  write_out_k<<<CDIV(NB*HWT*DIM, 256), 256, 0, stream>>>(OUTT, d_out, FLAG);

#undef GEMMF
#undef GEMMM
}

// Round 6
// 1960.557 us; speedup vs baseline: 4.0344x; 1.3878x over previous
//
#include <hip/hip_runtime.h>
#include <hip/hip_bf16.h>

typedef __hip_bfloat16 bf16;
typedef short short8v __attribute__((ext_vector_type(8)));
typedef float float4v __attribute__((ext_vector_type(4)));

static __device__ __forceinline__ float b2f(bf16 x){ return __bfloat162float(x); }

// dtype-flexible input load: isbf ? bf16[i] : f32[i]
static __device__ __forceinline__ float ldin(const void* p, size_t i, bool isbf) {
  return isbf ? b2f(((const bf16*)p)[i]) : ((const float*)p)[i];
}

static __device__ __forceinline__ unsigned short f2bu(float f) {
  bf16 h = __float2bfloat16(f);
  return *reinterpret_cast<unsigned short*>(&h);
}

#define CDIV(a,b) (((a)+(b)-1)/(b))

// Model constants
#define NB   4
#define NSL  50
#define HWT  256
#define NT   306     // NSL + HWT
#define DIM  512
#define NH   8
#define FF   2048
#define RPP  28100   // mixed rel-pos pairs per batch
#define PCH  56200   // rel-pos chunk (2 chunks of NB*RPP/2)

// decode mixed-pair index q (0..RPP-1) -> (i,j)
static __device__ __forceinline__ void rp_decode(int q, int& i, int& j) {
  if (q < 15300) { i = q / NT; j = q % NT; }
  else { int r = q - 15300; i = NSL + r / NSL; j = r % NSL; }
}

// ---------------------------------------------------------------------------
// dtype detector (bf16 vs f32 served data); flag=1 means bf16.
// ---------------------------------------------------------------------------
__global__ void detect_k(const void* p, int* flag) {
  const unsigned short* u = (const unsigned short*)p;
  int t = threadIdx.x;
  int e = (u[t] >> 7) & 0xFF;
  __shared__ int anybad;
  if (t == 0) anybad = 0;
  __syncthreads();
  if (e >= 0x88) atomicOr(&anybad, 1);
  __syncthreads();
  if (t == 0) *flag = anybad ? 0 : 1;
}

// ---------------------------------------------------------------------------
// MFMA bf16 GEMM body: C = act(A[M,K] @ W[woff..][K,N] + bias[boff..])
// aty: 0 A=f32, 1 A=bf16.  oty: 0 C=f32 (accum allowed), 1 C=bf16.
// act: 0 none, 1 relu, 2 gelu(tanh), 3 silu. N%64==0, K%32==0.
// ---------------------------------------------------------------------------
#define LDT 40
static __device__ __forceinline__ void gemm_body(
    const void* __restrict__ A, int aty,
    const void* __restrict__ W, size_t woff,
    const void* __restrict__ bias, size_t boff,
    void* __restrict__ C, int oty,
    int M, int N, int K, int act, int accum, bool isbf)
{
  __shared__ unsigned short As[64 * LDT];
  __shared__ unsigned short Bs[64 * LDT];
  const int tid  = threadIdx.x;
  const int lane = tid & 63, wave = tid >> 6;
  const int quad = lane >> 4, ti = lane & 15;
  const int wm = (wave & 1) * 32, wn = (wave >> 1) * 32;
  const int bm = blockIdx.y * 64, bn = blockIdx.x * 64;
  const int arow = tid >> 2, ach = (tid & 3) * 8;
  const int bk = tid & 31, bch = (tid >> 5) * 8;

  float4v acc00 = {0,0,0,0}, acc01 = {0,0,0,0}, acc10 = {0,0,0,0}, acc11 = {0,0,0,0};

  for (int k0 = 0; k0 < K; k0 += 32) {
    {
      int gm = bm + arow;
      unsigned short h[8];
      if (gm < M) {
        if (aty) {
          const ushort4* ap = reinterpret_cast<const ushort4*>(
              (const unsigned short*)A + (size_t)gm * K + k0 + ach);
          ushort4 u0 = ap[0], u1 = ap[1];
          h[0]=u0.x; h[1]=u0.y; h[2]=u0.z; h[3]=u0.w; h[4]=u1.x; h[5]=u1.y; h[6]=u1.z; h[7]=u1.w;
        } else {
          const float* ap = (const float*)A + (size_t)gm * K + k0 + ach;
          float4 x = *reinterpret_cast<const float4*>(ap);
          float4 y = *reinterpret_cast<const float4*>(ap + 4);
          h[0]=f2bu(x.x); h[1]=f2bu(x.y); h[2]=f2bu(x.z); h[3]=f2bu(x.w);
          h[4]=f2bu(y.x); h[5]=f2bu(y.y); h[6]=f2bu(y.z); h[7]=f2bu(y.w);
        }
      } else {
#pragma unroll
        for (int i = 0; i < 8; ++i) h[i] = 0;
      }
      *reinterpret_cast<short8v*>(&As[arow * LDT + ach]) = *reinterpret_cast<short8v*>(h);
    }
    {
      size_t base = woff + (size_t)(k0 + bk) * N + bn + bch;
      unsigned short h[8];
      if (isbf) {
        const ushort4* wp = reinterpret_cast<const ushort4*>((const unsigned short*)W + base);
        ushort4 u0 = wp[0], u1 = wp[1];
        h[0]=u0.x; h[1]=u0.y; h[2]=u0.z; h[3]=u0.w; h[4]=u1.x; h[5]=u1.y; h[6]=u1.z; h[7]=u1.w;
      } else {
        const float4* wp = reinterpret_cast<const float4*>((const float*)W + base);
        float4 f0 = wp[0], f1 = wp[1];
        h[0]=f2bu(f0.x); h[1]=f2bu(f0.y); h[2]=f2bu(f0.z); h[3]=f2bu(f0.w);
        h[4]=f2bu(f1.x); h[5]=f2bu(f1.y); h[6]=f2bu(f1.z); h[7]=f2bu(f1.w);
      }
#pragma unroll
      for (int i = 0; i < 8; ++i) Bs[(bch + i) * LDT + bk] = h[i];
    }
    __syncthreads();
    short8v a0 = *reinterpret_cast<const short8v*>(&As[(wm + ti)      * LDT + quad * 8]);
    short8v a1 = *reinterpret_cast<const short8v*>(&As[(wm + 16 + ti) * LDT + quad * 8]);
    short8v b0 = *reinterpret_cast<const short8v*>(&Bs[(wn + ti)      * LDT + quad * 8]);
    short8v b1 = *reinterpret_cast<const short8v*>(&Bs[(wn + 16 + ti) * LDT + quad * 8]);
    acc00 = __builtin_amdgcn_mfma_f32_16x16x32_bf16(a0, b0, acc00, 0, 0, 0);
    acc01 = __builtin_amdgcn_mfma_f32_16x16x32_bf16(a0, b1, acc01, 0, 0, 0);
    acc10 = __builtin_amdgcn_mfma_f32_16x16x32_bf16(a1, b0, acc10, 0, 0, 0);
    acc11 = __builtin_amdgcn_mfma_f32_16x16x32_bf16(a1, b1, acc11, 0, 0, 0);
    __syncthreads();
  }

  float4v accs[2][2] = {{acc00, acc01}, {acc10, acc11}};
#pragma unroll
  for (int mi = 0; mi < 2; ++mi) {
#pragma unroll
    for (int ni = 0; ni < 2; ++ni) {
      int row0 = bm + wm + mi * 16 + quad * 4;
      int col  = bn + wn + ni * 16 + ti;
      float bv = bias ? ldin(bias, boff + col, isbf) : 0.f;
#pragma unroll
      for (int r = 0; r < 4; ++r) {
        int row = row0 + r;
        if (row >= M) continue;
        float v = accs[mi][ni][r] + bv;
        if (act == 1) v = fmaxf(v, 0.f);
        else if (act == 2) {
          float u = 0.7978845608028654f * (v + 0.044715f * v * v * v);
          v = 0.5f * v * (1.f + tanhf(u));
        } else if (act == 3) {
          v = v / (1.f + expf(-v));
        }
        size_t idx = (size_t)row * N + col;
        if (oty) ((bf16*)C)[idx] = __float2bfloat16(v);
        else { if (accum) ((float*)C)[idx] += v; else ((float*)C)[idx] = v; }
      }
    }
  }
}

__global__ __launch_bounds__(256) void gemm_mfma(
    const void* A, int aty, const void* W, size_t woff,
    const void* bias, size_t boff, void* C, int oty,
    int M, int N, int K, int act, int accum, const int* __restrict__ flagp)
{
  gemm_body(A, aty, W, woff, bias, boff, C, oty, M, N, K, act, accum, *flagp != 0);
}

// 3 GEMMs sharing A and shapes (QKV); blockIdx.z selects job
__global__ __launch_bounds__(256) void gemm_mfma_tri(
    const void* A, int aty, const void* W0, const void* W1, const void* W2p,
    size_t woff, void* C0, void* C1, void* C2, int oty,
    int M, int N, int K, const int* __restrict__ flagp)
{
  const void* W = blockIdx.z == 0 ? W0 : (blockIdx.z == 1 ? W1 : W2p);
  void* C = blockIdx.z == 0 ? C0 : (blockIdx.z == 1 ? C1 : C2);
  gemm_body(A, aty, W, woff, nullptr, 0, C, oty, M, N, K, 0, 0, *flagp != 0);
}

// 2 GEMMs with separate A/W/bias/C, shared shapes
__global__ __launch_bounds__(256) void gemm_mfma_duo(
    const void* A0, const void* A1, int aty, const void* W0, const void* W1,
    const void* bias0, const void* bias1, void* C0, void* C1, int oty,
    int M, int N, int K, const int* __restrict__ flagp)
{
  const void* A = blockIdx.z == 0 ? A0 : A1;
  const void* W = blockIdx.z == 0 ? W0 : W1;
  const void* bias = blockIdx.z == 0 ? bias0 : bias1;
  void* C = blockIdx.z == 0 ? C0 : C1;
  gemm_body(A, aty, W, 0, bias, 0, C, oty, M, N, K, 0, 0, *flagp != 0);
}

// ---------------------------------------------------------------------------
// f32 GEMM (only for the N=2 coords projection)
// ---------------------------------------------------------------------------
__global__ __launch_bounds__(256) void gemm_k(
    const float* __restrict__ A, const void* __restrict__ W, size_t woff,
    const void* __restrict__ bias, size_t boff, float* __restrict__ C,
    int M, int N, int K, const int* __restrict__ flagp)
{
  const bool isbf = *flagp != 0;
  __shared__ float As[16][68];
  __shared__ float Ws[16][68];
  const int bm = blockIdx.y * 64, bn = blockIdx.x * 64;
  const int tx = threadIdx.x, ty = threadIdx.y;
  const int tid = ty * 16 + tx;
  float acc[4][4] = {};
  for (int k0 = 0; k0 < K; k0 += 16) {
#pragma unroll
    for (int i = 0; i < 4; ++i) {
      int idx = tid + i * 256;
      int m  = idx >> 4, k = idx & 15;
      int gm = bm + m;
      As[k][m] = (gm < M) ? A[(size_t)gm * K + k0 + k] : 0.f;
      int kk = idx >> 6, n = idx & 63;
      int gn = bn + n;
      Ws[kk][n] = (gn < N) ? ldin(W, woff + (size_t)(k0 + kk) * N + gn, isbf) : 0.f;
    }
    __syncthreads();
#pragma unroll
    for (int k = 0; k < 16; ++k) {
      float4 a4 = *reinterpret_cast<const float4*>(&As[k][ty * 4]);
      float4 w4 = *reinterpret_cast<const float4*>(&Ws[k][tx * 4]);
      float a[4] = {a4.x, a4.y, a4.z, a4.w};
      float w[4] = {w4.x, w4.y, w4.z, w4.w};
#pragma unroll
      for (int i = 0; i < 4; ++i)
#pragma unroll
        for (int j = 0; j < 4; ++j)
          acc[i][j] = fmaf(a[i], w[j], acc[i][j]);
    }
    __syncthreads();
  }
#pragma unroll
  for (int i = 0; i < 4; ++i) {
    int gm = bm + ty * 4 + i;
    if (gm >= M) continue;
#pragma unroll
    for (int j = 0; j < 4; ++j) {
      int gn = bn + tx * 4 + j;
      if (gn >= N) continue;
      float v = acc[i][j];
      if (bias) v += ldin(bias, boff + gn, isbf);
      C[(size_t)gm * N + gn] = v;
    }
  }
}

// ---------------------------------------------------------------------------
// Patch extraction (im2col) -> bf16
// ---------------------------------------------------------------------------
__global__ void patchify_k(const void* __restrict__ img, unsigned short* __restrict__ xp,
                           const int* __restrict__ flagp) {
  const bool isbf = *flagp != 0;
  int i = blockIdx.x * 256 + threadIdx.x;
  if (i >= NB * HWT * 768) return;
  int col = i % 768, row = i / 768;
  int c = col % 3, p2 = (col / 3) & 15, p1 = col / 48;
  int w = row & 15, h = (row >> 4) & 15, b = row >> 8;
  xp[i] = f2bu(ldin(img, (((size_t)(b * 3 + c) * 256 + h * 16 + p1) * 256) + w * 16 + p2, isbf));
}

__global__ void addpos_k(float* __restrict__ tok, const void* __restrict__ hp,
                         const void* __restrict__ wp, const int* __restrict__ flagp) {
  const bool isbf = *flagp != 0;
  int i = blockIdx.x * 256 + threadIdx.x;
  if (i >= NB * HWT * DIM) return;
  int d = i & 511;
  int row = i >> 9;
  int w = row & 15, h = (row >> 4) & 15;
  tok[i] += ldin(hp, h * DIM + d, isbf) + ldin(wp, w * DIM + d, isbf);
}

// ---------------------------------------------------------------------------
// LayerNorm (bf16 out) / RMSNorm (bf16 out) over 512-dim rows
// ---------------------------------------------------------------------------
__global__ void ln512_k(const float* __restrict__ X, const void* __restrict__ g,
                        const void* __restrict__ b, unsigned short* __restrict__ Y,
                        const int* __restrict__ flagp) {
  const bool isbf = *flagp != 0;
  int row = blockIdx.x, t = threadIdx.x;
  const float* x = X + (size_t)row * DIM;
  float v0 = x[t], v1 = x[t + 256];
  __shared__ float rs[256], rq[256];
  rs[t] = v0 + v1; rq[t] = v0 * v0 + v1 * v1;
  __syncthreads();
  for (int o = 128; o > 0; o >>= 1) {
    if (t < o) { rs[t] += rs[t + o]; rq[t] += rq[t + o]; }
    __syncthreads();
  }
  float mean = rs[0] * (1.f / 512.f);
  float var  = rq[0] * (1.f / 512.f) - mean * mean;
  float inv  = rsqrtf(var + 1e-5f);
  unsigned short* y = Y + (size_t)row * DIM;
  y[t]       = f2bu((v0 - mean) * inv * ldin(g, t, isbf)       + ldin(b, t, isbf));
  y[t + 256] = f2bu((v1 - mean) * inv * ldin(g, t + 256, isbf) + ldin(b, t + 256, isbf));
}

__global__ void rms512_k(const float* __restrict__ X, const void* __restrict__ g,
                         int goff, unsigned short* __restrict__ Y, const int* __restrict__ flagp) {
  const bool isbf = *flagp != 0;
  int row = blockIdx.x, t = threadIdx.x;
  const float* x = X + (size_t)row * DIM;
  float v0 = x[t], v1 = x[t + 256];
  __shared__ float rq[256];
  rq[t] = v0 * v0 + v1 * v1;
  __syncthreads();
  for (int o = 128; o > 0; o >>= 1) {
    if (t < o) rq[t] += rq[t + o];
    __syncthreads();
  }
  float nrm = sqrtf(rq[0]);
  float sc = 22.62741699796952f / fmaxf(nrm, 1e-12f);
  unsigned short* y = Y + (size_t)row * DIM;
  y[t]       = f2bu(v0 * sc * ldin(g, goff + t, isbf));
  y[t + 256] = f2bu(v1 * sc * ldin(g, goff + t + 256, isbf));
}

// ---------------------------------------------------------------------------
// Slot attention pieces
// ---------------------------------------------------------------------------
__global__ void slots_init_k(const void* __restrict__ mu, const void* __restrict__ ls,
                             const void* __restrict__ noise, float* __restrict__ slots,
                             const int* __restrict__ flagp) {
  const bool isbf = *flagp != 0;
  int i = blockIdx.x * 256 + threadIdx.x;
  if (i >= NB * NSL * DIM) return;
  int d = i & 511;
  slots[i] = ldin(mu, d, isbf) + expf(ldin(ls, d, isbf)) * ldin(noise, i, isbf);
}

__global__ void slot_dots_k(const float* __restrict__ q, const float* __restrict__ k,
                            float* __restrict__ dots) {
  int blk = blockIdx.x;                 // b*200 + h*50 + i
  int i = blk % 50, h = (blk / 50) & 3, b = blk / 200;
  int j = threadIdx.x;
  __shared__ float qs[64];
  if (threadIdx.x < 64) qs[threadIdx.x] = q[((size_t)(b * 50 + i)) * 256 + h * 64 + threadIdx.x];
  __syncthreads();
  const float* kr = k + ((size_t)(b * 256 + j)) * 256 + h * 64;
  float s = 0.f;
#pragma unroll 8
  for (int d = 0; d < 64; ++d) s = fmaf(qs[d], kr[d], s);
  dots[(((size_t)(b * 4 + h) * 50) + i) * 256 + j] = s * 0.125f;
}

__global__ void softmax_slots_k(float* __restrict__ dots) {
  int idx = blockIdx.x * 256 + threadIdx.x;
  if (idx >= 4096) return;
  int j = idx & 255, h = (idx >> 8) & 3, b = idx >> 10;
  float* base = dots + ((size_t)(b * 4 + h) * 50) * 256 + j;
  float m = -1e30f;
  for (int i = 0; i < 50; ++i) m = fmaxf(m, base[i * 256]);
  float s = 0.f;
  for (int i = 0; i < 50; ++i) { float e = expf(base[i * 256] - m); base[i * 256] = e; s += e; }
  float inv = 1.f / s;
  for (int i = 0; i < 50; ++i) base[i * 256] *= inv;
}

__global__ void renorm_attn_k(float* __restrict__ attn) {
  int t = threadIdx.x;
  float* row = attn + (size_t)blockIdx.x * 256;
  float v = row[t] + 1e-8f;
  __shared__ float rs[256];
  rs[t] = v;
  __syncthreads();
  for (int o = 128; o > 0; o >>= 1) {
    if (t < o) rs[t] += rs[t + o];
    __syncthreads();
  }
  row[t] = v / rs[0];
}

__global__ void slot_upd_k(const float* __restrict__ attn, const float* __restrict__ v,
                           float* __restrict__ upd) {
  int bi = blockIdx.x;        // b*50+i
  int b = bi / 50, i = bi % 50;
  int t = threadIdx.x, h = t >> 6;
  const float* arow = attn + ((size_t)((b * 4 + h) * 50) + i) * 256;
  float s = 0.f;
  for (int j = 0; j < 256; ++j) s = fmaf(arow[j], v[((size_t)(b * 256 + j)) * 256 + t], s);
  upd[(size_t)bi * 256 + t] = s;
}

// in-place safe: prev==slots allowed (elementwise)
__global__ void gru_k(const float* __restrict__ gx, const float* __restrict__ gh,
                      float* __restrict__ slots) {
  int i = blockIdx.x * 256 + threadIdx.x;
  if (i >= NB * NSL * DIM) return;
  int row = i >> 9, d = i & 511;
  size_t b3 = (size_t)row * 1536;
  float xr = gx[b3 + d], xz = gx[b3 + 512 + d], xn = gx[b3 + 1024 + d];
  float hr = gh[b3 + d], hz = gh[b3 + 512 + d], hn = gh[b3 + 1024 + d];
  float r = 1.f / (1.f + expf(-(xr + hr)));
  float z = 1.f / (1.f + expf(-(xz + hz)));
  float n = tanhf(xn + r * hn);
  float prev = slots[i];
  slots[i] = (1.f - z) * n + z * prev;
}

// ---------------------------------------------------------------------------
// Rel-pos bias
// ---------------------------------------------------------------------------
__global__ void build_coords_k(const float* __restrict__ sc, float* __restrict__ coords) {
  int i = blockIdx.x * 256 + threadIdx.x;
  if (i >= NB * NT) return;
  int b = i / NT, n = i % NT;
  float cx, cy;
  if (n < NSL) { cx = sc[(b * NSL + n) * 2]; cy = sc[(b * NSL + n) * 2 + 1]; }
  else { int t = n - NSL; cx = (float)(t >> 4); cy = (float)(t & 15); }
  coords[i * 2] = cx; coords[i * 2 + 1] = cy;
}

__global__ void relpos_table_k(const void* w1, const void* b1, const void* w2,
                               const void* b2, const void* w3, const void* b3,
                               float* __restrict__ tab, const int* __restrict__ flagp) {
  const bool isbf = *flagp != 0;
  int blk = blockIdx.x;  // 961
  float r0 = (float)(blk / 31 - 15), r1 = (float)(blk % 31 - 15);
  int t = threadIdx.x;
  __shared__ float h1[128], h2[128];
  float a = fmaf(r0, ldin(w1, t, isbf), fmaf(r1, ldin(w1, 128 + t, isbf), ldin(b1, t, isbf)));
  h1[t] = a / (1.f + expf(-a));
  __syncthreads();
  float s = ldin(b2, t, isbf);
#pragma unroll 4
  for (int k = 0; k < 128; ++k) s = fmaf(h1[k], ldin(w2, k * 128 + t, isbf), s);
  h2[t] = s / (1.f + expf(-s));
  __syncthreads();
  if (t < 8) {
    float o = ldin(b3, t, isbf);
#pragma unroll 4
    for (int k = 0; k < 128; ++k) o = fmaf(h2[k], ldin(w3, k * 8 + t, isbf), o);
    tab[blk * 8 + t] = o;
  }
}

__global__ void bias_fill_k(const float* __restrict__ tab, float* __restrict__ bias) {
  int i = blockIdx.x * 256 + threadIdx.x;
  if (i >= NB * NH * HWT * HWT) return;
  int jj = i & 255, ii = (i >> 8) & 255, h = (i >> 16) & 7, b = i >> 19;
  int di = (ii >> 4) - (jj >> 4) + 15;
  int dj = (ii & 15) - (jj & 15) + 15;
  bias[(((size_t)(b * NH + h) * NT) + NSL + ii) * NT + NSL + jj] = tab[(di * 31 + dj) * 8 + h];
}

// layer1 silu -> H1 bf16 [pcount,128], chunked
__global__ void rp_l1_k(const float* __restrict__ coords, const void* w1, const void* b1,
                        unsigned short* __restrict__ H, int pbase, int pcount,
                        const int* __restrict__ flagp) {
  const bool isbf = *flagp != 0;
  int idx = blockIdx.x * 256 + threadIdx.x;
  if (idx >= pcount * 128) return;
  int pl = idx >> 7, u = idx & 127;
  int p = pbase + pl;
  int q = p % RPP, bb = p / RPP;
  int ii, jj;
  rp_decode(q, ii, jj);
  float r0 = coords[(bb * NT + ii) * 2]     - coords[(bb * NT + jj) * 2];
  float r1 = coords[(bb * NT + ii) * 2 + 1] - coords[(bb * NT + jj) * 2 + 1];
  float a = fmaf(r0, ldin(w1, u, isbf), fmaf(r1, ldin(w1, 128 + u, isbf), ldin(b1, u, isbf)));
  H[(size_t)pl * 128 + u] = f2bu(a / (1.f + expf(-a)));
}

// layer3 (128->8) + scatter. 32 pairs/block, 8 threads/pair.
__global__ __launch_bounds__(256) void rp_l3_k(
    const unsigned short* __restrict__ H2, const void* w3, const void* b3,
    float* __restrict__ bias, int pbase, int pcount, const int* __restrict__ flagp) {
  const bool isbf = *flagp != 0;
  __shared__ float W3s[128 * 8];
  int t = threadIdx.x;
  for (int e = t; e < 1024; e += 256) W3s[e] = ldin(w3, e, isbf);
  __syncthreads();
  int pl = blockIdx.x * 32 + (t >> 3), hh = t & 7;
  if (pl >= pcount) return;
  int p = pbase + pl;
  int q = p % RPP, bb = p / RPP;
  int ii, jj;
  rp_decode(q, ii, jj);
  float s = ldin(b3, hh, isbf);
  const unsigned short* hrow = H2 + (size_t)pl * 128;
#pragma unroll 8
  for (int k = 0; k < 128; ++k) {
    bf16 hv = *reinterpret_cast<const bf16*>(&hrow[k]);
    s = fmaf(b2f(hv), W3s[k * 8 + hh], s);
  }
  bias[((size_t)(bb * NH + hh) * NT + ii) * NT + jj] = s;
}

// ---------------------------------------------------------------------------
// Transformer pieces
// ---------------------------------------------------------------------------
__global__ void build_x_k(const float* __restrict__ slots, const float* __restrict__ tok,
                          float* __restrict__ x) {
  int i = blockIdx.x * 256 + threadIdx.x;
  if (i >= NB * NT * DIM) return;
  int d = i & 511, n = (i >> 9) % NT, b = i / (NT * DIM);
  x[i] = (n < NSL) ? slots[((size_t)(b * NSL + n)) * DIM + d]
                   : tok[((size_t)(b * HWT + (n - NSL))) * DIM + d];
}

// SIM[bh,i,j] = 0.125 * Q·K + bias, MFMA. grid (5,5,32)
__global__ __launch_bounds__(256) void attn_sim_k(
    const unsigned short* __restrict__ Qb, const unsigned short* __restrict__ Kb,
    const float* __restrict__ bias, float* __restrict__ sim)
{
  const int bh = blockIdx.z, b = bh >> 3, h = bh & 7;
  const int bm = blockIdx.y * 64, bn = blockIdx.x * 64;
  __shared__ unsigned short As[64 * 72];
  __shared__ unsigned short Bs[64 * 72];
  const int tid = threadIdx.x;
  const int lane = tid & 63, wave = tid >> 6, quad = lane >> 4, ti = lane & 15;
  const int wm = (wave & 1) * 32, wn = (wave >> 1) * 32;
  {
    // each thread stages 16 shorts of Q and 16 of K (4 threads x 16 = 64/row)
    int r = tid >> 2, c = (tid & 3) * 16;
    ushort4 z4 = {0,0,0,0};
    ushort4 a[4] = {z4, z4, z4, z4}, bq[4] = {z4, z4, z4, z4};
    int gi = bm + r, gj = bn + r;
    if (gi < NT) {
      const ushort4* p = reinterpret_cast<const ushort4*>(Qb + ((size_t)(b * NT + gi)) * DIM + h * 64 + c);
#pragma unroll
      for (int i = 0; i < 4; ++i) a[i] = p[i];
    }
    if (gj < NT) {
      const ushort4* p = reinterpret_cast<const ushort4*>(Kb + ((size_t)(b * NT + gj)) * DIM + h * 64 + c);
#pragma unroll
      for (int i = 0; i < 4; ++i) bq[i] = p[i];
    }
#pragma unroll
    for (int i = 0; i < 4; ++i) {
      *reinterpret_cast<ushort4*>(&As[r * 72 + c + i * 4]) = a[i];
      *reinterpret_cast<ushort4*>(&Bs[r * 72 + c + i * 4]) = bq[i];
    }
  }
  __syncthreads();
  float4v acc00 = {0,0,0,0}, acc01 = {0,0,0,0}, acc10 = {0,0,0,0}, acc11 = {0,0,0,0};
#pragma unroll
  for (int ks = 0; ks < 2; ++ks) {
    short8v a0 = *reinterpret_cast<const short8v*>(&As[(wm + ti)      * 72 + ks * 32 + quad * 8]);
    short8v a1 = *reinterpret_cast<const short8v*>(&As[(wm + 16 + ti) * 72 + ks * 32 + quad * 8]);
    short8v b0 = *reinterpret_cast<const short8v*>(&Bs[(wn + ti)      * 72 + ks * 32 + quad * 8]);
    short8v b1 = *reinterpret_cast<const short8v*>(&Bs[(wn + 16 + ti) * 72 + ks * 32 + quad * 8]);
    acc00 = __builtin_amdgcn_mfma_f32_16x16x32_bf16(a0, b0, acc00, 0, 0, 0);
    acc01 = __builtin_amdgcn_mfma_f32_16x16x32_bf16(a0, b1, acc01, 0, 0, 0);
    acc10 = __builtin_amdgcn_mfma_f32_16x16x32_bf16(a1, b0, acc10, 0, 0, 0);
    acc11 = __builtin_amdgcn_mfma_f32_16x16x32_bf16(a1, b1, acc11, 0, 0, 0);
  }
  float4v accs[2][2] = {{acc00, acc01}, {acc10, acc11}};
#pragma unroll
  for (int mi = 0; mi < 2; ++mi) {
#pragma unroll
    for (int ni = 0; ni < 2; ++ni) {
      int row0 = bm + wm + mi * 16 + quad * 4;
      int col  = bn + wn + ni * 16 + ti;
      if (col >= NT) continue;
#pragma unroll
      for (int r = 0; r < 4; ++r) {
        int row = row0 + r;
        if (row >= NT) continue;
        size_t idx = ((size_t)bh * NT + row) * NT + col;
        sim[idx] = accs[mi][ni][r] * 0.125f + bias[idx];
      }
    }
  }
}

// row softmax over 306, writes bf16 prob padded to 320 (zero pad)
__global__ void softmax_prob_k(const float* __restrict__ sim, unsigned short* __restrict__ prob) {
  int row = blockIdx.x;       // bh*NT + i
  const float* src = sim + (size_t)row * NT;
  unsigned short* dst = prob + (size_t)row * 320;
  int t = threadIdx.x;
  float v0 = (t < NT) ? src[t] : -1e30f;
  float v1 = (t + 256 < NT) ? src[t + 256] : -1e30f;
  __shared__ float rb[256];
  rb[t] = fmaxf(v0, v1);
  __syncthreads();
  for (int o = 128; o > 0; o >>= 1) {
    if (t < o) rb[t] = fmaxf(rb[t], rb[t + o]);
    __syncthreads();
  }
  float m = rb[0];
  __syncthreads();
  float e0 = (t < NT) ? expf(v0 - m) : 0.f;
  float e1 = (t + 256 < NT) ? expf(v1 - m) : 0.f;
  rb[t] = e0 + e1;
  __syncthreads();
  for (int o = 128; o > 0; o >>= 1) {
    if (t < o) rb[t] += rb[t + o];
    __syncthreads();
  }
  float inv = 1.f / rb[0];
  dst[t] = f2bu(e0 * inv);
  if (t + 256 < 320) dst[t + 256] = f2bu(t + 256 < NT ? e1 * inv : 0.f);
}

// OB = P @ V, MFMA. grid (5, 32): x=i-tile, y=bh. K=320 (prob pad zero)
__global__ __launch_bounds__(256) void attn_av_k(
    const unsigned short* __restrict__ prob, const unsigned short* __restrict__ Vb,
    unsigned short* __restrict__ Ob)
{
  const int bh = blockIdx.y, b = bh >> 3, h = bh & 7;
  const int bm = blockIdx.x * 64;
  __shared__ unsigned short As[64 * LDT];
  __shared__ unsigned short Bs[64 * LDT];
  const int tid = threadIdx.x;
  const int lane = tid & 63, wave = tid >> 6, quad = lane >> 4, ti = lane & 15;
  const int wm = (wave & 1) * 32, wn = (wave >> 1) * 32;
  const int arow = tid >> 2, ach = (tid & 3) * 8;
  const int bk = tid & 31, bch = tid >> 5;

  float4v acc00 = {0,0,0,0}, acc01 = {0,0,0,0}, acc10 = {0,0,0,0}, acc11 = {0,0,0,0};

  for (int k0 = 0; k0 < 320; k0 += 32) {
    {
      int gi = bm + arow;
      ushort4 u0 = {0,0,0,0}, u1 = {0,0,0,0};
      if (gi < NT) {
        const ushort4* p = reinterpret_cast<const ushort4*>(
            prob + ((size_t)bh * NT + gi) * 320 + k0 + ach);
        u0 = p[0]; u1 = p[1];
      }
      *reinterpret_cast<ushort4*>(&As[arow * LDT + ach])     = u0;
      *reinterpret_cast<ushort4*>(&As[arow * LDT + ach + 4]) = u1;
    }
    {
      int j = k0 + bk;
      unsigned short h8[8];
      if (j < NT) {
        const ushort4* p = reinterpret_cast<const ushort4*>(
            Vb + ((size_t)(b * NT + j)) * DIM + h * 64 + bch * 8);
        ushort4 u0 = p[0], u1 = p[1];
        h8[0]=u0.x; h8[1]=u0.y; h8[2]=u0.z; h8[3]=u0.w; h8[4]=u1.x; h8[5]=u1.y; h8[6]=u1.z; h8[7]=u1.w;
      } else {
#pragma unroll
        for (int i = 0; i < 8; ++i) h8[i] = 0;
      }
#pragma unroll
      for (int i = 0; i < 8; ++i) Bs[(bch * 8 + i) * LDT + bk] = h8[i];
    }
    __syncthreads();
    short8v a0 = *reinterpret_cast<const short8v*>(&As[(wm + ti)      * LDT + quad * 8]);
    short8v a1 = *reinterpret_cast<const short8v*>(&As[(wm + 16 + ti) * LDT + quad * 8]);
    short8v b0 = *reinterpret_cast<const short8v*>(&Bs[(wn + ti)      * LDT + quad * 8]);
    short8v b1 = *reinterpret_cast<const short8v*>(&Bs[(wn + 16 + ti) * LDT + quad * 8]);
    acc00 = __builtin_amdgcn_mfma_f32_16x16x32_bf16(a0, b0, acc00, 0, 0, 0);
    acc01 = __builtin_amdgcn_mfma_f32_16x16x32_bf16(a0, b1, acc01, 0, 0, 0);
    acc10 = __builtin_amdgcn_mfma_f32_16x16x32_bf16(a1, b0, acc10, 0, 0, 0);
    acc11 = __builtin_amdgcn_mfma_f32_16x16x32_bf16(a1, b1, acc11, 0, 0, 0);
    __syncthreads();
  }
  float4v accs[2][2] = {{acc00, acc01}, {acc10, acc11}};
#pragma unroll
  for (int mi = 0; mi < 2; ++mi) {
#pragma unroll
    for (int ni = 0; ni < 2; ++ni) {
      int row0 = bm + wm + mi * 16 + quad * 4;
      int col  = wn + ni * 16 + ti;
#pragma unroll
      for (int r = 0; r < 4; ++r) {
        int row = row0 + r;
        if (row >= NT) continue;
        Ob[((size_t)(b * NT + row)) * DIM + h * 64 + col] = f2bu(accs[mi][ni][r]);
      }
    }
  }
}

__global__ void write_out_k(const float* __restrict__ tmp, void* __restrict__ out,
                            const int* __restrict__ flagp) {
  const bool isbf = *flagp != 0;
  int i = blockIdx.x * 256 + threadIdx.x;
  if (i >= NB * HWT * DIM) return;
  int d = i & 511, tt = (i >> 9) & 255, b = i / (HWT * DIM);
  float v = tmp[((size_t)(b * NT + NSL + tt)) * DIM + d];
  if (isbf) ((bf16*)out)[i] = __float2bfloat16(v);
  else      ((float*)out)[i] = v;
}

// ---------------------------------------------------------------------------
extern "C" void kernel_launch(void* const* d_in, const int* in_sizes, int n_in,
                              void* d_out, int out_size, void* d_ws, size_t ws_size,
                              hipStream_t stream) {
  const void* images        = d_in[0];
  const void* slot_noise    = d_in[1];
  const void* patch_w       = d_in[2];
  const void* patch_b       = d_in[3];
  const void* hpos          = d_in[4];
  const void* wpos          = d_in[5];
  const void* rp_w1         = d_in[6];
  const void* rp_b1         = d_in[7];
  const void* rp_w2         = d_in[8];
  const void* rp_b2         = d_in[9];
  const void* rp_w3         = d_in[10];
  const void* rp_b3         = d_in[11];
  const void* slots_mu      = d_in[12];
  const void* slots_logsig  = d_in[13];
  const void* sa_ln_in_g    = d_in[14];
  const void* sa_ln_in_b    = d_in[15];
  const void* sa_ln_sl_g    = d_in[16];
  const void* sa_ln_sl_b    = d_in[17];
  const void* sa_wq         = d_in[18];
  const void* sa_bq         = d_in[19];
  const void* sa_wk         = d_in[20];
  const void* sa_bk         = d_in[21];
  const void* sa_wv         = d_in[22];
  const void* sa_bv         = d_in[23];
  const void* sa_wo         = d_in[24];
  const void* sa_bo         = d_in[25];
  const void* gru_wih       = d_in[26];
  const void* gru_whh       = d_in[27];
  const void* gru_bih       = d_in[28];
  const void* gru_bhh       = d_in[29];
  const void* sa_ln_ff_g    = d_in[30];
  const void* sa_ln_ff_b    = d_in[31];
  const void* sa_mlp_w1     = d_in[32];
  const void* sa_mlp_b1     = d_in[33];
  const void* sa_mlp_w2     = d_in[34];
  const void* sa_mlp_b2     = d_in[35];
  const void* s2c_w         = d_in[36];
  const void* s2c_b         = d_in[37];
  const void* attn_g        = d_in[38];
  const void* wq            = d_in[39];
  const void* wk            = d_in[40];
  const void* wv            = d_in[41];
  const void* wo            = d_in[42];
  const void* ff_g          = d_in[43];
  const void* ff_w1         = d_in[44];
  const void* ff_b1         = d_in[45];
  const void* ff_w2         = d_in[46];
  const void* ff_b2         = d_in[47];
  const void* final_g       = d_in[48];
  const void* pred_w        = d_in[49];
  const void* pred_b        = d_in[50];

  float* ws = (float*)d_ws;
  int* FLAG = (int*)ws;
  size_t off = 16;
  auto alloc = [&](size_t n) { float* p = ws + off; off += n; return p; };
  unsigned short* XPB  = (unsigned short*)alloc((size_t)NB * HWT * 768 / 2);
  float* TOK   = alloc((size_t)NB * HWT * DIM);
  unsigned short* INPB = (unsigned short*)alloc((size_t)NB * HWT * DIM / 2);
  float* KB    = alloc((size_t)NB * HWT * 256);
  float* VB    = alloc((size_t)NB * HWT * 256);
  float* SLOTS = alloc((size_t)NB * NSL * DIM);
  unsigned short* SLNB = (unsigned short*)alloc((size_t)NB * NSL * DIM / 2);
  float* QB    = alloc((size_t)NB * NSL * 256);
  float* ATT   = alloc((size_t)NB * 4 * NSL * HWT);
  float* UPD   = alloc((size_t)NB * NSL * 256);
  float* UPDP  = alloc((size_t)NB * NSL * DIM);
  float* GX    = alloc((size_t)NB * NSL * 1536);
  float* GH    = alloc((size_t)NB * NSL * 1536);
  unsigned short* HIDSB = (unsigned short*)alloc((size_t)NB * NSL * DIM / 2);
  float* SC    = alloc((size_t)NB * NSL * 2);
  float* CRD   = alloc((size_t)NB * NT * 2);
  float* TAB   = alloc((size_t)961 * 8);
  float* BIAS  = alloc((size_t)NB * NH * NT * NT);
  float* X     = alloc((size_t)NB * NT * DIM);
  // attention-region buffers (contiguous; aliased by rel-pos H1/H2 chunks)
  unsigned short* HBB  = (unsigned short*)alloc((size_t)NB * NT * DIM / 2);
  unsigned short* QHB  = (unsigned short*)alloc((size_t)NB * NT * DIM / 2);
  unsigned short* KHB  = (unsigned short*)alloc((size_t)NB * NT * DIM / 2);
  unsigned short* VHB  = (unsigned short*)alloc((size_t)NB * NT * DIM / 2);
  float* SIM   = alloc((size_t)NB * NH * NT * NT);
  unsigned short* PROBB = (unsigned short*)alloc((size_t)NB * NH * NT * 320 / 2);
  unsigned short* OBB  = (unsigned short*)alloc((size_t)NB * NT * DIM / 2);
  unsigned short* FFHB = (unsigned short*)alloc((size_t)NB * NT * FF / 2);
  float* OUTT  = alloc((size_t)NB * NT * DIM);
  (void)ws_size; (void)in_sizes; (void)n_in; (void)out_size;

#define GEMMM(A_, ATY_, W_, WOFF_, BIAS_, BOFF_, C_, OTY_, M_, N_, K_, ACT_, ACC_) \
  gemm_mfma<<<dim3((N_)/64, CDIV((M_),64)), 256, 0, stream>>>( \
      A_, ATY_, W_, (size_t)(WOFF_), BIAS_, (size_t)(BOFF_), C_, OTY_, M_, N_, K_, ACT_, ACC_, FLAG)

  const int MROW = NB * NT;   // 1224
  const int MS   = NB * NSL;  // 200

  // ---- dtype detection ----
  detect_k<<<1, 256, 0, stream>>>(images, FLAG);

  // ---- patch embed ----
  patchify_k<<<CDIV(NB*HWT*768, 256), 256, 0, stream>>>(images, XPB, FLAG);
  GEMMM(XPB, 1, patch_w, 0, patch_b, 0, TOK, 0, NB*HWT, DIM, 768, 0, 0);
  addpos_k<<<CDIV(NB*HWT*DIM, 256), 256, 0, stream>>>(TOK, hpos, wpos, FLAG);

  // ---- slot attention: k, v ----
  ln512_k<<<NB*HWT, 256, 0, stream>>>(TOK, sa_ln_in_g, sa_ln_in_b, INPB, FLAG);
  gemm_mfma_duo<<<dim3(256/64, CDIV(NB*HWT,64), 2), 256, 0, stream>>>(
      INPB, INPB, 1, sa_wk, sa_wv, sa_bk, sa_bv, KB, VB, 0, NB*HWT, 256, DIM, FLAG);
  slots_init_k<<<CDIV(NB*NSL*DIM, 256), 256, 0, stream>>>(slots_mu, slots_logsig, slot_noise, SLOTS, FLAG);

  for (int it = 0; it < 3; ++it) {
    ln512_k<<<MS, 256, 0, stream>>>(SLOTS, sa_ln_sl_g, sa_ln_sl_b, SLNB, FLAG);
    GEMMM(SLNB, 1, sa_wq, 0, sa_bq, 0, QB, 0, MS, 256, DIM, 0, 0);
    slot_dots_k<<<NB*4*NSL, 256, 0, stream>>>(QB, KB, ATT);
    softmax_slots_k<<<16, 256, 0, stream>>>(ATT);
    renorm_attn_k<<<NB*4*NSL, 256, 0, stream>>>(ATT);
    slot_upd_k<<<MS, 256, 0, stream>>>(ATT, VB, UPD);
    GEMMM(UPD, 0, sa_wo, 0, sa_bo, 0, UPDP, 0, MS, DIM, 256, 0, 0);
    gemm_mfma_duo<<<dim3(1536/64, CDIV(MS,64), 2), 256, 0, stream>>>(
        UPDP, SLOTS, 0, gru_wih, gru_whh, gru_bih, gru_bhh, GX, GH, 0, MS, 1536, DIM, FLAG);
    gru_k<<<CDIV(NB*NSL*DIM, 256), 256, 0, stream>>>(GX, GH, SLOTS);
    ln512_k<<<MS, 256, 0, stream>>>(SLOTS, sa_ln_ff_g, sa_ln_ff_b, SLNB, FLAG);
    GEMMM(SLNB, 1, sa_mlp_w1, 0, sa_mlp_b1, 0, HIDSB, 1, MS, DIM, DIM, 1, 0);
    GEMMM(HIDSB, 1, sa_mlp_w2, 0, sa_mlp_b2, 0, SLOTS, 0, MS, DIM, DIM, 0, 1);
  }

  // ---- rel-pos bias ----
  gemm_k<<<dim3(1, CDIV(MS,64)), dim3(16,16), 0, stream>>>(
      SLOTS, s2c_w, 0, s2c_b, 0, SC, MS, 2, DIM, FLAG);
  build_coords_k<<<CDIV(NB*NT, 256), 256, 0, stream>>>(SC, CRD);
  relpos_table_k<<<961, 128, 0, stream>>>(rp_w1, rp_b1, rp_w2, rp_b2, rp_w3, rp_b3, TAB, FLAG);
  bias_fill_k<<<CDIV(NB*NH*HWT*HWT, 256), 256, 0, stream>>>(TAB, BIAS);
  // mixed pairs: L1 elementwise -> H1, L2 as MFMA GEMM -> H2, L3 + scatter.
  // H1/H2 chunks alias the (dead) attention region starting at HBB.
  {
    unsigned short* H1 = HBB;
    unsigned short* H2 = HBB + (size_t)PCH * 128;
    for (int c = 0; c < 2; ++c) {
      int pb = c * PCH;
      rp_l1_k<<<CDIV(PCH*128, 256), 256, 0, stream>>>(CRD, rp_w1, rp_b1, H1, pb, PCH, FLAG);
      gemm_mfma<<<dim3(2, CDIV(PCH,64)), 256, 0, stream>>>(
          H1, 1, rp_w2, 0, rp_b2, 0, H2, 1, PCH, 128, 128, 3, 0, FLAG);
      rp_l3_k<<<CDIV(PCH,32), 256, 0, stream>>>(H2, rp_w3, rp_b3, BIAS, pb, PCH, FLAG);
    }
  }

  // ---- transformer ----
  build_x_k<<<CDIV(NB*NT*DIM, 256), 256, 0, stream>>>(SLOTS, TOK, X);
  for (int l = 0; l < 6; ++l) {
    size_t woff = (size_t)l * DIM * DIM;
    rms512_k<<<MROW, 256, 0, stream>>>(X, attn_g, l * DIM, HBB, FLAG);
    gemm_mfma_tri<<<dim3(DIM/64, CDIV(MROW,64), 3), 256, 0, stream>>>(
        HBB, 1, wq, wk, wv, woff, QHB, KHB, VHB, 1, MROW, DIM, DIM, FLAG);
    attn_sim_k<<<dim3(CDIV(NT,64), CDIV(NT,64), NB*NH), 256, 0, stream>>>(QHB, KHB, BIAS, SIM);
    softmax_prob_k<<<NB*NH*NT, 256, 0, stream>>>(SIM, PROBB);
    attn_av_k<<<dim3(CDIV(NT,64), NB*NH), 256, 0, stream>>>(PROBB, VHB, OBB);
    GEMMM(OBB, 1, wo, woff, (const void*)nullptr, 0, X, 0, MROW, DIM, DIM, 0, 1);
    rms512_k<<<MROW, 256, 0, stream>>>(X, ff_g, l * DIM, HBB, FLAG);
    GEMMM(HBB, 1, ff_w1, (size_t)l * DIM * FF, ff_b1, (size_t)l * FF, FFHB, 1, MROW, FF, DIM, 2, 0);
    GEMMM(FFHB, 1, ff_w2, (size_t)l * FF * DIM, ff_b2, (size_t)l * DIM, X, 0, MROW, DIM, FF, 0, 1);
  }

  // ---- head ----
  rms512_k<<<MROW, 256, 0, stream>>>(X, final_g, 0, HBB, FLAG);
  GEMMM(HBB, 1, pred_w, 0, pred_b, 0, OUTT, 0, MROW, DIM, DIM, 0, 0);
  write_out_k<<<CDIV(NB*HWT*DIM, 256), 256, 0, stream>>>(OUTT, d_out, FLAG);

#undef GEMMM
}

// Round 7
// 1407.876 us; speedup vs baseline: 5.6181x; 1.3926x over previous
//
#include <hip/hip_runtime.h>
#include <hip/hip_bf16.h>

typedef __hip_bfloat16 bf16;
typedef short short8v __attribute__((ext_vector_type(8)));
typedef float float4v __attribute__((ext_vector_type(4)));

static __device__ __forceinline__ float b2f(bf16 x){ return __bfloat162float(x); }

// dtype-flexible input load: isbf ? bf16[i] : f32[i]
static __device__ __forceinline__ float ldin(const void* p, size_t i, bool isbf) {
  return isbf ? b2f(((const bf16*)p)[i]) : ((const float*)p)[i];
}

static __device__ __forceinline__ unsigned short f2bu(float f) {
  bf16 h = __float2bfloat16(f);
  return *reinterpret_cast<unsigned short*>(&h);
}

#define CDIV(a,b) (((a)+(b)-1)/(b))

// Model constants
#define NB   4
#define NSL  50
#define HWT  256
#define NT   306     // NSL + HWT
#define DIM  512
#define NH   8
#define FF   2048
#define RPP  28100   // mixed rel-pos pairs per batch
#define PCH  56200   // rel-pos chunk (2 chunks of NB*RPP/2)

// decode mixed-pair index q (0..RPP-1) -> (i,j)
static __device__ __forceinline__ void rp_decode(int q, int& i, int& j) {
  if (q < 15300) { i = q / NT; j = q % NT; }
  else { int r = q - 15300; i = NSL + r / NSL; j = r % NSL; }
}

// ---------------------------------------------------------------------------
// dtype detector (bf16 vs f32 served data); flag=1 means bf16.
// ---------------------------------------------------------------------------
__global__ void detect_k(const void* p, int* flag) {
  const unsigned short* u = (const unsigned short*)p;
  int t = threadIdx.x;
  int e = (u[t] >> 7) & 0xFF;
  __shared__ int anybad;
  if (t == 0) anybad = 0;
  __syncthreads();
  if (e >= 0x88) atomicOr(&anybad, 1);
  __syncthreads();
  if (t == 0) *flag = anybad ? 0 : 1;
}

// ---------------------------------------------------------------------------
// Weight transpose: W[K,N] (bf16 or f32) -> WT[N,K] bf16. K,N multiples of 64.
// blockIdx.z = layer slice (offset z*K*N both sides).
// ---------------------------------------------------------------------------
__global__ __launch_bounds__(256) void wtrans_k(const void* __restrict__ W,
    unsigned short* __restrict__ WT, int K, int N, const int* __restrict__ flagp) {
  const bool isbf = *flagp != 0;
  __shared__ unsigned short S[64 * 72];
  const size_t slice = (size_t)K * N * blockIdx.z;
  int n0 = blockIdx.x * 64, k0 = blockIdx.y * 64;
  int t = threadIdx.x;
  int kk = t >> 4, nn = (t & 15) * 4;
#pragma unroll
  for (int r = 0; r < 4; ++r) {
    int k = k0 + kk + r * 16;
    unsigned short v[4];
    if (isbf) {
      ushort4 u = *(const ushort4*)((const unsigned short*)W + slice + (size_t)k * N + n0 + nn);
      v[0]=u.x; v[1]=u.y; v[2]=u.z; v[3]=u.w;
    } else {
      float4 f = *(const float4*)((const float*)W + slice + (size_t)k * N + n0 + nn);
      v[0]=f2bu(f.x); v[1]=f2bu(f.y); v[2]=f2bu(f.z); v[3]=f2bu(f.w);
    }
#pragma unroll
    for (int i = 0; i < 4; ++i) S[(nn + i) * 72 + kk + r * 16] = v[i];
  }
  __syncthreads();
  int nr = t >> 2, kc = (t & 3) * 16;
  short8v s0 = *(const short8v*)&S[nr * 72 + kc];
  short8v s1 = *(const short8v*)&S[nr * 72 + kc + 8];
  unsigned short* dst = WT + slice + (size_t)(n0 + nr) * K + k0 + kc;
  *(short8v*)dst = s0;
  *(short8v*)(dst + 8) = s1;
}

// ---------------------------------------------------------------------------
// MFMA bf16 GEMM body v2: C = act(A[M,K] @ W + bias), W given TRANSPOSED as
// WT[N,K] bf16. Both tiles staged k-contiguous with coalesced 16B/thread reads
// and conflict-free b128 LDS writes; register prefetch of tile k+1 overlaps
// global latency with MFMA. aty: A f32/bf16. oty: C f32/bf16.
// mode: 0=store, 1=accumulate, 2=atomicAdd (K-split). bias added iff kbeg==0.
// act: 0 none, 1 relu, 2 gelu(tanh), 3 silu. N%64==0, K%32==0.
// ---------------------------------------------------------------------------
#define LDT 40
static __device__ __forceinline__ void gemm_body2(
    const void* __restrict__ A, int aty,
    const unsigned short* __restrict__ WT,
    const void* __restrict__ bias, size_t boff,
    void* __restrict__ C, int oty,
    int M, int N, int K, int kbeg, int kend,
    int act, int mode, bool isbf)
{
  __shared__ unsigned short As[64 * LDT];
  __shared__ unsigned short Bs[64 * LDT];
  const int tid = threadIdx.x;
  const int lane = tid & 63, wave = tid >> 6;
  const int quad = lane >> 4, ti = lane & 15;
  const int wm = (wave & 1) * 32, wn = (wave >> 1) * 32;
  const int bm = blockIdx.y * 64, bn = blockIdx.x * 64;
  const int srow = tid >> 2, sch = (tid & 3) * 8;

  unsigned short ha[8], hb[8];
  const int gm = bm + srow;
  const bool aok = gm < M;
  const unsigned short* Abf = (const unsigned short*)A + (size_t)gm * K;
  const float*          Af  = (const float*)A + (size_t)gm * K;
  const unsigned short* Bp  = WT + (size_t)(bn + srow) * K;

  auto fetchA = [&](int k0) {
    if (aok) {
      if (aty) {
        const ushort4* ap = (const ushort4*)(Abf + k0 + sch);
        ushort4 u0 = ap[0], u1 = ap[1];
        ha[0]=u0.x; ha[1]=u0.y; ha[2]=u0.z; ha[3]=u0.w;
        ha[4]=u1.x; ha[5]=u1.y; ha[6]=u1.z; ha[7]=u1.w;
      } else {
        const float* ap = Af + k0 + sch;
        float4 x = *(const float4*)ap, y = *(const float4*)(ap + 4);
        ha[0]=f2bu(x.x); ha[1]=f2bu(x.y); ha[2]=f2bu(x.z); ha[3]=f2bu(x.w);
        ha[4]=f2bu(y.x); ha[5]=f2bu(y.y); ha[6]=f2bu(y.z); ha[7]=f2bu(y.w);
      }
    } else {
      for (int i = 0; i < 8; ++i) ha[i] = 0;
    }
  };
  auto fetchB = [&](int k0) {
    const ushort4* bp = (const ushort4*)(Bp + k0 + sch);
    ushort4 u0 = bp[0], u1 = bp[1];
    hb[0]=u0.x; hb[1]=u0.y; hb[2]=u0.z; hb[3]=u0.w;
    hb[4]=u1.x; hb[5]=u1.y; hb[6]=u1.z; hb[7]=u1.w;
  };

  float4v acc00 = {0,0,0,0}, acc01 = {0,0,0,0}, acc10 = {0,0,0,0}, acc11 = {0,0,0,0};
  fetchA(kbeg); fetchB(kbeg);
  for (int k0 = kbeg; k0 < kend; k0 += 32) {
    *(short8v*)&As[srow * LDT + sch] = *(short8v*)ha;
    *(short8v*)&Bs[srow * LDT + sch] = *(short8v*)hb;
    __syncthreads();
    if (k0 + 32 < kend) { fetchA(k0 + 32); fetchB(k0 + 32); }
    short8v a0 = *reinterpret_cast<const short8v*>(&As[(wm + ti)      * LDT + quad * 8]);
    short8v a1 = *reinterpret_cast<const short8v*>(&As[(wm + 16 + ti) * LDT + quad * 8]);
    short8v b0 = *reinterpret_cast<const short8v*>(&Bs[(wn + ti)      * LDT + quad * 8]);
    short8v b1 = *reinterpret_cast<const short8v*>(&Bs[(wn + 16 + ti) * LDT + quad * 8]);
    acc00 = __builtin_amdgcn_mfma_f32_16x16x32_bf16(a0, b0, acc00, 0, 0, 0);
    acc01 = __builtin_amdgcn_mfma_f32_16x16x32_bf16(a0, b1, acc01, 0, 0, 0);
    acc10 = __builtin_amdgcn_mfma_f32_16x16x32_bf16(a1, b0, acc10, 0, 0, 0);
    acc11 = __builtin_amdgcn_mfma_f32_16x16x32_bf16(a1, b1, acc11, 0, 0, 0);
    __syncthreads();
  }

  float4v accs[2][2] = {{acc00, acc01}, {acc10, acc11}};
#pragma unroll
  for (int mi = 0; mi < 2; ++mi) {
#pragma unroll
    for (int ni = 0; ni < 2; ++ni) {
      int row0 = bm + wm + mi * 16 + quad * 4;
      int col  = bn + wn + ni * 16 + ti;
      float bv = (bias && kbeg == 0) ? ldin(bias, boff + col, isbf) : 0.f;
#pragma unroll
      for (int r = 0; r < 4; ++r) {
        int row = row0 + r;
        if (row >= M) continue;
        float v = accs[mi][ni][r] + bv;
        if (act == 1) v = fmaxf(v, 0.f);
        else if (act == 2) {
          float u = 0.7978845608028654f * (v + 0.044715f * v * v * v);
          v = 0.5f * v * (1.f + tanhf(u));
        } else if (act == 3) {
          v = v / (1.f + expf(-v));
        }
        size_t idx = (size_t)row * N + col;
        if (oty) ((bf16*)C)[idx] = __float2bfloat16(v);
        else {
          float* Cf = (float*)C;
          if (mode == 2) atomicAdd(&Cf[idx], v);
          else if (mode == 1) Cf[idx] += v;
          else Cf[idx] = v;
        }
      }
    }
  }
}

__global__ __launch_bounds__(256) void gemm_mfma(
    const void* A, int aty, const unsigned short* WT, size_t woff,
    const void* bias, size_t boff, void* C, int oty,
    int M, int N, int K, int act, int accum, int zsplit, const int* __restrict__ flagp)
{
  int ksz = K / zsplit;
  int kbeg = blockIdx.z * ksz;
  int mode = zsplit > 1 ? 2 : (accum ? 1 : 0);
  gemm_body2(A, aty, WT + woff, bias, boff, C, oty, M, N, K, kbeg, kbeg + ksz,
             act, mode, *flagp != 0);
}

// 3 GEMMs sharing A/shapes (QKV); blockIdx.z selects job
__global__ __launch_bounds__(256) void gemm_mfma_tri(
    const void* A, int aty, const unsigned short* WT, size_t o0, size_t o1, size_t o2,
    void* C0, void* C1, void* C2, int oty, int M, int N, int K,
    const int* __restrict__ flagp)
{
  size_t o = blockIdx.z == 0 ? o0 : (blockIdx.z == 1 ? o1 : o2);
  void* C = blockIdx.z == 0 ? C0 : (blockIdx.z == 1 ? C1 : C2);
  gemm_body2(A, aty, WT + o, nullptr, 0, C, oty, M, N, K, 0, K, 0, 0, *flagp != 0);
}

// 2 GEMMs, separate A/W/bias/C, shared shapes
__global__ __launch_bounds__(256) void gemm_mfma_duo(
    const void* A0, const void* A1, int aty, const unsigned short* WT, size_t o0, size_t o1,
    const void* bias0, const void* bias1, void* C0, void* C1, int oty,
    int M, int N, int K, const int* __restrict__ flagp)
{
  const void* A = blockIdx.z ? A1 : A0;
  size_t o = blockIdx.z ? o1 : o0;
  const void* bias = blockIdx.z ? bias1 : bias0;
  void* C = blockIdx.z ? C1 : C0;
  gemm_body2(A, aty, WT + o, bias, 0, C, oty, M, N, K, 0, K, 0, 0, *flagp != 0);
}

// ---------------------------------------------------------------------------
// f32 GEMM (only for the N=2 coords projection)
// ---------------------------------------------------------------------------
__global__ __launch_bounds__(256) void gemm_k(
    const float* __restrict__ A, const void* __restrict__ W, size_t woff,
    const void* __restrict__ bias, size_t boff, float* __restrict__ C,
    int M, int N, int K, const int* __restrict__ flagp)
{
  const bool isbf = *flagp != 0;
  __shared__ float As[16][68];
  __shared__ float Ws[16][68];
  const int bm = blockIdx.y * 64, bn = blockIdx.x * 64;
  const int tx = threadIdx.x, ty = threadIdx.y;
  const int tid = ty * 16 + tx;
  float acc[4][4] = {};
  for (int k0 = 0; k0 < K; k0 += 16) {
#pragma unroll
    for (int i = 0; i < 4; ++i) {
      int idx = tid + i * 256;
      int m  = idx >> 4, k = idx & 15;
      int gm = bm + m;
      As[k][m] = (gm < M) ? A[(size_t)gm * K + k0 + k] : 0.f;
      int kk = idx >> 6, n = idx & 63;
      int gn = bn + n;
      Ws[kk][n] = (gn < N) ? ldin(W, woff + (size_t)(k0 + kk) * N + gn, isbf) : 0.f;
    }
    __syncthreads();
#pragma unroll
    for (int k = 0; k < 16; ++k) {
      float4 a4 = *reinterpret_cast<const float4*>(&As[k][ty * 4]);
      float4 w4 = *reinterpret_cast<const float4*>(&Ws[k][tx * 4]);
      float a[4] = {a4.x, a4.y, a4.z, a4.w};
      float w[4] = {w4.x, w4.y, w4.z, w4.w};
#pragma unroll
      for (int i = 0; i < 4; ++i)
#pragma unroll
        for (int j = 0; j < 4; ++j)
          acc[i][j] = fmaf(a[i], w[j], acc[i][j]);
    }
    __syncthreads();
  }
#pragma unroll
  for (int i = 0; i < 4; ++i) {
    int gm = bm + ty * 4 + i;
    if (gm >= M) continue;
#pragma unroll
    for (int j = 0; j < 4; ++j) {
      int gn = bn + tx * 4 + j;
      if (gn >= N) continue;
      float v = acc[i][j];
      if (bias) v += ldin(bias, boff + gn, isbf);
      C[(size_t)gm * N + gn] = v;
    }
  }
}

// ---------------------------------------------------------------------------
// Patch extraction (im2col) -> bf16
// ---------------------------------------------------------------------------
__global__ void patchify_k(const void* __restrict__ img, unsigned short* __restrict__ xp,
                           const int* __restrict__ flagp) {
  const bool isbf = *flagp != 0;
  int i = blockIdx.x * 256 + threadIdx.x;
  if (i >= NB * HWT * 768) return;
  int col = i % 768, row = i / 768;
  int c = col % 3, p2 = (col / 3) & 15, p1 = col / 48;
  int w = row & 15, h = (row >> 4) & 15, b = row >> 8;
  xp[i] = f2bu(ldin(img, (((size_t)(b * 3 + c) * 256 + h * 16 + p1) * 256) + w * 16 + p2, isbf));
}

__global__ void addpos_k(float* __restrict__ tok, const void* __restrict__ hp,
                         const void* __restrict__ wp, const int* __restrict__ flagp) {
  const bool isbf = *flagp != 0;
  int i = blockIdx.x * 256 + threadIdx.x;
  if (i >= NB * HWT * DIM) return;
  int d = i & 511;
  int row = i >> 9;
  int w = row & 15, h = (row >> 4) & 15;
  tok[i] += ldin(hp, h * DIM + d, isbf) + ldin(wp, w * DIM + d, isbf);
}

// ---------------------------------------------------------------------------
// LayerNorm (bf16 out) / RMSNorm (bf16 out) over 512-dim rows
// ---------------------------------------------------------------------------
__global__ void ln512_k(const float* __restrict__ X, const void* __restrict__ g,
                        const void* __restrict__ b, unsigned short* __restrict__ Y,
                        const int* __restrict__ flagp) {
  const bool isbf = *flagp != 0;
  int row = blockIdx.x, t = threadIdx.x;
  const float* x = X + (size_t)row * DIM;
  float v0 = x[t], v1 = x[t + 256];
  __shared__ float rs[256], rq[256];
  rs[t] = v0 + v1; rq[t] = v0 * v0 + v1 * v1;
  __syncthreads();
  for (int o = 128; o > 0; o >>= 1) {
    if (t < o) { rs[t] += rs[t + o]; rq[t] += rq[t + o]; }
    __syncthreads();
  }
  float mean = rs[0] * (1.f / 512.f);
  float var  = rq[0] * (1.f / 512.f) - mean * mean;
  float inv  = rsqrtf(var + 1e-5f);
  unsigned short* y = Y + (size_t)row * DIM;
  y[t]       = f2bu((v0 - mean) * inv * ldin(g, t, isbf)       + ldin(b, t, isbf));
  y[t + 256] = f2bu((v1 - mean) * inv * ldin(g, t + 256, isbf) + ldin(b, t + 256, isbf));
}

__global__ void rms512_k(const float* __restrict__ X, const void* __restrict__ g,
                         int goff, unsigned short* __restrict__ Y, const int* __restrict__ flagp) {
  const bool isbf = *flagp != 0;
  int row = blockIdx.x, t = threadIdx.x;
  const float* x = X + (size_t)row * DIM;
  float v0 = x[t], v1 = x[t + 256];
  __shared__ float rq[256];
  rq[t] = v0 * v0 + v1 * v1;
  __syncthreads();
  for (int o = 128; o > 0; o >>= 1) {
    if (t < o) rq[t] += rq[t + o];
    __syncthreads();
  }
  float nrm = sqrtf(rq[0]);
  float sc = 22.62741699796952f / fmaxf(nrm, 1e-12f);
  unsigned short* y = Y + (size_t)row * DIM;
  y[t]       = f2bu(v0 * sc * ldin(g, goff + t, isbf));
  y[t + 256] = f2bu(v1 * sc * ldin(g, goff + t + 256, isbf));
}

// ---------------------------------------------------------------------------
// Slot attention pieces
// ---------------------------------------------------------------------------
__global__ void slots_init_k(const void* __restrict__ mu, const void* __restrict__ ls,
                             const void* __restrict__ noise, float* __restrict__ slots,
                             const int* __restrict__ flagp) {
  const bool isbf = *flagp != 0;
  int i = blockIdx.x * 256 + threadIdx.x;
  if (i >= NB * NSL * DIM) return;
  int d = i & 511;
  slots[i] = ldin(mu, d, isbf) + expf(ldin(ls, d, isbf)) * ldin(noise, i, isbf);
}

__global__ void slot_dots_k(const float* __restrict__ q, const float* __restrict__ k,
                            float* __restrict__ dots) {
  int blk = blockIdx.x;                 // b*200 + h*50 + i
  int i = blk % 50, h = (blk / 50) & 3, b = blk / 200;
  int j = threadIdx.x;
  __shared__ float qs[64];
  if (threadIdx.x < 64) qs[threadIdx.x] = q[((size_t)(b * 50 + i)) * 256 + h * 64 + threadIdx.x];
  __syncthreads();
  const float* kr = k + ((size_t)(b * 256 + j)) * 256 + h * 64;
  float s = 0.f;
#pragma unroll 8
  for (int d = 0; d < 64; ++d) s = fmaf(qs[d], kr[d], s);
  dots[(((size_t)(b * 4 + h) * 50) + i) * 256 + j] = s * 0.125f;
}

__global__ void softmax_slots_k(float* __restrict__ dots) {
  int idx = blockIdx.x * 256 + threadIdx.x;
  if (idx >= 4096) return;
  int j = idx & 255, h = (idx >> 8) & 3, b = idx >> 10;
  float* base = dots + ((size_t)(b * 4 + h) * 50) * 256 + j;
  float m = -1e30f;
  for (int i = 0; i < 50; ++i) m = fmaxf(m, base[i * 256]);
  float s = 0.f;
  for (int i = 0; i < 50; ++i) { float e = expf(base[i * 256] - m); base[i * 256] = e; s += e; }
  float inv = 1.f / s;
  for (int i = 0; i < 50; ++i) base[i * 256] *= inv;
}

__global__ void renorm_attn_k(float* __restrict__ attn) {
  int t = threadIdx.x;
  float* row = attn + (size_t)blockIdx.x * 256;
  float v = row[t] + 1e-8f;
  __shared__ float rs[256];
  rs[t] = v;
  __syncthreads();
  for (int o = 128; o > 0; o >>= 1) {
    if (t < o) rs[t] += rs[t + o];
    __syncthreads();
  }
  row[t] = v / rs[0];
}

__global__ void slot_upd_k(const float* __restrict__ attn, const float* __restrict__ v,
                           float* __restrict__ upd) {
  int bi = blockIdx.x;        // b*50+i
  int b = bi / 50, i = bi % 50;
  int t = threadIdx.x, h = t >> 6;
  const float* arow = attn + ((size_t)((b * 4 + h) * 50) + i) * 256;
  float s = 0.f;
  for (int j = 0; j < 256; ++j) s = fmaf(arow[j], v[((size_t)(b * 256 + j)) * 256 + t], s);
  upd[(size_t)bi * 256 + t] = s;
}

// in-place safe (elementwise)
__global__ void gru_k(const float* __restrict__ gx, const float* __restrict__ gh,
                      float* __restrict__ slots) {
  int i = blockIdx.x * 256 + threadIdx.x;
  if (i >= NB * NSL * DIM) return;
  int row = i >> 9, d = i & 511;
  size_t b3 = (size_t)row * 1536;
  float xr = gx[b3 + d], xz = gx[b3 + 512 + d], xn = gx[b3 + 1024 + d];
  float hr = gh[b3 + d], hz = gh[b3 + 512 + d], hn = gh[b3 + 1024 + d];
  float r = 1.f / (1.f + expf(-(xr + hr)));
  float z = 1.f / (1.f + expf(-(xz + hz)));
  float n = tanhf(xn + r * hn);
  float prev = slots[i];
  slots[i] = (1.f - z) * n + z * prev;
}

// ---------------------------------------------------------------------------
// Rel-pos bias
// ---------------------------------------------------------------------------
__global__ void build_coords_k(const float* __restrict__ sc, float* __restrict__ coords) {
  int i = blockIdx.x * 256 + threadIdx.x;
  if (i >= NB * NT) return;
  int b = i / NT, n = i % NT;
  float cx, cy;
  if (n < NSL) { cx = sc[(b * NSL + n) * 2]; cy = sc[(b * NSL + n) * 2 + 1]; }
  else { int t = n - NSL; cx = (float)(t >> 4); cy = (float)(t & 15); }
  coords[i * 2] = cx; coords[i * 2 + 1] = cy;
}

__global__ void relpos_table_k(const void* w1, const void* b1, const void* w2,
                               const void* b2, const void* w3, const void* b3,
                               float* __restrict__ tab, const int* __restrict__ flagp) {
  const bool isbf = *flagp != 0;
  int blk = blockIdx.x;  // 961
  float r0 = (float)(blk / 31 - 15), r1 = (float)(blk % 31 - 15);
  int t = threadIdx.x;
  __shared__ float h1[128], h2[128];
  float a = fmaf(r0, ldin(w1, t, isbf), fmaf(r1, ldin(w1, 128 + t, isbf), ldin(b1, t, isbf)));
  h1[t] = a / (1.f + expf(-a));
  __syncthreads();
  float s = ldin(b2, t, isbf);
#pragma unroll 4
  for (int k = 0; k < 128; ++k) s = fmaf(h1[k], ldin(w2, k * 128 + t, isbf), s);
  h2[t] = s / (1.f + expf(-s));
  __syncthreads();
  if (t < 8) {
    float o = ldin(b3, t, isbf);
#pragma unroll 4
    for (int k = 0; k < 128; ++k) o = fmaf(h2[k], ldin(w3, k * 8 + t, isbf), o);
    tab[blk * 8 + t] = o;
  }
}

__global__ void bias_fill_k(const float* __restrict__ tab, float* __restrict__ bias) {
  int i = blockIdx.x * 256 + threadIdx.x;
  if (i >= NB * NH * HWT * HWT) return;
  int jj = i & 255, ii = (i >> 8) & 255, h = (i >> 16) & 7, b = i >> 19;
  int di = (ii >> 4) - (jj >> 4) + 15;
  int dj = (ii & 15) - (jj & 15) + 15;
  bias[(((size_t)(b * NH + h) * NT) + NSL + ii) * NT + NSL + jj] = tab[(di * 31 + dj) * 8 + h];
}

// layer1 silu -> H1 bf16 [pcount,128], chunked
__global__ void rp_l1_k(const float* __restrict__ coords, const void* w1, const void* b1,
                        unsigned short* __restrict__ H, int pbase, int pcount,
                        const int* __restrict__ flagp) {
  const bool isbf = *flagp != 0;
  int idx = blockIdx.x * 256 + threadIdx.x;
  if (idx >= pcount * 128) return;
  int pl = idx >> 7, u = idx & 127;
  int p = pbase + pl;
  int q = p % RPP, bb = p / RPP;
  int ii, jj;
  rp_decode(q, ii, jj);
  float r0 = coords[(bb * NT + ii) * 2]     - coords[(bb * NT + jj) * 2];
  float r1 = coords[(bb * NT + ii) * 2 + 1] - coords[(bb * NT + jj) * 2 + 1];
  float a = fmaf(r0, ldin(w1, u, isbf), fmaf(r1, ldin(w1, 128 + u, isbf), ldin(b1, u, isbf)));
  H[(size_t)pl * 128 + u] = f2bu(a / (1.f + expf(-a)));
}

// layer3 (128->8) + scatter. 32 pairs/block, 8 threads/pair.
__global__ __launch_bounds__(256) void rp_l3_k(
    const unsigned short* __restrict__ H2, const void* w3, const void* b3,
    float* __restrict__ bias, int pbase, int pcount, const int* __restrict__ flagp) {
  const bool isbf = *flagp != 0;
  __shared__ float W3s[128 * 8];
  int t = threadIdx.x;
  for (int e = t; e < 1024; e += 256) W3s[e] = ldin(w3, e, isbf);
  __syncthreads();
  int pl = blockIdx.x * 32 + (t >> 3), hh = t & 7;
  if (pl >= pcount) return;
  int p = pbase + pl;
  int q = p % RPP, bb = p / RPP;
  int ii, jj;
  rp_decode(q, ii, jj);
  float s = ldin(b3, hh, isbf);
  const unsigned short* hrow = H2 + (size_t)pl * 128;
#pragma unroll 8
  for (int k = 0; k < 128; ++k) {
    bf16 hv = *reinterpret_cast<const bf16*>(&hrow[k]);
    s = fmaf(b2f(hv), W3s[k * 8 + hh], s);
  }
  bias[((size_t)(bb * NH + hh) * NT + ii) * NT + jj] = s;
}

// ---------------------------------------------------------------------------
// Transformer pieces
// ---------------------------------------------------------------------------
__global__ void build_x_k(const float* __restrict__ slots, const float* __restrict__ tok,
                          float* __restrict__ x) {
  int i = blockIdx.x * 256 + threadIdx.x;
  if (i >= NB * NT * DIM) return;
  int d = i & 511, n = (i >> 9) % NT, b = i / (NT * DIM);
  x[i] = (n < NSL) ? slots[((size_t)(b * NSL + n)) * DIM + d]
                   : tok[((size_t)(b * HWT + (n - NSL))) * DIM + d];
}

// SIM[bh,i,j] = 0.125 * Q·K + bias, MFMA. grid (5,5,32)
__global__ __launch_bounds__(256) void attn_sim_k(
    const unsigned short* __restrict__ Qb, const unsigned short* __restrict__ Kb,
    const float* __restrict__ bias, float* __restrict__ sim)
{
  const int bh = blockIdx.z, b = bh >> 3, h = bh & 7;
  const int bm = blockIdx.y * 64, bn = blockIdx.x * 64;
  __shared__ unsigned short As[64 * 72];
  __shared__ unsigned short Bs[64 * 72];
  const int tid = threadIdx.x;
  const int lane = tid & 63, wave = tid >> 6, quad = lane >> 4, ti = lane & 15;
  const int wm = (wave & 1) * 32, wn = (wave >> 1) * 32;
  {
    int r = tid >> 2, c = (tid & 3) * 16;
    ushort4 z4 = {0,0,0,0};
    ushort4 a[4] = {z4, z4, z4, z4}, bq[4] = {z4, z4, z4, z4};
    int gi = bm + r, gj = bn + r;
    if (gi < NT) {
      const ushort4* p = reinterpret_cast<const ushort4*>(Qb + ((size_t)(b * NT + gi)) * DIM + h * 64 + c);
#pragma unroll
      for (int i = 0; i < 4; ++i) a[i] = p[i];
    }
    if (gj < NT) {
      const ushort4* p = reinterpret_cast<const ushort4*>(Kb + ((size_t)(b * NT + gj)) * DIM + h * 64 + c);
#pragma unroll
      for (int i = 0; i < 4; ++i) bq[i] = p[i];
    }
#pragma unroll
    for (int i = 0; i < 4; ++i) {
      *reinterpret_cast<ushort4*>(&As[r * 72 + c + i * 4]) = a[i];
      *reinterpret_cast<ushort4*>(&Bs[r * 72 + c + i * 4]) = bq[i];
    }
  }
  __syncthreads();
  float4v acc00 = {0,0,0,0}, acc01 = {0,0,0,0}, acc10 = {0,0,0,0}, acc11 = {0,0,0,0};
#pragma unroll
  for (int ks = 0; ks < 2; ++ks) {
    short8v a0 = *reinterpret_cast<const short8v*>(&As[(wm + ti)      * 72 + ks * 32 + quad * 8]);
    short8v a1 = *reinterpret_cast<const short8v*>(&As[(wm + 16 + ti) * 72 + ks * 32 + quad * 8]);
    short8v b0 = *reinterpret_cast<const short8v*>(&Bs[(wn + ti)      * 72 + ks * 32 + quad * 8]);
    short8v b1 = *reinterpret_cast<const short8v*>(&Bs[(wn + 16 + ti) * 72 + ks * 32 + quad * 8]);
    acc00 = __builtin_amdgcn_mfma_f32_16x16x32_bf16(a0, b0, acc00, 0, 0, 0);
    acc01 = __builtin_amdgcn_mfma_f32_16x16x32_bf16(a0, b1, acc01, 0, 0, 0);
    acc10 = __builtin_amdgcn_mfma_f32_16x16x32_bf16(a1, b0, acc10, 0, 0, 0);
    acc11 = __builtin_amdgcn_mfma_f32_16x16x32_bf16(a1, b1, acc11, 0, 0, 0);
  }
  float4v accs[2][2] = {{acc00, acc01}, {acc10, acc11}};
#pragma unroll
  for (int mi = 0; mi < 2; ++mi) {
#pragma unroll
    for (int ni = 0; ni < 2; ++ni) {
      int row0 = bm + wm + mi * 16 + quad * 4;
      int col  = bn + wn + ni * 16 + ti;
      if (col >= NT) continue;
#pragma unroll
      for (int r = 0; r < 4; ++r) {
        int row = row0 + r;
        if (row >= NT) continue;
        size_t idx = ((size_t)bh * NT + row) * NT + col;
        sim[idx] = accs[mi][ni][r] * 0.125f + bias[idx];
      }
    }
  }
}

// row softmax over 306, writes bf16 prob padded to 320 (zero pad)
__global__ void softmax_prob_k(const float* __restrict__ sim, unsigned short* __restrict__ prob) {
  int row = blockIdx.x;       // bh*NT + i
  const float* src = sim + (size_t)row * NT;
  unsigned short* dst = prob + (size_t)row * 320;
  int t = threadIdx.x;
  float v0 = (t < NT) ? src[t] : -1e30f;
  float v1 = (t + 256 < NT) ? src[t + 256] : -1e30f;
  __shared__ float rb[256];
  rb[t] = fmaxf(v0, v1);
  __syncthreads();
  for (int o = 128; o > 0; o >>= 1) {
    if (t < o) rb[t] = fmaxf(rb[t], rb[t + o]);
    __syncthreads();
  }
  float m = rb[0];
  __syncthreads();
  float e0 = (t < NT) ? expf(v0 - m) : 0.f;
  float e1 = (t + 256 < NT) ? expf(v1 - m) : 0.f;
  rb[t] = e0 + e1;
  __syncthreads();
  for (int o = 128; o > 0; o >>= 1) {
    if (t < o) rb[t] += rb[t + o];
    __syncthreads();
  }
  float inv = 1.f / rb[0];
  dst[t] = f2bu(e0 * inv);
  if (t + 256 < 320) dst[t + 256] = f2bu(t + 256 < NT ? e1 * inv : 0.f);
}

// OB = P @ V, MFMA. grid (5, 32): x=i-tile, y=bh. K=320 (prob pad zero)
__global__ __launch_bounds__(256) void attn_av_k(
    const unsigned short* __restrict__ prob, const unsigned short* __restrict__ Vb,
    unsigned short* __restrict__ Ob)
{
  const int bh = blockIdx.y, b = bh >> 3, h = bh & 7;
  const int bm = blockIdx.x * 64;
  __shared__ unsigned short As[64 * LDT];
  __shared__ unsigned short Bs[64 * LDT];
  const int tid = threadIdx.x;
  const int lane = tid & 63, wave = tid >> 6, quad = lane >> 4, ti = lane & 15;
  const int wm = (wave & 1) * 32, wn = (wave >> 1) * 32;
  const int arow = tid >> 2, ach = (tid & 3) * 8;
  const int bk = tid & 31, bch = tid >> 5;

  float4v acc00 = {0,0,0,0}, acc01 = {0,0,0,0}, acc10 = {0,0,0,0}, acc11 = {0,0,0,0};

  for (int k0 = 0; k0 < 320; k0 += 32) {
    {
      int gi = bm + arow;
      ushort4 u0 = {0,0,0,0}, u1 = {0,0,0,0};
      if (gi < NT) {
        const ushort4* p = reinterpret_cast<const ushort4*>(
            prob + ((size_t)bh * NT + gi) * 320 + k0 + ach);
        u0 = p[0]; u1 = p[1];
      }
      *reinterpret_cast<ushort4*>(&As[arow * LDT + ach])     = u0;
      *reinterpret_cast<ushort4*>(&As[arow * LDT + ach + 4]) = u1;
    }
    {
      int j = k0 + bk;
      unsigned short h8[8];
      if (j < NT) {
        const ushort4* p = reinterpret_cast<const ushort4*>(
            Vb + ((size_t)(b * NT + j)) * DIM + h * 64 + bch * 8);
        ushort4 u0 = p[0], u1 = p[1];
        h8[0]=u0.x; h8[1]=u0.y; h8[2]=u0.z; h8[3]=u0.w; h8[4]=u1.x; h8[5]=u1.y; h8[6]=u1.z; h8[7]=u1.w;
      } else {
#pragma unroll
        for (int i = 0; i < 8; ++i) h8[i] = 0;
      }
#pragma unroll
      for (int i = 0; i < 8; ++i) Bs[(bch * 8 + i) * LDT + bk] = h8[i];
    }
    __syncthreads();
    short8v a0 = *reinterpret_cast<const short8v*>(&As[(wm + ti)      * LDT + quad * 8]);
    short8v a1 = *reinterpret_cast<const short8v*>(&As[(wm + 16 + ti) * LDT + quad * 8]);
    short8v b0 = *reinterpret_cast<const short8v*>(&Bs[(wn + ti)      * LDT + quad * 8]);
    short8v b1 = *reinterpret_cast<const short8v*>(&Bs[(wn + 16 + ti) * LDT + quad * 8]);
    acc00 = __builtin_amdgcn_mfma_f32_16x16x32_bf16(a0, b0, acc00, 0, 0, 0);
    acc01 = __builtin_amdgcn_mfma_f32_16x16x32_bf16(a0, b1, acc01, 0, 0, 0);
    acc10 = __builtin_amdgcn_mfma_f32_16x16x32_bf16(a1, b0, acc10, 0, 0, 0);
    acc11 = __builtin_amdgcn_mfma_f32_16x16x32_bf16(a1, b1, acc11, 0, 0, 0);
    __syncthreads();
  }
  float4v accs[2][2] = {{acc00, acc01}, {acc10, acc11}};
#pragma unroll
  for (int mi = 0; mi < 2; ++mi) {
#pragma unroll
    for (int ni = 0; ni < 2; ++ni) {
      int row0 = bm + wm + mi * 16 + quad * 4;
      int col  = wn + ni * 16 + ti;
#pragma unroll
      for (int r = 0; r < 4; ++r) {
        int row = row0 + r;
        if (row >= NT) continue;
        Ob[((size_t)(b * NT + row)) * DIM + h * 64 + col] = f2bu(accs[mi][ni][r]);
      }
    }
  }
}

__global__ void write_out_k(const float* __restrict__ tmp, void* __restrict__ out,
                            const int* __restrict__ flagp) {
  const bool isbf = *flagp != 0;
  int i = blockIdx.x * 256 + threadIdx.x;
  if (i >= NB * HWT * DIM) return;
  int d = i & 511, tt = (i >> 9) & 255, b = i / (HWT * DIM);
  float v = tmp[((size_t)(b * NT + NSL + tt)) * DIM + d];
  if (isbf) ((bf16*)out)[i] = __float2bfloat16(v);
  else      ((float*)out)[i] = v;
}

// ---------------------------------------------------------------------------
extern "C" void kernel_launch(void* const* d_in, const int* in_sizes, int n_in,
                              void* d_out, int out_size, void* d_ws, size_t ws_size,
                              hipStream_t stream) {
  const void* images        = d_in[0];
  const void* slot_noise    = d_in[1];
  const void* patch_w       = d_in[2];
  const void* patch_b       = d_in[3];
  const void* hpos          = d_in[4];
  const void* wpos          = d_in[5];
  const void* rp_w1         = d_in[6];
  const void* rp_b1         = d_in[7];
  const void* rp_w2         = d_in[8];
  const void* rp_b2         = d_in[9];
  const void* rp_w3         = d_in[10];
  const void* rp_b3         = d_in[11];
  const void* slots_mu      = d_in[12];
  const void* slots_logsig  = d_in[13];
  const void* sa_ln_in_g    = d_in[14];
  const void* sa_ln_in_b    = d_in[15];
  const void* sa_ln_sl_g    = d_in[16];
  const void* sa_ln_sl_b    = d_in[17];
  const void* sa_wq         = d_in[18];
  const void* sa_bq         = d_in[19];
  const void* sa_wk         = d_in[20];
  const void* sa_bk         = d_in[21];
  const void* sa_wv         = d_in[22];
  const void* sa_bv         = d_in[23];
  const void* sa_wo         = d_in[24];
  const void* sa_bo         = d_in[25];
  const void* gru_wih       = d_in[26];
  const void* gru_whh       = d_in[27];
  const void* gru_bih       = d_in[28];
  const void* gru_bhh       = d_in[29];
  const void* sa_ln_ff_g    = d_in[30];
  const void* sa_ln_ff_b    = d_in[31];
  const void* sa_mlp_w1     = d_in[32];
  const void* sa_mlp_b1     = d_in[33];
  const void* sa_mlp_w2     = d_in[34];
  const void* sa_mlp_b2     = d_in[35];
  const void* s2c_w         = d_in[36];
  const void* s2c_b         = d_in[37];
  const void* attn_g        = d_in[38];
  const void* wq            = d_in[39];
  const void* wk            = d_in[40];
  const void* wv            = d_in[41];
  const void* wo            = d_in[42];
  const void* ff_g          = d_in[43];
  const void* ff_w1         = d_in[44];
  const void* ff_b1         = d_in[45];
  const void* ff_w2         = d_in[46];
  const void* ff_b2         = d_in[47];
  const void* final_g       = d_in[48];
  const void* pred_w        = d_in[49];
  const void* pred_b        = d_in[50];

  float* ws = (float*)d_ws;
  int* FLAG = (int*)ws;
  size_t off = 16;
  auto alloc = [&](size_t n) { float* p = ws + off; off += (n + 15) & ~(size_t)15; return p; };
  float* TOK   = alloc((size_t)NB * HWT * DIM);
  unsigned short* INPB = (unsigned short*)alloc((size_t)NB * HWT * DIM / 2);
  float* KB    = alloc((size_t)NB * HWT * 256);
  float* VB    = alloc((size_t)NB * HWT * 256);
  float* SLOTS = alloc((size_t)NB * NSL * DIM);
  unsigned short* SLNB = (unsigned short*)alloc((size_t)NB * NSL * DIM / 2);
  float* QB    = alloc((size_t)NB * NSL * 256);
  float* ATT   = alloc((size_t)NB * 4 * NSL * HWT);
  float* UPD   = alloc((size_t)NB * NSL * 256);
  float* UPDP  = alloc((size_t)NB * NSL * DIM);
  unsigned short* HIDSB = (unsigned short*)alloc((size_t)NB * NSL * DIM / 2);
  float* SC    = alloc((size_t)NB * NSL * 2);
  float* CRD   = alloc((size_t)NB * NT * 2);
  float* TAB   = alloc((size_t)961 * 8);
  float* BIAS  = alloc((size_t)NB * NH * NT * NT);
  float* X     = alloc((size_t)NB * NT * DIM);
  // attention-region (contiguous; aliased by rel-pos H1/H2 chunks)
  unsigned short* HBB  = (unsigned short*)alloc((size_t)NB * NT * DIM / 2);
  unsigned short* QHB  = (unsigned short*)alloc((size_t)NB * NT * DIM / 2);
  unsigned short* KHB  = (unsigned short*)alloc((size_t)NB * NT * DIM / 2);
  unsigned short* VHB  = (unsigned short*)alloc((size_t)NB * NT * DIM / 2);
  float* SIM   = alloc((size_t)NB * NH * NT * NT);
  unsigned short* PROBB = (unsigned short*)alloc((size_t)NB * NH * NT * 320 / 2);
  unsigned short* OBB  = (unsigned short*)alloc((size_t)NB * NT * DIM / 2);
  unsigned short* FFHB = (unsigned short*)alloc((size_t)NB * NT * FF / 2);
  float* OUTT  = alloc((size_t)NB * NT * DIM);
  // aliases (dead-region reuse)
  unsigned short* XPB = (unsigned short*)OUTT;            // im2col; dead before head
  float* GX = SIM;                                        // GRU gates; dead before transformer
  float* GH = SIM + (size_t)NB * NSL * 1536;
  // transposed-weight arena (bf16 [N,K] per weight)
  const size_t oPatch = 0;
  const size_t oKw    = oPatch + (size_t)512 * 768;
  const size_t oVw    = oKw    + (size_t)256 * 512;
  const size_t oQw    = oVw    + (size_t)256 * 512;
  const size_t oWo    = oQw    + (size_t)256 * 512;
  const size_t oGih   = oWo    + (size_t)512 * 256;
  const size_t oGhh   = oGih   + (size_t)1536 * 512;
  const size_t oMlp1  = oGhh   + (size_t)1536 * 512;
  const size_t oMlp2  = oMlp1  + (size_t)512 * 512;
  const size_t oRp2   = oMlp2  + (size_t)512 * 512;
  const size_t oWq    = oRp2   + (size_t)128 * 128;
  const size_t oWk    = oWq    + (size_t)6 * 512 * 512;
  const size_t oWv    = oWk    + (size_t)6 * 512 * 512;
  const size_t oWol   = oWv    + (size_t)6 * 512 * 512;
  const size_t oFf1   = oWol   + (size_t)6 * 512 * 512;
  const size_t oFf2   = oFf1   + (size_t)6 * 512 * 2048;
  const size_t oPred  = oFf2   + (size_t)6 * 2048 * 512;
  const size_t wtTotal = oPred + (size_t)512 * 512;      // 22.17M shorts
  unsigned short* WTS = (unsigned short*)alloc((wtTotal + 1) / 2);
  (void)ws_size; (void)in_sizes; (void)n_in; (void)out_size;

#define GEMMM(A_, ATY_, WOFF_, BIAS_, BOFF_, C_, OTY_, M_, N_, K_, ACT_, ACC_, ZS_) \
  gemm_mfma<<<dim3((N_)/64, CDIV((M_),64), (ZS_)), 256, 0, stream>>>( \
      A_, ATY_, WTS, (size_t)(WOFF_), BIAS_, (size_t)(BOFF_), C_, OTY_, M_, N_, K_, ACT_, ACC_, ZS_, FLAG)

  const int MROW = NB * NT;   // 1224
  const int MS   = NB * NSL;  // 200

  // ---- dtype detection + weight transposes ----
  detect_k<<<1, 256, 0, stream>>>(images, FLAG);
  wtrans_k<<<dim3(8, 12, 1),  256, 0, stream>>>(patch_w,  WTS + oPatch, 768,  512,  FLAG);
  wtrans_k<<<dim3(4, 8, 1),   256, 0, stream>>>(sa_wk,    WTS + oKw,    512,  256,  FLAG);
  wtrans_k<<<dim3(4, 8, 1),   256, 0, stream>>>(sa_wv,    WTS + oVw,    512,  256,  FLAG);
  wtrans_k<<<dim3(4, 8, 1),   256, 0, stream>>>(sa_wq,    WTS + oQw,    512,  256,  FLAG);
  wtrans_k<<<dim3(8, 4, 1),   256, 0, stream>>>(sa_wo,    WTS + oWo,    256,  512,  FLAG);
  wtrans_k<<<dim3(24, 8, 1),  256, 0, stream>>>(gru_wih,  WTS + oGih,   512,  1536, FLAG);
  wtrans_k<<<dim3(24, 8, 1),  256, 0, stream>>>(gru_whh,  WTS + oGhh,   512,  1536, FLAG);
  wtrans_k<<<dim3(8, 8, 1),   256, 0, stream>>>(sa_mlp_w1, WTS + oMlp1, 512,  512,  FLAG);
  wtrans_k<<<dim3(8, 8, 1),   256, 0, stream>>>(sa_mlp_w2, WTS + oMlp2, 512,  512,  FLAG);
  wtrans_k<<<dim3(2, 2, 1),   256, 0, stream>>>(rp_w2,    WTS + oRp2,   128,  128,  FLAG);
  wtrans_k<<<dim3(8, 8, 6),   256, 0, stream>>>(wq,       WTS + oWq,    512,  512,  FLAG);
  wtrans_k<<<dim3(8, 8, 6),   256, 0, stream>>>(wk,       WTS + oWk,    512,  512,  FLAG);
  wtrans_k<<<dim3(8, 8, 6),   256, 0, stream>>>(wv,       WTS + oWv,    512,  512,  FLAG);
  wtrans_k<<<dim3(8, 8, 6),   256, 0, stream>>>(wo,       WTS + oWol,   512,  512,  FLAG);
  wtrans_k<<<dim3(32, 8, 6),  256, 0, stream>>>(ff_w1,    WTS + oFf1,   512,  2048, FLAG);
  wtrans_k<<<dim3(8, 32, 6),  256, 0, stream>>>(ff_w2,    WTS + oFf2,   2048, 512,  FLAG);
  wtrans_k<<<dim3(8, 8, 1),   256, 0, stream>>>(pred_w,   WTS + oPred,  512,  512,  FLAG);

  // ---- patch embed (K-split 3, atomic into zeroed TOK) ----
  patchify_k<<<CDIV(NB*HWT*768, 256), 256, 0, stream>>>(images, XPB, FLAG);
  hipMemsetAsync(TOK, 0, (size_t)NB * HWT * DIM * sizeof(float), stream);
  GEMMM(XPB, 1, oPatch, patch_b, 0, TOK, 0, NB*HWT, DIM, 768, 0, 0, 3);
  addpos_k<<<CDIV(NB*HWT*DIM, 256), 256, 0, stream>>>(TOK, hpos, wpos, FLAG);

  // ---- slot attention: k, v ----
  ln512_k<<<NB*HWT, 256, 0, stream>>>(TOK, sa_ln_in_g, sa_ln_in_b, INPB, FLAG);
  gemm_mfma_duo<<<dim3(4, 16, 2), 256, 0, stream>>>(
      INPB, INPB, 1, WTS, oKw, oVw, sa_bk, sa_bv, KB, VB, 0, NB*HWT, 256, DIM, FLAG);
  slots_init_k<<<CDIV(NB*NSL*DIM, 256), 256, 0, stream>>>(slots_mu, slots_logsig, slot_noise, SLOTS, FLAG);

  for (int it = 0; it < 3; ++it) {
    ln512_k<<<MS, 256, 0, stream>>>(SLOTS, sa_ln_sl_g, sa_ln_sl_b, SLNB, FLAG);
    GEMMM(SLNB, 1, oQw, sa_bq, 0, QB, 0, MS, 256, DIM, 0, 0, 1);
    slot_dots_k<<<NB*4*NSL, 256, 0, stream>>>(QB, KB, ATT);
    softmax_slots_k<<<16, 256, 0, stream>>>(ATT);
    renorm_attn_k<<<NB*4*NSL, 256, 0, stream>>>(ATT);
    slot_upd_k<<<MS, 256, 0, stream>>>(ATT, VB, UPD);
    GEMMM(UPD, 0, oWo, sa_bo, 0, UPDP, 0, MS, DIM, 256, 0, 0, 1);
    gemm_mfma_duo<<<dim3(24, 4, 2), 256, 0, stream>>>(
        UPDP, SLOTS, 0, WTS, oGih, oGhh, gru_bih, gru_bhh, GX, GH, 0, MS, 1536, DIM, FLAG);
    gru_k<<<CDIV(NB*NSL*DIM, 256), 256, 0, stream>>>(GX, GH, SLOTS);
    ln512_k<<<MS, 256, 0, stream>>>(SLOTS, sa_ln_ff_g, sa_ln_ff_b, SLNB, FLAG);
    GEMMM(SLNB, 1, oMlp1, sa_mlp_b1, 0, HIDSB, 1, MS, DIM, DIM, 1, 0, 1);
    GEMMM(HIDSB, 1, oMlp2, sa_mlp_b2, 0, SLOTS, 0, MS, DIM, DIM, 0, 1, 1);
  }

  // ---- rel-pos bias ----
  gemm_k<<<dim3(1, CDIV(MS,64)), dim3(16,16), 0, stream>>>(
      SLOTS, s2c_w, 0, s2c_b, 0, SC, MS, 2, DIM, FLAG);
  build_coords_k<<<CDIV(NB*NT, 256), 256, 0, stream>>>(SC, CRD);
  relpos_table_k<<<961, 128, 0, stream>>>(rp_w1, rp_b1, rp_w2, rp_b2, rp_w3, rp_b3, TAB, FLAG);
  bias_fill_k<<<CDIV(NB*NH*HWT*HWT, 256), 256, 0, stream>>>(TAB, BIAS);
  {
    unsigned short* H1 = HBB;
    unsigned short* H2 = HBB + (size_t)PCH * 128;
    for (int c = 0; c < 2; ++c) {
      int pb = c * PCH;
      rp_l1_k<<<CDIV(PCH*128, 256), 256, 0, stream>>>(CRD, rp_w1, rp_b1, H1, pb, PCH, FLAG);
      GEMMM(H1, 1, oRp2, rp_b2, 0, H2, 1, PCH, 128, 128, 3, 0, 1);
      rp_l3_k<<<CDIV(PCH,32), 256, 0, stream>>>(H2, rp_w3, rp_b3, BIAS, pb, PCH, FLAG);
    }
  }

  // ---- transformer ----
  build_x_k<<<CDIV(NB*NT*DIM, 256), 256, 0, stream>>>(SLOTS, TOK, X);
  for (int l = 0; l < 6; ++l) {
    size_t lw = (size_t)l * 512 * 512;
    rms512_k<<<MROW, 256, 0, stream>>>(X, attn_g, l * DIM, HBB, FLAG);
    gemm_mfma_tri<<<dim3(8, 20, 3), 256, 0, stream>>>(
        HBB, 1, WTS, oWq + lw, oWk + lw, oWv + lw, QHB, KHB, VHB, 1, MROW, DIM, DIM, FLAG);
    attn_sim_k<<<dim3(CDIV(NT,64), CDIV(NT,64), NB*NH), 256, 0, stream>>>(QHB, KHB, BIAS, SIM);
    softmax_prob_k<<<NB*NH*NT, 256, 0, stream>>>(SIM, PROBB);
    attn_av_k<<<dim3(CDIV(NT,64), NB*NH), 256, 0, stream>>>(PROBB, VHB, OBB);
    GEMMM(OBB, 1, oWol + lw, (const void*)nullptr, 0, X, 0, MROW, DIM, DIM, 0, 1, 2);
    rms512_k<<<MROW, 256, 0, stream>>>(X, ff_g, l * DIM, HBB, FLAG);
    GEMMM(HBB, 1, oFf1 + (size_t)l * 512 * 2048, ff_b1, l * FF, FFHB, 1, MROW, FF, DIM, 2, 0, 1);
    GEMMM(FFHB, 1, oFf2 + (size_t)l * 2048 * 512, ff_b2, l * DIM, X, 0, MROW, DIM, FF, 0, 1, 4);
  }

  // ---- head (K-split 2, atomic into zeroed OUTT) ----
  rms512_k<<<MROW, 256, 0, stream>>>(X, final_g, 0, HBB, FLAG);
  hipMemsetAsync(OUTT, 0, (size_t)NB * NT * DIM * sizeof(float), stream);
  GEMMM(HBB, 1, oPred, pred_b, 0, OUTT, 0, MROW, DIM, DIM, 0, 0, 2);
  write_out_k<<<CDIV(NB*HWT*DIM, 256), 256, 0, stream>>>(OUTT, d_out, FLAG);

#undef GEMMM
}

// Round 8
// 1309.579 us; speedup vs baseline: 6.0398x; 1.0751x over previous
//
#include <hip/hip_runtime.h>
#include <hip/hip_bf16.h>

typedef __hip_bfloat16 bf16;
typedef short short8v __attribute__((ext_vector_type(8)));
typedef float float4v __attribute__((ext_vector_type(4)));

static __device__ __forceinline__ float b2f(bf16 x){ return __bfloat162float(x); }

// dtype-flexible input load: isbf ? bf16[i] : f32[i]
static __device__ __forceinline__ float ldin(const void* p, size_t i, bool isbf) {
  return isbf ? b2f(((const bf16*)p)[i]) : ((const float*)p)[i];
}

static __device__ __forceinline__ unsigned short f2bu(float f) {
  bf16 h = __float2bfloat16(f);
  return *reinterpret_cast<unsigned short*>(&h);
}

#define CDIV(a,b) (((a)+(b)-1)/(b))

// Model constants
#define NB   4
#define NSL  50
#define HWT  256
#define NT   306     // NSL + HWT
#define DIM  512
#define NH   8
#define FF   2048
#define RPP  28100   // mixed rel-pos pairs per batch
#define PCH  56200   // rel-pos chunk (2 chunks of NB*RPP/2)

// decode mixed-pair index q (0..RPP-1) -> (i,j)
static __device__ __forceinline__ void rp_decode(int q, int& i, int& j) {
  if (q < 15300) { i = q / NT; j = q % NT; }
  else { int r = q - 15300; i = NSL + r / NSL; j = r % NSL; }
}

// ---------------------------------------------------------------------------
// dtype detector (bf16 vs f32 served data); flag=1 means bf16.
// ---------------------------------------------------------------------------
__global__ void detect_k(const void* p, int* flag) {
  const unsigned short* u = (const unsigned short*)p;
  int t = threadIdx.x;
  int e = (u[t] >> 7) & 0xFF;
  __shared__ int anybad;
  if (t == 0) anybad = 0;
  __syncthreads();
  if (e >= 0x88) atomicOr(&anybad, 1);
  __syncthreads();
  if (t == 0) *flag = anybad ? 0 : 1;
}

// ---------------------------------------------------------------------------
// Weight transpose: W[K,N] (bf16 or f32) -> WT[N,K] bf16. K,N multiples of 64.
// blockIdx.z = layer slice (offset z*K*N both sides).
// ---------------------------------------------------------------------------
__global__ __launch_bounds__(256) void wtrans_k(const void* __restrict__ W,
    unsigned short* __restrict__ WT, int K, int N, const int* __restrict__ flagp) {
  const bool isbf = *flagp != 0;
  __shared__ unsigned short S[64 * 72];
  const size_t slice = (size_t)K * N * blockIdx.z;
  int n0 = blockIdx.x * 64, k0 = blockIdx.y * 64;
  int t = threadIdx.x;
  int kk = t >> 4, nn = (t & 15) * 4;
#pragma unroll
  for (int r = 0; r < 4; ++r) {
    int k = k0 + kk + r * 16;
    unsigned short v[4];
    if (isbf) {
      ushort4 u = *(const ushort4*)((const unsigned short*)W + slice + (size_t)k * N + n0 + nn);
      v[0]=u.x; v[1]=u.y; v[2]=u.z; v[3]=u.w;
    } else {
      float4 f = *(const float4*)((const float*)W + slice + (size_t)k * N + n0 + nn);
      v[0]=f2bu(f.x); v[1]=f2bu(f.y); v[2]=f2bu(f.z); v[3]=f2bu(f.w);
    }
#pragma unroll
    for (int i = 0; i < 4; ++i) S[(nn + i) * 72 + kk + r * 16] = v[i];
  }
  __syncthreads();
  int nr = t >> 2, kc = (t & 3) * 16;
  short8v s0 = *(const short8v*)&S[nr * 72 + kc];
  short8v s1 = *(const short8v*)&S[nr * 72 + kc + 8];
  unsigned short* dst = WT + slice + (size_t)(n0 + nr) * K + k0 + kc;
  *(short8v*)dst = s0;
  *(short8v*)(dst + 8) = s1;
}

// ---------------------------------------------------------------------------
// MFMA bf16 GEMM body v2: C = act(A[M,K] @ W + bias), W given TRANSPOSED as
// WT[N,K] bf16. Coalesced k-contig staging + register prefetch.
// mode: 0=store, 1=accumulate, 2=atomicAdd (K-split). bias added iff kbeg==0.
// act: 0 none, 1 relu, 2 gelu(tanh), 3 silu. N%64==0, K%32==0.
// ---------------------------------------------------------------------------
#define LDT 40
static __device__ __forceinline__ void gemm_body2(
    const void* __restrict__ A, int aty,
    const unsigned short* __restrict__ WT,
    const void* __restrict__ bias, size_t boff,
    void* __restrict__ C, int oty,
    int M, int N, int K, int kbeg, int kend,
    int act, int mode, bool isbf)
{
  __shared__ unsigned short As[64 * LDT];
  __shared__ unsigned short Bs[64 * LDT];
  const int tid = threadIdx.x;
  const int lane = tid & 63, wave = tid >> 6;
  const int quad = lane >> 4, ti = lane & 15;
  const int wm = (wave & 1) * 32, wn = (wave >> 1) * 32;
  const int bm = blockIdx.y * 64, bn = blockIdx.x * 64;
  const int srow = tid >> 2, sch = (tid & 3) * 8;

  unsigned short ha[8], hb[8];
  const int gm = bm + srow;
  const bool aok = gm < M;
  const unsigned short* Abf = (const unsigned short*)A + (size_t)gm * K;
  const float*          Af  = (const float*)A + (size_t)gm * K;
  const unsigned short* Bp  = WT + (size_t)(bn + srow) * K;

  auto fetchA = [&](int k0) {
    if (aok) {
      if (aty) {
        const ushort4* ap = (const ushort4*)(Abf + k0 + sch);
        ushort4 u0 = ap[0], u1 = ap[1];
        ha[0]=u0.x; ha[1]=u0.y; ha[2]=u0.z; ha[3]=u0.w;
        ha[4]=u1.x; ha[5]=u1.y; ha[6]=u1.z; ha[7]=u1.w;
      } else {
        const float* ap = Af + k0 + sch;
        float4 x = *(const float4*)ap, y = *(const float4*)(ap + 4);
        ha[0]=f2bu(x.x); ha[1]=f2bu(x.y); ha[2]=f2bu(x.z); ha[3]=f2bu(x.w);
        ha[4]=f2bu(y.x); ha[5]=f2bu(y.y); ha[6]=f2bu(y.z); ha[7]=f2bu(y.w);
      }
    } else {
      for (int i = 0; i < 8; ++i) ha[i] = 0;
    }
  };
  auto fetchB = [&](int k0) {
    const ushort4* bp = (const ushort4*)(Bp + k0 + sch);
    ushort4 u0 = bp[0], u1 = bp[1];
    hb[0]=u0.x; hb[1]=u0.y; hb[2]=u0.z; hb[3]=u0.w;
    hb[4]=u1.x; hb[5]=u1.y; hb[6]=u1.z; hb[7]=u1.w;
  };

  float4v acc00 = {0,0,0,0}, acc01 = {0,0,0,0}, acc10 = {0,0,0,0}, acc11 = {0,0,0,0};
  fetchA(kbeg); fetchB(kbeg);
  for (int k0 = kbeg; k0 < kend; k0 += 32) {
    *(short8v*)&As[srow * LDT + sch] = *(short8v*)ha;
    *(short8v*)&Bs[srow * LDT + sch] = *(short8v*)hb;
    __syncthreads();
    if (k0 + 32 < kend) { fetchA(k0 + 32); fetchB(k0 + 32); }
    short8v a0 = *reinterpret_cast<const short8v*>(&As[(wm + ti)      * LDT + quad * 8]);
    short8v a1 = *reinterpret_cast<const short8v*>(&As[(wm + 16 + ti) * LDT + quad * 8]);
    short8v b0 = *reinterpret_cast<const short8v*>(&Bs[(wn + ti)      * LDT + quad * 8]);
    short8v b1 = *reinterpret_cast<const short8v*>(&Bs[(wn + 16 + ti) * LDT + quad * 8]);
    acc00 = __builtin_amdgcn_mfma_f32_16x16x32_bf16(a0, b0, acc00, 0, 0, 0);
    acc01 = __builtin_amdgcn_mfma_f32_16x16x32_bf16(a0, b1, acc01, 0, 0, 0);
    acc10 = __builtin_amdgcn_mfma_f32_16x16x32_bf16(a1, b0, acc10, 0, 0, 0);
    acc11 = __builtin_amdgcn_mfma_f32_16x16x32_bf16(a1, b1, acc11, 0, 0, 0);
    __syncthreads();
  }

  float4v accs[2][2] = {{acc00, acc01}, {acc10, acc11}};
#pragma unroll
  for (int mi = 0; mi < 2; ++mi) {
#pragma unroll
    for (int ni = 0; ni < 2; ++ni) {
      int row0 = bm + wm + mi * 16 + quad * 4;
      int col  = bn + wn + ni * 16 + ti;
      float bv = (bias && kbeg == 0) ? ldin(bias, boff + col, isbf) : 0.f;
#pragma unroll
      for (int r = 0; r < 4; ++r) {
        int row = row0 + r;
        if (row >= M) continue;
        float v = accs[mi][ni][r] + bv;
        if (act == 1) v = fmaxf(v, 0.f);
        else if (act == 2) {
          float u = 0.7978845608028654f * (v + 0.044715f * v * v * v);
          v = 0.5f * v * (1.f + tanhf(u));
        } else if (act == 3) {
          v = v / (1.f + expf(-v));
        }
        size_t idx = (size_t)row * N + col;
        if (oty) ((bf16*)C)[idx] = __float2bfloat16(v);
        else {
          float* Cf = (float*)C;
          if (mode == 2) atomicAdd(&Cf[idx], v);
          else if (mode == 1) Cf[idx] += v;
          else Cf[idx] = v;
        }
      }
    }
  }
}

__global__ __launch_bounds__(256) void gemm_mfma(
    const void* A, int aty, const unsigned short* WT, size_t woff,
    const void* bias, size_t boff, void* C, int oty,
    int M, int N, int K, int act, int accum, int zsplit, const int* __restrict__ flagp)
{
  int ksz = K / zsplit;
  int kbeg = blockIdx.z * ksz;
  int mode = zsplit > 1 ? 2 : (accum ? 1 : 0);
  gemm_body2(A, aty, WT + woff, bias, boff, C, oty, M, N, K, kbeg, kbeg + ksz,
             act, mode, *flagp != 0);
}

// 3 GEMMs sharing A/shapes (QKV); blockIdx.z selects job
__global__ __launch_bounds__(256) void gemm_mfma_tri(
    const void* A, int aty, const unsigned short* WT, size_t o0, size_t o1, size_t o2,
    void* C0, void* C1, void* C2, int oty, int M, int N, int K,
    const int* __restrict__ flagp)
{
  size_t o = blockIdx.z == 0 ? o0 : (blockIdx.z == 1 ? o1 : o2);
  void* C = blockIdx.z == 0 ? C0 : (blockIdx.z == 1 ? C1 : C2);
  gemm_body2(A, aty, WT + o, nullptr, 0, C, oty, M, N, K, 0, K, 0, 0, *flagp != 0);
}

// 2 GEMMs, separate A/W/bias/C, shared shapes
__global__ __launch_bounds__(256) void gemm_mfma_duo(
    const void* A0, const void* A1, int aty, const unsigned short* WT, size_t o0, size_t o1,
    const void* bias0, const void* bias1, void* C0, void* C1, int oty,
    int M, int N, int K, const int* __restrict__ flagp)
{
  const void* A = blockIdx.z ? A1 : A0;
  size_t o = blockIdx.z ? o1 : o0;
  const void* bias = blockIdx.z ? bias1 : bias0;
  void* C = blockIdx.z ? C1 : C0;
  gemm_body2(A, aty, WT + o, bias, 0, C, oty, M, N, K, 0, K, 0, 0, *flagp != 0);
}

// ---------------------------------------------------------------------------
// slot coords projection: SC[row,0:2] = SLOTS[row,:] @ s2c_w + s2c_b
// one block per row (200 blocks)
// ---------------------------------------------------------------------------
__global__ void s2c_k(const float* __restrict__ slots, const void* __restrict__ w,
                      const void* __restrict__ bv, float* __restrict__ sc,
                      const int* __restrict__ flagp) {
  const bool isbf = *flagp != 0;
  int row = blockIdx.x, t = threadIdx.x;
  const float* x = slots + (size_t)row * DIM;
  float v0 = x[t], v1 = x[t + 256];
  float a0 = v0 * ldin(w, 2 * t, isbf)     + v1 * ldin(w, 2 * (t + 256), isbf);
  float a1 = v0 * ldin(w, 2 * t + 1, isbf) + v1 * ldin(w, 2 * (t + 256) + 1, isbf);
  __shared__ float r0[256], r1[256];
  r0[t] = a0; r1[t] = a1;
  __syncthreads();
  for (int o = 128; o > 0; o >>= 1) {
    if (t < o) { r0[t] += r0[t + o]; r1[t] += r1[t + o]; }
    __syncthreads();
  }
  if (t == 0) {
    sc[row * 2]     = r0[0] + ldin(bv, 0, isbf);
    sc[row * 2 + 1] = r1[0] + ldin(bv, 1, isbf);
  }
}

// ---------------------------------------------------------------------------
// Patch extraction (im2col) -> bf16
// ---------------------------------------------------------------------------
__global__ void patchify_k(const void* __restrict__ img, unsigned short* __restrict__ xp,
                           const int* __restrict__ flagp) {
  const bool isbf = *flagp != 0;
  int i = blockIdx.x * 256 + threadIdx.x;
  if (i >= NB * HWT * 768) return;
  int col = i % 768, row = i / 768;
  int c = col % 3, p2 = (col / 3) & 15, p1 = col / 48;
  int w = row & 15, h = (row >> 4) & 15, b = row >> 8;
  xp[i] = f2bu(ldin(img, (((size_t)(b * 3 + c) * 256 + h * 16 + p1) * 256) + w * 16 + p2, isbf));
}

__global__ void addpos_k(float* __restrict__ tok, const void* __restrict__ hp,
                         const void* __restrict__ wp, const int* __restrict__ flagp) {
  const bool isbf = *flagp != 0;
  int i = blockIdx.x * 256 + threadIdx.x;
  if (i >= NB * HWT * DIM) return;
  int d = i & 511;
  int row = i >> 9;
  int w = row & 15, h = (row >> 4) & 15;
  tok[i] += ldin(hp, h * DIM + d, isbf) + ldin(wp, w * DIM + d, isbf);
}

// ---------------------------------------------------------------------------
// LayerNorm (bf16 out) / RMSNorm (bf16 out) over 512-dim rows
// ---------------------------------------------------------------------------
__global__ void ln512_k(const float* __restrict__ X, const void* __restrict__ g,
                        const void* __restrict__ b, unsigned short* __restrict__ Y,
                        const int* __restrict__ flagp) {
  const bool isbf = *flagp != 0;
  int row = blockIdx.x, t = threadIdx.x;
  const float* x = X + (size_t)row * DIM;
  float v0 = x[t], v1 = x[t + 256];
  __shared__ float rs[256], rq[256];
  rs[t] = v0 + v1; rq[t] = v0 * v0 + v1 * v1;
  __syncthreads();
  for (int o = 128; o > 0; o >>= 1) {
    if (t < o) { rs[t] += rs[t + o]; rq[t] += rq[t + o]; }
    __syncthreads();
  }
  float mean = rs[0] * (1.f / 512.f);
  float var  = rq[0] * (1.f / 512.f) - mean * mean;
  float inv  = rsqrtf(var + 1e-5f);
  unsigned short* y = Y + (size_t)row * DIM;
  y[t]       = f2bu((v0 - mean) * inv * ldin(g, t, isbf)       + ldin(b, t, isbf));
  y[t + 256] = f2bu((v1 - mean) * inv * ldin(g, t + 256, isbf) + ldin(b, t + 256, isbf));
}

__global__ void rms512_k(const float* __restrict__ X, const void* __restrict__ g,
                         int goff, unsigned short* __restrict__ Y, const int* __restrict__ flagp) {
  const bool isbf = *flagp != 0;
  int row = blockIdx.x, t = threadIdx.x;
  const float* x = X + (size_t)row * DIM;
  float v0 = x[t], v1 = x[t + 256];
  __shared__ float rq[256];
  rq[t] = v0 * v0 + v1 * v1;
  __syncthreads();
  for (int o = 128; o > 0; o >>= 1) {
    if (t < o) rq[t] += rq[t + o];
    __syncthreads();
  }
  float nrm = sqrtf(rq[0]);
  float sc = 22.62741699796952f / fmaxf(nrm, 1e-12f);
  unsigned short* y = Y + (size_t)row * DIM;
  y[t]       = f2bu(v0 * sc * ldin(g, goff + t, isbf));
  y[t + 256] = f2bu(v1 * sc * ldin(g, goff + t + 256, isbf));
}

// ---------------------------------------------------------------------------
// Slot attention pieces
// ---------------------------------------------------------------------------
__global__ void slots_init_k(const void* __restrict__ mu, const void* __restrict__ ls,
                             const void* __restrict__ noise, float* __restrict__ slots,
                             const int* __restrict__ flagp) {
  const bool isbf = *flagp != 0;
  int i = blockIdx.x * 256 + threadIdx.x;
  if (i >= NB * NSL * DIM) return;
  int d = i & 511;
  slots[i] = ldin(mu, d, isbf) + expf(ldin(ls, d, isbf)) * ldin(noise, i, isbf);
}

__global__ void slot_dots_k(const float* __restrict__ q, const float* __restrict__ k,
                            float* __restrict__ dots) {
  int blk = blockIdx.x;                 // b*200 + h*50 + i
  int i = blk % 50, h = (blk / 50) & 3, b = blk / 200;
  int j = threadIdx.x;
  __shared__ float qs[64];
  if (threadIdx.x < 64) qs[threadIdx.x] = q[((size_t)(b * 50 + i)) * 256 + h * 64 + threadIdx.x];
  __syncthreads();
  const float* kr = k + ((size_t)(b * 256 + j)) * 256 + h * 64;
  float s = 0.f;
#pragma unroll 8
  for (int d = 0; d < 64; ++d) s = fmaf(qs[d], kr[d], s);
  dots[(((size_t)(b * 4 + h) * 50) + i) * 256 + j] = s * 0.125f;
}

__global__ void softmax_slots_k(float* __restrict__ dots) {
  int idx = blockIdx.x * 256 + threadIdx.x;
  if (idx >= 4096) return;
  int j = idx & 255, h = (idx >> 8) & 3, b = idx >> 10;
  float* base = dots + ((size_t)(b * 4 + h) * 50) * 256 + j;
  float m = -1e30f;
  for (int i = 0; i < 50; ++i) m = fmaxf(m, base[i * 256]);
  float s = 0.f;
  for (int i = 0; i < 50; ++i) { float e = expf(base[i * 256] - m); base[i * 256] = e; s += e; }
  float inv = 1.f / s;
  for (int i = 0; i < 50; ++i) base[i * 256] *= inv;
}

__global__ void renorm_attn_k(float* __restrict__ attn) {
  int t = threadIdx.x;
  float* row = attn + (size_t)blockIdx.x * 256;
  float v = row[t] + 1e-8f;
  __shared__ float rs[256];
  rs[t] = v;
  __syncthreads();
  for (int o = 128; o > 0; o >>= 1) {
    if (t < o) rs[t] += rs[t + o];
    __syncthreads();
  }
  row[t] = v / rs[0];
}

__global__ void slot_upd_k(const float* __restrict__ attn, const float* __restrict__ v,
                           float* __restrict__ upd) {
  int bi = blockIdx.x;        // b*50+i
  int b = bi / 50, i = bi % 50;
  int t = threadIdx.x, h = t >> 6;
  const float* arow = attn + ((size_t)((b * 4 + h) * 50) + i) * 256;
  float s = 0.f;
  for (int j = 0; j < 256; ++j) s = fmaf(arow[j], v[((size_t)(b * 256 + j)) * 256 + t], s);
  upd[(size_t)bi * 256 + t] = s;
}

// in-place safe (elementwise)
__global__ void gru_k(const float* __restrict__ gx, const float* __restrict__ gh,
                      float* __restrict__ slots) {
  int i = blockIdx.x * 256 + threadIdx.x;
  if (i >= NB * NSL * DIM) return;
  int row = i >> 9, d = i & 511;
  size_t b3 = (size_t)row * 1536;
  float xr = gx[b3 + d], xz = gx[b3 + 512 + d], xn = gx[b3 + 1024 + d];
  float hr = gh[b3 + d], hz = gh[b3 + 512 + d], hn = gh[b3 + 1024 + d];
  float r = 1.f / (1.f + expf(-(xr + hr)));
  float z = 1.f / (1.f + expf(-(xz + hz)));
  float n = tanhf(xn + r * hn);
  float prev = slots[i];
  slots[i] = (1.f - z) * n + z * prev;
}

// ---------------------------------------------------------------------------
// Rel-pos bias
// ---------------------------------------------------------------------------
__global__ void build_coords_k(const float* __restrict__ sc, float* __restrict__ coords) {
  int i = blockIdx.x * 256 + threadIdx.x;
  if (i >= NB * NT) return;
  int b = i / NT, n = i % NT;
  float cx, cy;
  if (n < NSL) { cx = sc[(b * NSL + n) * 2]; cy = sc[(b * NSL + n) * 2 + 1]; }
  else { int t = n - NSL; cx = (float)(t >> 4); cy = (float)(t & 15); }
  coords[i * 2] = cx; coords[i * 2 + 1] = cy;
}

__global__ void relpos_table_k(const void* w1, const void* b1, const void* w2,
                               const void* b2, const void* w3, const void* b3,
                               float* __restrict__ tab, const int* __restrict__ flagp) {
  const bool isbf = *flagp != 0;
  int blk = blockIdx.x;  // 961
  float r0 = (float)(blk / 31 - 15), r1 = (float)(blk % 31 - 15);
  int t = threadIdx.x;
  __shared__ float h1[128], h2[128];
  float a = fmaf(r0, ldin(w1, t, isbf), fmaf(r1, ldin(w1, 128 + t, isbf), ldin(b1, t, isbf)));
  h1[t] = a / (1.f + expf(-a));
  __syncthreads();
  float s = ldin(b2, t, isbf);
#pragma unroll 4
  for (int k = 0; k < 128; ++k) s = fmaf(h1[k], ldin(w2, k * 128 + t, isbf), s);
  h2[t] = s / (1.f + expf(-s));
  __syncthreads();
  if (t < 8) {
    float o = ldin(b3, t, isbf);
#pragma unroll 4
    for (int k = 0; k < 128; ++k) o = fmaf(h2[k], ldin(w3, k * 8 + t, isbf), o);
    tab[blk * 8 + t] = o;
  }
}

__global__ void bias_fill_k(const float* __restrict__ tab, float* __restrict__ bias) {
  int i = blockIdx.x * 256 + threadIdx.x;
  if (i >= NB * NH * HWT * HWT) return;
  int jj = i & 255, ii = (i >> 8) & 255, h = (i >> 16) & 7, b = i >> 19;
  int di = (ii >> 4) - (jj >> 4) + 15;
  int dj = (ii & 15) - (jj & 15) + 15;
  bias[(((size_t)(b * NH + h) * NT) + NSL + ii) * NT + NSL + jj] = tab[(di * 31 + dj) * 8 + h];
}

// layer1 silu -> H1 bf16 [pcount,128], chunked
__global__ void rp_l1_k(const float* __restrict__ coords, const void* w1, const void* b1,
                        unsigned short* __restrict__ H, int pbase, int pcount,
                        const int* __restrict__ flagp) {
  const bool isbf = *flagp != 0;
  int idx = blockIdx.x * 256 + threadIdx.x;
  if (idx >= pcount * 128) return;
  int pl = idx >> 7, u = idx & 127;
  int p = pbase + pl;
  int q = p % RPP, bb = p / RPP;
  int ii, jj;
  rp_decode(q, ii, jj);
  float r0 = coords[(bb * NT + ii) * 2]     - coords[(bb * NT + jj) * 2];
  float r1 = coords[(bb * NT + ii) * 2 + 1] - coords[(bb * NT + jj) * 2 + 1];
  float a = fmaf(r0, ldin(w1, u, isbf), fmaf(r1, ldin(w1, 128 + u, isbf), ldin(b1, u, isbf)));
  H[(size_t)pl * 128 + u] = f2bu(a / (1.f + expf(-a)));
}

// layer3 (128->8) + scatter. 32 pairs/block, 8 threads/pair.
__global__ __launch_bounds__(256) void rp_l3_k(
    const unsigned short* __restrict__ H2, const void* w3, const void* b3,
    float* __restrict__ bias, int pbase, int pcount, const int* __restrict__ flagp) {
  const bool isbf = *flagp != 0;
  __shared__ float W3s[128 * 8];
  int t = threadIdx.x;
  for (int e = t; e < 1024; e += 256) W3s[e] = ldin(w3, e, isbf);
  __syncthreads();
  int pl = blockIdx.x * 32 + (t >> 3), hh = t & 7;
  if (pl >= pcount) return;
  int p = pbase + pl;
  int q = p % RPP, bb = p / RPP;
  int ii, jj;
  rp_decode(q, ii, jj);
  float s = ldin(b3, hh, isbf);
  const unsigned short* hrow = H2 + (size_t)pl * 128;
#pragma unroll 8
  for (int k = 0; k < 128; ++k) {
    bf16 hv = *reinterpret_cast<const bf16*>(&hrow[k]);
    s = fmaf(b2f(hv), W3s[k * 8 + hh], s);
  }
  bias[((size_t)(bb * NH + hh) * NT + ii) * NT + jj] = s;
}

// ---------------------------------------------------------------------------
// Transformer pieces
// ---------------------------------------------------------------------------
__global__ void build_x_k(const float* __restrict__ slots, const float* __restrict__ tok,
                          float* __restrict__ x) {
  int i = blockIdx.x * 256 + threadIdx.x;
  if (i >= NB * NT * DIM) return;
  int d = i & 511, n = (i >> 9) % NT, b = i / (NT * DIM);
  x[i] = (n < NSL) ? slots[((size_t)(b * NSL + n)) * DIM + d]
                   : tok[((size_t)(b * HWT + (n - NSL))) * DIM + d];
}

// ---------------------------------------------------------------------------
// Fused attention: per block = 32 q-rows x one (b,h). S = QK^T*0.125 + bias
// (f32 LDS), in-block softmax (8 lanes/row), P bf16 in place, O = P V.
// grid (10, 32). LDS ~56 KB.
// ---------------------------------------------------------------------------
__global__ __launch_bounds__(256) void attn_fused_k(
    const unsigned short* __restrict__ Qb, const unsigned short* __restrict__ Kb,
    const unsigned short* __restrict__ Vb, const float* __restrict__ bias,
    unsigned short* __restrict__ Ob)
{
  const int bh = blockIdx.y, b = bh >> 3, h = bh & 7;
  const int i0 = blockIdx.x * 32;
  __shared__ unsigned short Qs[32 * 72];
  __shared__ unsigned short Ks[64 * 72];
  __shared__ float S[32 * 332];
  unsigned short* P = (unsigned short*)S;   // bf16 prob, row stride 664 shorts

  const int tid = threadIdx.x;
  const int lane = tid & 63, wave = tid >> 6, quad = lane >> 4, ti = lane & 15;
  const int mi = wave & 1, nh = wave >> 1;

  // ---- load Q tile (32 x 64) ----
  {
    int r = tid >> 3, c = (tid & 7) * 8;
    int gi = i0 + r;
    ushort4 u0 = {0,0,0,0}, u1 = {0,0,0,0};
    if (gi < NT) {
      const ushort4* p = (const ushort4*)(Qb + ((size_t)(b * NT + gi)) * DIM + h * 64 + c);
      u0 = p[0]; u1 = p[1];
    }
    *(ushort4*)&Qs[r * 72 + c] = u0;
    *(ushort4*)&Qs[r * 72 + c + 4] = u1;
  }

  // ---- phase 1: scores ----
  for (int kt = 0; kt < 5; ++kt) {
    __syncthreads();
    {
      int kr = tid >> 2, c = (tid & 3) * 16;
      int gj = kt * 64 + kr;
      ushort4 v[4] = {{0,0,0,0},{0,0,0,0},{0,0,0,0},{0,0,0,0}};
      if (gj < NT) {
        const ushort4* p = (const ushort4*)(Kb + ((size_t)(b * NT + gj)) * DIM + h * 64 + c);
#pragma unroll
        for (int i = 0; i < 4; ++i) v[i] = p[i];
      }
#pragma unroll
      for (int i = 0; i < 4; ++i) *(ushort4*)&Ks[kr * 72 + c + i * 4] = v[i];
    }
    __syncthreads();
#pragma unroll
    for (int ntl = 0; ntl < 2; ++ntl) {
      int nt = nh * 2 + ntl;
      float4v acc = {0,0,0,0};
#pragma unroll
      for (int ks = 0; ks < 2; ++ks) {
        short8v a  = *(const short8v*)&Qs[(mi * 16 + ti) * 72 + ks * 32 + quad * 8];
        short8v bb = *(const short8v*)&Ks[(nt * 16 + ti) * 72 + ks * 32 + quad * 8];
        acc = __builtin_amdgcn_mfma_f32_16x16x32_bf16(a, bb, acc, 0, 0, 0);
      }
      int colL = kt * 64 + nt * 16 + ti;
      int row0 = mi * 16 + quad * 4;
#pragma unroll
      for (int r = 0; r < 4; ++r) {
        int row_g = i0 + row0 + r;
        float val;
        if (colL < NT) {
          float bv = (row_g < NT) ? bias[((size_t)bh * NT + row_g) * NT + colL] : 0.f;
          val = acc[r] * 0.125f + bv;
        } else val = -1e30f;
        S[(row0 + r) * 332 + colL] = val;
      }
    }
  }
  __syncthreads();

  // ---- phase 2: softmax (rows in regs), write P bf16 in place ----
  {
    int rl = tid >> 3, sub = tid & 7;
    float sv[40];
#pragma unroll
    for (int k = 0; k < 40; ++k) sv[k] = S[rl * 332 + sub + k * 8];
    float m = -1e30f;
#pragma unroll
    for (int k = 0; k < 40; ++k) m = fmaxf(m, sv[k]);
    m = fmaxf(m, __shfl_xor(m, 1));
    m = fmaxf(m, __shfl_xor(m, 2));
    m = fmaxf(m, __shfl_xor(m, 4));
    float s = 0.f;
#pragma unroll
    for (int k = 0; k < 40; ++k) { float e = __expf(sv[k] - m); sv[k] = e; s += e; }
    s += __shfl_xor(s, 1);
    s += __shfl_xor(s, 2);
    s += __shfl_xor(s, 4);
    float inv = 1.f / s;
    __syncthreads();   // all S reads complete before bf16 overwrite
#pragma unroll
    for (int k = 0; k < 40; ++k) P[rl * 664 + sub + k * 8] = f2bu(sv[k] * inv);
  }

  // ---- phase 3: O = P V ----
  float4v oacc[2] = {{0,0,0,0},{0,0,0,0}};
  for (int vt = 0; vt < 5; ++vt) {
    __syncthreads();
    {
      int key = tid & 63, d0 = (tid >> 6) * 16;
      int gj = vt * 64 + key;
      unsigned short hv[16];
      if (gj < NT) {
        const ushort4* p = (const ushort4*)(Vb + ((size_t)(b * NT + gj)) * DIM + h * 64 + d0);
#pragma unroll
        for (int i = 0; i < 4; ++i) {
          ushort4 u = p[i];
          hv[i*4+0]=u.x; hv[i*4+1]=u.y; hv[i*4+2]=u.z; hv[i*4+3]=u.w;
        }
      } else {
#pragma unroll
        for (int i = 0; i < 16; ++i) hv[i] = 0;
      }
#pragma unroll
      for (int i = 0; i < 16; ++i) Ks[(d0 + i) * 72 + key] = hv[i];
    }
    __syncthreads();
#pragma unroll
    for (int ntl = 0; ntl < 2; ++ntl) {
      int nt = nh * 2 + ntl;
#pragma unroll
      for (int ks = 0; ks < 2; ++ks) {
        short8v a  = *(const short8v*)&P[(mi * 16 + ti) * 664 + vt * 64 + ks * 32 + quad * 8];
        short8v bb = *(const short8v*)&Ks[(nt * 16 + ti) * 72 + ks * 32 + quad * 8];
        oacc[ntl] = __builtin_amdgcn_mfma_f32_16x16x32_bf16(a, bb, oacc[ntl], 0, 0, 0);
      }
    }
  }

  // ---- write O ----
#pragma unroll
  for (int ntl = 0; ntl < 2; ++ntl) {
    int dim = nh * 32 + ntl * 16 + ti;
#pragma unroll
    for (int r = 0; r < 4; ++r) {
      int row_g = i0 + mi * 16 + quad * 4 + r;
      if (row_g < NT)
        Ob[((size_t)(b * NT + row_g)) * DIM + h * 64 + dim] = f2bu(oacc[ntl][r]);
    }
  }
}

__global__ void write_out_k(const float* __restrict__ tmp, void* __restrict__ out,
                            const int* __restrict__ flagp) {
  const bool isbf = *flagp != 0;
  int i = blockIdx.x * 256 + threadIdx.x;
  if (i >= NB * HWT * DIM) return;
  int d = i & 511, tt = (i >> 9) & 255, b = i / (HWT * DIM);
  float v = tmp[((size_t)(b * NT + NSL + tt)) * DIM + d];
  if (isbf) ((bf16*)out)[i] = __float2bfloat16(v);
  else      ((float*)out)[i] = v;
}

// ---------------------------------------------------------------------------
extern "C" void kernel_launch(void* const* d_in, const int* in_sizes, int n_in,
                              void* d_out, int out_size, void* d_ws, size_t ws_size,
                              hipStream_t stream) {
  const void* images        = d_in[0];
  const void* slot_noise    = d_in[1];
  const void* patch_w       = d_in[2];
  const void* patch_b       = d_in[3];
  const void* hpos          = d_in[4];
  const void* wpos          = d_in[5];
  const void* rp_w1         = d_in[6];
  const void* rp_b1         = d_in[7];
  const void* rp_w2         = d_in[8];
  const void* rp_b2         = d_in[9];
  const void* rp_w3         = d_in[10];
  const void* rp_b3         = d_in[11];
  const void* slots_mu      = d_in[12];
  const void* slots_logsig  = d_in[13];
  const void* sa_ln_in_g    = d_in[14];
  const void* sa_ln_in_b    = d_in[15];
  const void* sa_ln_sl_g    = d_in[16];
  const void* sa_ln_sl_b    = d_in[17];
  const void* sa_wq         = d_in[18];
  const void* sa_bq         = d_in[19];
  const void* sa_wk         = d_in[20];
  const void* sa_bk         = d_in[21];
  const void* sa_wv         = d_in[22];
  const void* sa_bv         = d_in[23];
  const void* sa_wo         = d_in[24];
  const void* sa_bo         = d_in[25];
  const void* gru_wih       = d_in[26];
  const void* gru_whh       = d_in[27];
  const void* gru_bih       = d_in[28];
  const void* gru_bhh       = d_in[29];
  const void* sa_ln_ff_g    = d_in[30];
  const void* sa_ln_ff_b    = d_in[31];
  const void* sa_mlp_w1     = d_in[32];
  const void* sa_mlp_b1     = d_in[33];
  const void* sa_mlp_w2     = d_in[34];
  const void* sa_mlp_b2     = d_in[35];
  const void* s2c_w         = d_in[36];
  const void* s2c_b         = d_in[37];
  const void* attn_g        = d_in[38];
  const void* wq            = d_in[39];
  const void* wk            = d_in[40];
  const void* wv            = d_in[41];
  const void* wo            = d_in[42];
  const void* ff_g          = d_in[43];
  const void* ff_w1         = d_in[44];
  const void* ff_b1         = d_in[45];
  const void* ff_w2         = d_in[46];
  const void* ff_b2         = d_in[47];
  const void* final_g       = d_in[48];
  const void* pred_w        = d_in[49];
  const void* pred_b        = d_in[50];

  float* ws = (float*)d_ws;
  int* FLAG = (int*)ws;
  size_t off = 16;
  auto alloc = [&](size_t n) { float* p = ws + off; off += (n + 15) & ~(size_t)15; return p; };
  float* TOK   = alloc((size_t)NB * HWT * DIM);
  unsigned short* INPB = (unsigned short*)alloc((size_t)NB * HWT * DIM / 2);
  float* KB    = alloc((size_t)NB * HWT * 256);
  float* VB    = alloc((size_t)NB * HWT * 256);
  float* SLOTS = alloc((size_t)NB * NSL * DIM);
  unsigned short* SLNB = (unsigned short*)alloc((size_t)NB * NSL * DIM / 2);
  float* QB    = alloc((size_t)NB * NSL * 256);
  float* ATT   = alloc((size_t)NB * 4 * NSL * HWT);
  float* UPD   = alloc((size_t)NB * NSL * 256);
  float* UPDP  = alloc((size_t)NB * NSL * DIM);
  unsigned short* HIDSB = (unsigned short*)alloc((size_t)NB * NSL * DIM / 2);
  float* SC    = alloc((size_t)NB * NSL * 2);
  float* CRD   = alloc((size_t)NB * NT * 2);
  float* TAB   = alloc((size_t)961 * 8);
  float* BIAS  = alloc((size_t)NB * NH * NT * NT);
  float* X     = alloc((size_t)NB * NT * DIM);
  // attention-region (contiguous; aliased by rel-pos H1/H2 chunks)
  unsigned short* HBB  = (unsigned short*)alloc((size_t)NB * NT * DIM / 2);
  unsigned short* QHB  = (unsigned short*)alloc((size_t)NB * NT * DIM / 2);
  unsigned short* KHB  = (unsigned short*)alloc((size_t)NB * NT * DIM / 2);
  unsigned short* VHB  = (unsigned short*)alloc((size_t)NB * NT * DIM / 2);
  float* SIM   = alloc((size_t)NB * NH * NT * NT);        // used as GRU-gate + rel-pos alias space
  unsigned short* PROBB = (unsigned short*)alloc((size_t)NB * NH * NT * 320 / 2); // alias space
  unsigned short* OBB  = (unsigned short*)alloc((size_t)NB * NT * DIM / 2);
  unsigned short* FFHB = (unsigned short*)alloc((size_t)NB * NT * FF / 2);
  float* OUTT  = alloc((size_t)NB * NT * DIM);
  (void)PROBB;
  // aliases (dead-region reuse)
  unsigned short* XPB = (unsigned short*)OUTT;            // im2col; dead before head
  float* GX = SIM;                                        // GRU gates; dead before transformer
  float* GH = SIM + (size_t)NB * NSL * 1536;
  // transposed-weight arena (bf16 [N,K] per weight)
  const size_t oPatch = 0;
  const size_t oKw    = oPatch + (size_t)512 * 768;
  const size_t oVw    = oKw    + (size_t)256 * 512;
  const size_t oQw    = oVw    + (size_t)256 * 512;
  const size_t oWo    = oQw    + (size_t)256 * 512;
  const size_t oGih   = oWo    + (size_t)512 * 256;
  const size_t oGhh   = oGih   + (size_t)1536 * 512;
  const size_t oMlp1  = oGhh   + (size_t)1536 * 512;
  const size_t oMlp2  = oMlp1  + (size_t)512 * 512;
  const size_t oRp2   = oMlp2  + (size_t)512 * 512;
  const size_t oWq    = oRp2   + (size_t)128 * 128;
  const size_t oWk    = oWq    + (size_t)6 * 512 * 512;
  const size_t oWv    = oWk    + (size_t)6 * 512 * 512;
  const size_t oWol   = oWv    + (size_t)6 * 512 * 512;
  const size_t oFf1   = oWol   + (size_t)6 * 512 * 512;
  const size_t oFf2   = oFf1   + (size_t)6 * 512 * 2048;
  const size_t oPred  = oFf2   + (size_t)6 * 2048 * 512;
  const size_t wtTotal = oPred + (size_t)512 * 512;
  unsigned short* WTS = (unsigned short*)alloc((wtTotal + 1) / 2);
  (void)ws_size; (void)in_sizes; (void)n_in; (void)out_size;

#define GEMMM(A_, ATY_, WOFF_, BIAS_, BOFF_, C_, OTY_, M_, N_, K_, ACT_, ACC_, ZS_) \
  gemm_mfma<<<dim3((N_)/64, CDIV((M_),64), (ZS_)), 256, 0, stream>>>( \
      A_, ATY_, WTS, (size_t)(WOFF_), BIAS_, (size_t)(BOFF_), C_, OTY_, M_, N_, K_, ACT_, ACC_, ZS_, FLAG)

  const int MROW = NB * NT;   // 1224
  const int MS   = NB * NSL;  // 200

  // ---- dtype detection + weight transposes ----
  detect_k<<<1, 256, 0, stream>>>(images, FLAG);
  wtrans_k<<<dim3(8, 12, 1),  256, 0, stream>>>(patch_w,  WTS + oPatch, 768,  512,  FLAG);
  wtrans_k<<<dim3(4, 8, 1),   256, 0, stream>>>(sa_wk,    WTS + oKw,    512,  256,  FLAG);
  wtrans_k<<<dim3(4, 8, 1),   256, 0, stream>>>(sa_wv,    WTS + oVw,    512,  256,  FLAG);
  wtrans_k<<<dim3(4, 8, 1),   256, 0, stream>>>(sa_wq,    WTS + oQw,    512,  256,  FLAG);
  wtrans_k<<<dim3(8, 4, 1),   256, 0, stream>>>(sa_wo,    WTS + oWo,    256,  512,  FLAG);
  wtrans_k<<<dim3(24, 8, 1),  256, 0, stream>>>(gru_wih,  WTS + oGih,   512,  1536, FLAG);
  wtrans_k<<<dim3(24, 8, 1),  256, 0, stream>>>(gru_whh,  WTS + oGhh,   512,  1536, FLAG);
  wtrans_k<<<dim3(8, 8, 1),   256, 0, stream>>>(sa_mlp_w1, WTS + oMlp1, 512,  512,  FLAG);
  wtrans_k<<<dim3(8, 8, 1),   256, 0, stream>>>(sa_mlp_w2, WTS + oMlp2, 512,  512,  FLAG);
  wtrans_k<<<dim3(2, 2, 1),   256, 0, stream>>>(rp_w2,    WTS + oRp2,   128,  128,  FLAG);
  wtrans_k<<<dim3(8, 8, 6),   256, 0, stream>>>(wq,       WTS + oWq,    512,  512,  FLAG);
  wtrans_k<<<dim3(8, 8, 6),   256, 0, stream>>>(wk,       WTS + oWk,    512,  512,  FLAG);
  wtrans_k<<<dim3(8, 8, 6),   256, 0, stream>>>(wv,       WTS + oWv,    512,  512,  FLAG);
  wtrans_k<<<dim3(8, 8, 6),   256, 0, stream>>>(wo,       WTS + oWol,   512,  512,  FLAG);
  wtrans_k<<<dim3(32, 8, 6),  256, 0, stream>>>(ff_w1,    WTS + oFf1,   512,  2048, FLAG);
  wtrans_k<<<dim3(8, 32, 6),  256, 0, stream>>>(ff_w2,    WTS + oFf2,   2048, 512,  FLAG);
  wtrans_k<<<dim3(8, 8, 1),   256, 0, stream>>>(pred_w,   WTS + oPred,  512,  512,  FLAG);

  // ---- patch embed (K-split 3, atomic into zeroed TOK) ----
  patchify_k<<<CDIV(NB*HWT*768, 256), 256, 0, stream>>>(images, XPB, FLAG);
  hipMemsetAsync(TOK, 0, (size_t)NB * HWT * DIM * sizeof(float), stream);
  GEMMM(XPB, 1, oPatch, patch_b, 0, TOK, 0, NB*HWT, DIM, 768, 0, 0, 3);
  addpos_k<<<CDIV(NB*HWT*DIM, 256), 256, 0, stream>>>(TOK, hpos, wpos, FLAG);

  // ---- slot attention: k, v ----
  ln512_k<<<NB*HWT, 256, 0, stream>>>(TOK, sa_ln_in_g, sa_ln_in_b, INPB, FLAG);
  gemm_mfma_duo<<<dim3(4, 16, 2), 256, 0, stream>>>(
      INPB, INPB, 1, WTS, oKw, oVw, sa_bk, sa_bv, KB, VB, 0, NB*HWT, 256, DIM, FLAG);
  slots_init_k<<<CDIV(NB*NSL*DIM, 256), 256, 0, stream>>>(slots_mu, slots_logsig, slot_noise, SLOTS, FLAG);

  for (int it = 0; it < 3; ++it) {
    ln512_k<<<MS, 256, 0, stream>>>(SLOTS, sa_ln_sl_g, sa_ln_sl_b, SLNB, FLAG);
    GEMMM(SLNB, 1, oQw, sa_bq, 0, QB, 0, MS, 256, DIM, 0, 0, 1);
    slot_dots_k<<<NB*4*NSL, 256, 0, stream>>>(QB, KB, ATT);
    softmax_slots_k<<<16, 256, 0, stream>>>(ATT);
    renorm_attn_k<<<NB*4*NSL, 256, 0, stream>>>(ATT);
    slot_upd_k<<<MS, 256, 0, stream>>>(ATT, VB, UPD);
    GEMMM(UPD, 0, oWo, sa_bo, 0, UPDP, 0, MS, DIM, 256, 0, 0, 1);
    gemm_mfma_duo<<<dim3(24, 4, 2), 256, 0, stream>>>(
        UPDP, SLOTS, 0, WTS, oGih, oGhh, gru_bih, gru_bhh, GX, GH, 0, MS, 1536, DIM, FLAG);
    gru_k<<<CDIV(NB*NSL*DIM, 256), 256, 0, stream>>>(GX, GH, SLOTS);
    ln512_k<<<MS, 256, 0, stream>>>(SLOTS, sa_ln_ff_g, sa_ln_ff_b, SLNB, FLAG);
    GEMMM(SLNB, 1, oMlp1, sa_mlp_b1, 0, HIDSB, 1, MS, DIM, DIM, 1, 0, 1);
    GEMMM(HIDSB, 1, oMlp2, sa_mlp_b2, 0, SLOTS, 0, MS, DIM, DIM, 0, 1, 1);
  }

  // ---- rel-pos bias ----
  s2c_k<<<MS, 256, 0, stream>>>(SLOTS, s2c_w, s2c_b, SC, FLAG);
  build_coords_k<<<CDIV(NB*NT, 256), 256, 0, stream>>>(SC, CRD);
  relpos_table_k<<<961, 128, 0, stream>>>(rp_w1, rp_b1, rp_w2, rp_b2, rp_w3, rp_b3, TAB, FLAG);
  bias_fill_k<<<CDIV(NB*NH*HWT*HWT, 256), 256, 0, stream>>>(TAB, BIAS);
  {
    unsigned short* H1 = HBB;
    unsigned short* H2 = HBB + (size_t)PCH * 128;
    for (int c = 0; c < 2; ++c) {
      int pb = c * PCH;
      rp_l1_k<<<CDIV(PCH*128, 256), 256, 0, stream>>>(CRD, rp_w1, rp_b1, H1, pb, PCH, FLAG);
      GEMMM(H1, 1, oRp2, rp_b2, 0, H2, 1, PCH, 128, 128, 3, 0, 1);
      rp_l3_k<<<CDIV(PCH,32), 256, 0, stream>>>(H2, rp_w3, rp_b3, BIAS, pb, PCH, FLAG);
    }
  }

  // ---- transformer ----
  build_x_k<<<CDIV(NB*NT*DIM, 256), 256, 0, stream>>>(SLOTS, TOK, X);
  for (int l = 0; l < 6; ++l) {
    size_t lw = (size_t)l * 512 * 512;
    rms512_k<<<MROW, 256, 0, stream>>>(X, attn_g, l * DIM, HBB, FLAG);
    gemm_mfma_tri<<<dim3(8, 20, 3), 256, 0, stream>>>(
        HBB, 1, WTS, oWq + lw, oWk + lw, oWv + lw, QHB, KHB, VHB, 1, MROW, DIM, DIM, FLAG);
    attn_fused_k<<<dim3(10, NB*NH), 256, 0, stream>>>(QHB, KHB, VHB, BIAS, OBB);
    GEMMM(OBB, 1, oWol + lw, (const void*)nullptr, 0, X, 0, MROW, DIM, DIM, 0, 1, 2);
    rms512_k<<<MROW, 256, 0, stream>>>(X, ff_g, l * DIM, HBB, FLAG);
    GEMMM(HBB, 1, oFf1 + (size_t)l * 512 * 2048, ff_b1, l * FF, FFHB, 1, MROW, FF, DIM, 2, 0, 1);
    GEMMM(FFHB, 1, oFf2 + (size_t)l * 2048 * 512, ff_b2, l * DIM, X, 0, MROW, DIM, FF, 0, 1, 4);
  }

  // ---- head (K-split 2, atomic into zeroed OUTT) ----
  rms512_k<<<MROW, 256, 0, stream>>>(X, final_g, 0, HBB, FLAG);
  hipMemsetAsync(OUTT, 0, (size_t)NB * NT * DIM * sizeof(float), stream);
  GEMMM(HBB, 1, oPred, pred_b, 0, OUTT, 0, MROW, DIM, DIM, 0, 0, 2);
  write_out_k<<<CDIV(NB*HWT*DIM, 256), 256, 0, stream>>>(OUTT, d_out, FLAG);

#undef GEMMM
}